// Round 2
// baseline (7460.663 us; speedup 1.0000x reference)
//
#include <hip/hip_runtime.h>
#include <cstddef>

// Problem dims
#define NR 4096      // batch
#define CDIM 512     // concepts
#define HDIM 128     // hidden
#define TSTEPS 64
#define DDIM 20
#define KTOP 10

// ---------------------------------------------------------------------------
// Generic fp32 tiled GEMM: C[M,N] = A[M,K] @ op(B) (+bias)(+leaky_relu)
// flags: 1 = B is [N,K] (compute A@B^T), else B is [K,N]; 2 = add bias[n];
// 4 = leaky_relu(0.01)
// ---------------------------------------------------------------------------
struct GemmArgs {
    const float* A; const float* B; const float* bias; float* C;
    int N, K, flags;
};

__global__ __launch_bounds__(256) void gemm_multi(GemmArgs g0, GemmArgs g1)
{
    GemmArgs g = (blockIdx.z == 0) ? g0 : g1;
    const int tid = threadIdx.x;
    const int bm = blockIdx.y << 6, bn = blockIdx.x << 6;
    __shared__ float As[32][68];
    __shared__ float Bs[32][68];
    const int tx = tid & 15, ty = tid >> 4;
    const int lc = tid & 31, lr = tid >> 5;
    const int ln = tid & 63, lk = tid >> 6;
    const int K = g.K, N = g.N;
    float acc[4][4] = {};
    for (int k0 = 0; k0 < K; k0 += 32) {
        #pragma unroll
        for (int i = 0; i < 8; i++) {
            int row = lr + (i << 3);
            int k = k0 + lc;
            As[lc][row] = (k < K) ? g.A[(size_t)(bm + row) * K + k] : 0.f;
        }
        if (g.flags & 1) {
            #pragma unroll
            for (int i = 0; i < 8; i++) {
                int row = lr + (i << 3);
                int k = k0 + lc;
                Bs[lc][row] = (k < K) ? g.B[(size_t)(bn + row) * K + k] : 0.f;
            }
        } else {
            #pragma unroll
            for (int i = 0; i < 8; i++) {
                int kk = lk + (i << 2);
                int k = k0 + kk;
                Bs[kk][ln] = (k < K) ? g.B[(size_t)k * N + bn + ln] : 0.f;
            }
        }
        __syncthreads();
        #pragma unroll
        for (int kk = 0; kk < 32; kk++) {
            float a[4], b[4];
            #pragma unroll
            for (int i = 0; i < 4; i++) a[i] = As[kk][(ty << 2) + i];
            #pragma unroll
            for (int j = 0; j < 4; j++) b[j] = Bs[kk][(tx << 2) + j];
            #pragma unroll
            for (int i = 0; i < 4; i++)
                #pragma unroll
                for (int j = 0; j < 4; j++)
                    acc[i][j] += a[i] * b[j];
        }
        __syncthreads();
    }
    #pragma unroll
    for (int i = 0; i < 4; i++) {
        int m = bm + (ty << 2) + i;
        #pragma unroll
        for (int j = 0; j < 4; j++) {
            int n = bn + (tx << 2) + j;
            float v = acc[i][j];
            if (g.flags & 2) v += g.bias[n];
            if (g.flags & 4) v = v > 0.f ? v : 0.01f * v;
            g.C[(size_t)m * N + n] = v;
        }
    }
}

// ---------------------------------------------------------------------------
// Fused persistent 2-layer GRU. 256 blocks x 256 threads; block owns 16
// samples for all 64 steps. Weights pre-transposed to [K][384] so k-tiles
// (16x384 = 24.6 KB) stage coalesced into LDS via register double-buffer.
// Thread = (sample s = tid&15, 8 gate-columns j0 = wave*32 + quad*8).
// ---------------------------------------------------------------------------
#define HPITCH 132

#define FMA8(A, W0, W1, V) \
    A[0] += W0.x * (V); A[1] += W0.y * (V); A[2] += W0.z * (V); A[3] += W0.w * (V); \
    A[4] += W1.x * (V); A[5] += W1.y * (V); A[6] += W1.z * (V); A[7] += W1.w * (V);

__device__ __forceinline__ void mat_tiles(const float* __restrict__ W,
        const float* __restrict__ Wnext,
        const float* __restrict__ hrow,
        float4 (&pf)[6], float* wt, int j0,
        float (&accr)[8], float (&accz)[8], float (&accn)[8])
{
    const int tid = threadIdx.x;
    for (int kt = 0; kt < 8; kt++) {
        __syncthreads();                       // prev compute done; buf free
        float4* wv = (float4*)wt;
        #pragma unroll
        for (int c = 0; c < 6; c++) wv[tid + (c << 8)] = pf[c];
        const float4* nsrc = (const float4*)((kt < 7) ? (W + (size_t)(kt + 1) * 6144) : Wnext);
        #pragma unroll
        for (int c = 0; c < 6; c++) pf[c] = nsrc[tid + (c << 8)];
        __syncthreads();                       // tile visible
        #pragma unroll
        for (int kq = 0; kq < 4; kq++) {
            float4 hv = *(const float4*)(hrow + (kt << 4) + (kq << 2));
            #pragma unroll
            for (int k2 = 0; k2 < 4; k2++) {
                const float* wk = wt + ((kq << 2) + k2) * 384;
                float v = (&hv.x)[k2];
                float4 a0 = *(const float4*)(wk + j0);
                float4 a1 = *(const float4*)(wk + j0 + 4);
                float4 b0 = *(const float4*)(wk + 128 + j0);
                float4 b1 = *(const float4*)(wk + 128 + j0 + 4);
                float4 c0 = *(const float4*)(wk + 256 + j0);
                float4 c1 = *(const float4*)(wk + 256 + j0 + 4);
                FMA8(accr, a0, a1, v);
                FMA8(accz, b0, b1, v);
                FMA8(accn, c0, c1, v);
            }
        }
    }
}

__global__ __launch_bounds__(256) void gru_fused(
    const float* __restrict__ x,
    const float* __restrict__ wih0T, const float* __restrict__ whh0T,
    const float* __restrict__ wih1T, const float* __restrict__ whh1T,
    const float* __restrict__ bih0, const float* __restrict__ bhh0,
    const float* __restrict__ bih1, const float* __restrict__ bhh1,
    float* __restrict__ xh)
{
    __shared__ float wt[16 * 384];             // 24576 B
    __shared__ float hb[2][16 * HPITCH];       // 16896 B
    const int tid = threadIdx.x;
    const int s = tid & 15;
    const int j0 = ((tid >> 6) << 5) | (((tid >> 4) & 3) << 3);  // 0..120 step 8
    const int n0 = blockIdx.x << 4;
    float* h0row = &hb[0][s * HPITCH];
    float* h1row = &hb[1][s * HPITCH];

    for (int i = tid; i < 2 * 16 * HPITCH; i += 256) ((float*)hb)[i] = 0.f;

    // persistent per-thread biases
    float br0[8], bz0[8], bn0i[8], bn0h[8], br1[8], bz1[8], bn1i[8], bn1h[8];
    #pragma unroll
    for (int jj = 0; jj < 8; jj++) {
        int j = j0 + jj;
        br0[jj]  = bih0[j] + bhh0[j];
        bz0[jj]  = bih0[128 + j] + bhh0[128 + j];
        bn0i[jj] = bih0[256 + j];
        bn0h[jj] = bhh0[256 + j];
        br1[jj]  = bih1[j] + bhh1[j];
        bz1[jj]  = bih1[128 + j] + bhh1[128 + j];
        bn1i[jj] = bih1[256 + j];
        bn1h[jj] = bhh1[256 + j];
    }

    float4 pf[6];
    {
        const float4* src = (const float4*)whh0T;
        #pragma unroll
        for (int c = 0; c < 6; c++) pf[c] = src[tid + (c << 8)];
    }
    __syncthreads();

    float accr[8], accz[8], accni[8], accnh[8];
    const float* xrow = x + (size_t)(n0 + s) * (DDIM * TSTEPS);

    for (int t = 0; t < TSTEPS; t++) {
        // ---------------- layer 0 ----------------
        #pragma unroll
        for (int jj = 0; jj < 8; jj++) { accr[jj] = 0.f; accz[jj] = 0.f; accni[jj] = 0.f; accnh[jj] = 0.f; }
        // x-part (K=20) straight from global wih0T (L1-resident, 30 KB)
        for (int k = 0; k < DDIM; k++) {
            float xv = xrow[(k << 6) + t];
            const float* wk = wih0T + k * 384;
            float4 a0 = *(const float4*)(wk + j0);
            float4 a1 = *(const float4*)(wk + j0 + 4);
            float4 b0 = *(const float4*)(wk + 128 + j0);
            float4 b1 = *(const float4*)(wk + 128 + j0 + 4);
            float4 c0 = *(const float4*)(wk + 256 + j0);
            float4 c1 = *(const float4*)(wk + 256 + j0 + 4);
            FMA8(accr, a0, a1, xv);
            FMA8(accz, b0, b1, xv);
            FMA8(accni, c0, c1, xv);
        }
        // h-part: whh0 (8 tiles over k=0..127)
        mat_tiles(whh0T, wih1T, h0row, pf, wt, j0, accr, accz, accnh);
        __syncthreads();                       // all reads of h0 done
        {
            float4 ha = *(const float4*)(h0row + j0);
            float4 hbb = *(const float4*)(h0row + j0 + 4);
            float hold[8] = {ha.x, ha.y, ha.z, ha.w, hbb.x, hbb.y, hbb.z, hbb.w};
            float hnew[8];
            #pragma unroll
            for (int jj = 0; jj < 8; jj++) {
                float r = 1.f / (1.f + expf(-(accr[jj] + br0[jj])));
                float z = 1.f / (1.f + expf(-(accz[jj] + bz0[jj])));
                float nn = tanhf(accni[jj] + bn0i[jj] + r * (accnh[jj] + bn0h[jj]));
                hnew[jj] = (1.f - z) * nn + z * hold[jj];
            }
            *(float4*)(h0row + j0)     = make_float4(hnew[0], hnew[1], hnew[2], hnew[3]);
            *(float4*)(h0row + j0 + 4) = make_float4(hnew[4], hnew[5], hnew[6], hnew[7]);
        }
        // ---------------- layer 1 ----------------
        #pragma unroll
        for (int jj = 0; jj < 8; jj++) { accr[jj] = 0.f; accz[jj] = 0.f; accni[jj] = 0.f; accnh[jj] = 0.f; }
        mat_tiles(wih1T, whh1T, h0row, pf, wt, j0, accr, accz, accni);   // input = new h0
        mat_tiles(whh1T, whh0T, h1row, pf, wt, j0, accr, accz, accnh);   // recurrent = h1
        __syncthreads();                       // all reads of h1 done
        {
            float4 ha = *(const float4*)(h1row + j0);
            float4 hbb = *(const float4*)(h1row + j0 + 4);
            float hold[8] = {ha.x, ha.y, ha.z, ha.w, hbb.x, hbb.y, hbb.z, hbb.w};
            float hnew[8];
            #pragma unroll
            for (int jj = 0; jj < 8; jj++) {
                float r = 1.f / (1.f + expf(-(accr[jj] + br1[jj])));
                float z = 1.f / (1.f + expf(-(accz[jj] + bz1[jj])));
                float nn = tanhf(accni[jj] + bn1i[jj] + r * (accnh[jj] + bn1h[jj]));
                hnew[jj] = (1.f - z) * nn + z * hold[jj];
            }
            *(float4*)(h1row + j0)     = make_float4(hnew[0], hnew[1], hnew[2], hnew[3]);
            *(float4*)(h1row + j0 + 4) = make_float4(hnew[4], hnew[5], hnew[6], hnew[7]);
        }
    }
    // write x_hidden
    *(float4*)(xh + (size_t)(n0 + s) * HDIM + j0)     = *(const float4*)(h1row + j0);
    *(float4*)(xh + (size_t)(n0 + s) * HDIM + j0 + 4) = *(const float4*)(h1row + j0 + 4);
}

// w [384][K] -> wT [K][384]
__global__ void transpose_w(const float* __restrict__ w, float* __restrict__ wT, int K)
{
    int idx = blockIdx.x * 256 + threadIdx.x;
    if (idx >= 384 * K) return;
    int k = idx / 384, g = idx % 384;
    wT[idx] = w[g * K + k];
}

// ---------------------------------------------------------------------------
// Phase B/C/D helper kernels (unchanged from round 0)
// ---------------------------------------------------------------------------
__global__ void den_kernel(const float* __restrict__ cm, const float* __restrict__ mv,
                           float* __restrict__ den)
{
    int c = blockIdx.x * 64 + (threadIdx.x & 63);
    int rg = threadIdx.x >> 6;
    float acc = 0.f;
    for (int n = rg; n < NR; n += 4) acc += cm[(size_t)n * CDIM + c] * mv[n];
    __shared__ float red[4][64];
    red[rg][threadIdx.x & 63] = acc;
    __syncthreads();
    if (rg == 0)
        den[c] = red[0][threadIdx.x] + red[1][threadIdx.x] + red[2][threadIdx.x] + red[3][threadIdx.x];
}

__global__ void s2ct_kernel(const float* __restrict__ cm, const float* __restrict__ mv,
                            const float* __restrict__ den, float* __restrict__ s2cT)
{
    int idx = blockIdx.x * 256 + threadIdx.x;
    int c = idx >> 12, n = idx & (NR - 1);
    float m = cm[(size_t)n * CDIM + c];
    s2cT[idx] = (m * mv[n]) / (den[c] * m + 1.f);
}

__global__ void row_norm(const float* __restrict__ a, float* __restrict__ out)
{
    int r = blockIdx.x;
    float acc = 0.f;
    for (int h = threadIdx.x; h < HDIM; h += 64) {
        float v = a[(size_t)r * HDIM + h];
        acc += v * v;
    }
    for (int o = 32; o > 0; o >>= 1) acc += __shfl_down(acc, o);
    if (threadIdx.x == 0) out[r] = sqrtf(acc);
}

__global__ void row_nonzero(const float* __restrict__ a, float* __restrict__ out)
{
    int r = blockIdx.x;
    float acc = 0.f;
    for (int h = threadIdx.x; h < HDIM; h += 64) acc += a[(size_t)r * HDIM + h];
    for (int o = 32; o > 0; o >>= 1) acc += __shfl_down(acc, o);
    if (threadIdx.x == 0) out[r] = (acc != 0.f) ? 1.f : 0.f;
}

__global__ __launch_bounds__(256) void cos_softmax_row(float* __restrict__ data, int N,
        const float* __restrict__ rn, const float* __restrict__ cn,
        const float* __restrict__ vmask)
{
    int row = blockIdx.x;
    float* d = data + (size_t)row * N;
    int tid = threadIdx.x;
    __shared__ float red[256];
    float rnv = rn ? rn[row] : 0.f;
    float mx = -INFINITY;
    for (int j = tid; j < N; j += 256) {
        float v = d[j];
        if (cn) v = v / fmaxf(rnv * cn[j], 1e-12f);
        if (vmask && vmask[j] == 0.f) v = -1e9f;
        d[j] = v;
        mx = fmaxf(mx, v);
    }
    red[tid] = mx; __syncthreads();
    for (int sdx = 128; sdx > 0; sdx >>= 1) {
        if (tid < sdx) red[tid] = fmaxf(red[tid], red[tid + sdx]);
        __syncthreads();
    }
    float M = red[0]; __syncthreads();
    float sum = 0.f;
    for (int j = tid; j < N; j += 256) {
        float e = expf(d[j] - M);
        d[j] = e;
        sum += e;
    }
    red[tid] = sum; __syncthreads();
    for (int sdx = 128; sdx > 0; sdx >>= 1) {
        if (tid < sdx) red[tid] += red[tid + sdx];
        __syncthreads();
    }
    float inv = 1.f / red[0];
    for (int j = tid; j < N; j += 256) {
        float v = d[j] * inv;
        if (vmask) v *= vmask[j];
        d[j] = v;
    }
}

__global__ void hs2c_norm(float* __restrict__ S, const float* __restrict__ hn,
                          float* __restrict__ diag)
{
    int idx = blockIdx.x * 256 + threadIdx.x;
    int i = idx >> 12, j = idx & (NR - 1);
    float v = S[idx] / fmaxf(hn[i] * hn[j], 1e-12f);
    if (i == j) { diag[i] = v; v = 0.f; }
    S[idx] = v;
}

__global__ __launch_bounds__(256) void topk_kernel(const float* __restrict__ S,
        float* __restrict__ vals, int* __restrict__ idxs)
{
    int row = blockIdx.x;
    const float* d = S + (size_t)row * NR;
    int tid = threadIdx.x;
    float lv[16]; int li[16];
    #pragma unroll
    for (int i = 0; i < 16; i++) {
        int j = tid + i * 256;
        lv[i] = d[j];
        li[i] = j;
    }
    __shared__ float sv[256];
    __shared__ int si[256];
    for (int k = 0; k < KTOP; k++) {
        float bv = -INFINITY; int bi = 0x7fffffff;
        #pragma unroll
        for (int i = 0; i < 16; i++) {
            if (lv[i] > bv || (lv[i] == bv && li[i] < bi)) { bv = lv[i]; bi = li[i]; }
        }
        sv[tid] = bv; si[tid] = bi;
        __syncthreads();
        for (int sdx = 128; sdx > 0; sdx >>= 1) {
            if (tid < sdx) {
                if (sv[tid + sdx] > sv[tid] || (sv[tid + sdx] == sv[tid] && si[tid + sdx] < si[tid])) {
                    sv[tid] = sv[tid + sdx]; si[tid] = si[tid + sdx];
                }
            }
            __syncthreads();
        }
        if (tid == 0) { vals[row * KTOP + k] = sv[0]; idxs[row * KTOP + k] = si[0]; }
        int w = si[0];
        if ((w & 255) == tid) lv[w >> 8] = -INFINITY;
        __syncthreads();
    }
}

__global__ void colsum_scatter(const float* __restrict__ vals, const int* __restrict__ idxs,
                               float* __restrict__ colsum)
{
    int idx = blockIdx.x * 256 + threadIdx.x;
    if (idx < NR * KTOP) atomicAdd(&colsum[idxs[idx]], vals[idx]);
}

__global__ void hh_scatter(const float* __restrict__ vals, const int* __restrict__ idxs,
                           const float* __restrict__ hsh, float* __restrict__ hh)
{
    int p = blockIdx.x;
    int j = idxs[p];
    float v = vals[p];
    int i = p / KTOP;
    atomicAdd(&hh[(size_t)j * HDIM + threadIdx.x], v * hsh[(size_t)i * HDIM + threadIdx.x]);
}

__global__ void hh_diag(const float* __restrict__ colsum, const float* __restrict__ diag,
                        const float* __restrict__ hsh, float* __restrict__ hh)
{
    int idx = blockIdx.x * 256 + threadIdx.x;
    int j = idx >> 7;
    if (colsum[j] != 0.f) hh[idx] += diag[j] * hsh[idx];
}

__global__ void sub2_kernel(const float* __restrict__ a, const float* __restrict__ b,
                            float* __restrict__ o)
{
    int i = blockIdx.x * 256 + threadIdx.x;
    o[i] = a[i] - b[i];
}

__global__ void sub3_kernel(const float* __restrict__ a, const float* __restrict__ b,
                            const float* __restrict__ c, float* __restrict__ o)
{
    int i = blockIdx.x * 256 + threadIdx.x;
    o[i] = a[i] - b[i] - c[i];
}

__global__ void head_kernel(const float* __restrict__ ps, const float* __restrict__ hs,
                            const float* __restrict__ indi, const float* __restrict__ w,
                            const float* __restrict__ b, float* __restrict__ out)
{
    int n = blockIdx.x;
    int t = threadIdx.x;
    float acc = 0.f;
    for (int h = t; h < HDIM; h += 64) {
        size_t k = (size_t)n * HDIM + h;
        acc += (ps[k] + hs[k] + indi[k]) * w[h];
    }
    for (int o = 32; o > 0; o >>= 1) acc += __shfl_down(acc, o);
    if (t == 0) out[n] = acc + b[0];
}

static inline void launch_gemm(hipStream_t s, const float* A, const float* B,
                               const float* bias, float* C, int M, int N, int K, int flags)
{
    GemmArgs g{A, B, bias, C, N, K, flags};
    gemm_multi<<<dim3(N / 64, M / 64, 1), 256, 0, s>>>(g, g);
}

extern "C" void kernel_launch(void* const* d_in, const int* in_sizes, int n_in,
                              void* d_out, int out_size, void* d_ws, size_t ws_size,
                              hipStream_t stream)
{
    (void)in_sizes; (void)n_in; (void)out_size; (void)ws_size;
    const float* x    = (const float*)d_in[0];
    const float* cm   = (const float*)d_in[1];
    const float* mv   = (const float*)d_in[2];
    const float* wih0 = (const float*)d_in[3];
    const float* whh0 = (const float*)d_in[4];
    const float* bih0 = (const float*)d_in[5];
    const float* bhh0 = (const float*)d_in[6];
    const float* wih1 = (const float*)d_in[7];
    const float* whh1 = (const float*)d_in[8];
    const float* bih1 = (const float*)d_in[9];
    const float* bhh1 = (const float*)d_in[10];
    const float* w_ps = (const float*)d_in[11];
    const float* b_ps = (const float*)d_in[12];
    const float* w_hs = (const float*)d_in[13];
    const float* b_hs = (const float*)d_in[14];
    const float* w_ps_fore = (const float*)d_in[15];
    const float* b_ps_fore = (const float*)d_in[16];
    const float* w_hs_fore = (const float*)d_in[17];
    const float* b_hs_fore = (const float*)d_in[18];
    const float* w_ps_back = (const float*)d_in[19];
    const float* b_ps_back = (const float*)d_in[20];
    const float* w_hs_back = (const float*)d_in[21];
    const float* b_hs_back = (const float*)d_in[22];
    const float* w_indi = (const float*)d_in[23];
    const float* b_indi = (const float*)d_in[24];
    const float* w_out  = (const float*)d_in[25];
    const float* b_out  = (const float*)d_in[26];
    float* out = (float*)d_out;

    // ---- workspace layout (floats) ----
    float* ws = (float*)d_ws;
    float* BIG = ws;                         // 16,777,216 (overlaid)
    float* h0 = ws + 16777216;               // 524288 (unused now)
    float* h1 = h0 + 524288;                 // 524288 (= x_hidden)
    float* den = h1 + 524288;                // 512
    float* v1 = den + 512;                   // 512
    float* hidden = v1 + 512;                // 65536
    float* hidden2 = hidden + 65536;         // 65536
    float* xnorm = hidden2 + 65536;          // 4096
    float* h2n = xnorm + 4096;               // 512
    float* p0 = h2n + 512;                   // 524288
    float* p_shared = p0 + 524288;
    float* p_back = p_shared + 524288;
    float* out_ps = p_back + 524288;
    float* h_shared = out_ps + 524288;
    float* hn = h_shared + 524288;           // 4096
    float* diagv = hn + 4096;                // 4096
    float* colsum = diagv + 4096;            // 4096
    float* tvals = colsum + 4096;            // 40960
    int*   tidx = (int*)(tvals + 40960);     // 40960 ints
    float* hidden_h = (float*)(tidx + 40960);
    float* v2 = hidden_h + 524288;           // 4096
    float* hhn = v2 + 4096;                  // 4096
    float* hsi0 = hhn + 4096;                // 524288
    float* h_si = hsi0 + 524288;
    float* h_back = h_si + 524288;
    float* out_hs = h_back + 524288;
    float* indi = out_hs + 524288;
    float* out_indi = indi + 524288;
    // overlays inside BIG:
    float* wih0T = BIG;                      // 7680   (GRU phase)
    float* whh0T = wih0T + 7680;             // 49152
    float* wih1T = whh0T + 49152;            // 49152
    float* whh1T = wih1T + 49152;            // 49152
    float* s2cT = BIG;                       // 2,097,152  (concept phase)
    float* L    = BIG + 2097152;             // 2,097,152
    float* c2s  = BIG + 4194304;             // 2,097,152

    // ================= Phase A: fused 2-layer GRU =================
    transpose_w<<<(384 * DDIM + 255) / 256, 256, 0, stream>>>(wih0, wih0T, DDIM);
    transpose_w<<<(384 * HDIM + 255) / 256, 256, 0, stream>>>(whh0, whh0T, HDIM);
    transpose_w<<<(384 * HDIM + 255) / 256, 256, 0, stream>>>(wih1, wih1T, HDIM);
    transpose_w<<<(384 * HDIM + 255) / 256, 256, 0, stream>>>(whh1, whh1T, HDIM);
    gru_fused<<<NR / 16, 256, 0, stream>>>(x, wih0T, whh0T, wih1T, whh1T,
                                           bih0, bhh0, bih1, bhh1, h1);
    float* x_hidden = h1;

    // ================= Phase B: predefined-concept branch =================
    den_kernel<<<8, 256, 0, stream>>>(cm, mv, den);
    s2ct_kernel<<<(CDIM * NR) / 256, 256, 0, stream>>>(cm, mv, den, s2cT);
    launch_gemm(stream, s2cT, x_hidden, nullptr, hidden, CDIM, HDIM, NR, 0);
    row_nonzero<<<CDIM, 64, 0, stream>>>(hidden, v1);
    launch_gemm(stream, hidden, x_hidden, nullptr, L, CDIM, NR, HDIM, 1);
    cos_softmax_row<<<CDIM, 256, 0, stream>>>(L, NR, nullptr, nullptr, nullptr);
    launch_gemm(stream, L, x_hidden, nullptr, hidden2, CDIM, HDIM, NR, 0);
    row_norm<<<NR, 64, 0, stream>>>(x_hidden, xnorm);
    row_norm<<<CDIM, 64, 0, stream>>>(hidden2, h2n);
    launch_gemm(stream, x_hidden, hidden2, nullptr, c2s, NR, CDIM, HDIM, 1);
    cos_softmax_row<<<NR, 256, 0, stream>>>(c2s, CDIM, xnorm, h2n, v1);
    launch_gemm(stream, c2s, hidden2, nullptr, p0, NR, HDIM, CDIM, 0);
    launch_gemm(stream, p0, w_ps, b_ps, p_shared, NR, HDIM, HDIM, 1 | 2);
    launch_gemm(stream, p_shared, w_ps_back, b_ps_back, p_back, NR, HDIM, HDIM, 1 | 2);
    launch_gemm(stream, p_shared, w_ps_fore, b_ps_fore, out_ps, NR, HDIM, HDIM, 1 | 2 | 4);

    // ================= Phase C: hidden-concept branch =================
    sub2_kernel<<<2048, 256, 0, stream>>>(x_hidden, p_back, h_shared);
    row_norm<<<NR, 64, 0, stream>>>(h_shared, hn);
    launch_gemm(stream, h_shared, h_shared, nullptr, BIG, NR, NR, HDIM, 1);
    hs2c_norm<<<(NR * NR) / 256, 256, 0, stream>>>(BIG, hn, diagv);
    topk_kernel<<<NR, 256, 0, stream>>>(BIG, tvals, tidx);
    hipMemsetAsync(colsum, 0, NR * sizeof(float), stream);
    hipMemsetAsync(hidden_h, 0, 524288 * sizeof(float), stream);
    colsum_scatter<<<(NR * KTOP + 255) / 256, 256, 0, stream>>>(tvals, tidx, colsum);
    hh_scatter<<<NR * KTOP, HDIM, 0, stream>>>(tvals, tidx, h_shared, hidden_h);
    hh_diag<<<2048, 256, 0, stream>>>(colsum, diagv, h_shared, hidden_h);
    row_nonzero<<<NR, 64, 0, stream>>>(hidden_h, v2);
    row_norm<<<NR, 64, 0, stream>>>(hidden_h, hhn);
    launch_gemm(stream, h_shared, hidden_h, nullptr, BIG, NR, NR, HDIM, 1);
    cos_softmax_row<<<NR, 256, 0, stream>>>(BIG, NR, hn, hhn, v2);
    launch_gemm(stream, BIG, hidden_h, nullptr, hsi0, NR, HDIM, NR, 0);
    launch_gemm(stream, hsi0, w_hs, b_hs, h_si, NR, HDIM, HDIM, 1 | 2);
    launch_gemm(stream, h_si, w_hs_back, b_hs_back, h_back, NR, HDIM, HDIM, 1 | 2);
    launch_gemm(stream, h_si, w_hs_fore, b_hs_fore, out_hs, NR, HDIM, HDIM, 1 | 2 | 4);

    // ================= Phase D: individual branch + head =================
    sub3_kernel<<<2048, 256, 0, stream>>>(x_hidden, p_back, h_back, indi);
    launch_gemm(stream, indi, w_indi, b_indi, out_indi, NR, HDIM, HDIM, 1 | 2 | 4);
    head_kernel<<<NR, 64, 0, stream>>>(out_ps, out_hs, out_indi, w_out, b_out, out);
}

// Round 3
// 5369.095 us; speedup vs baseline: 1.3896x; 1.3896x over previous
//
#include <hip/hip_runtime.h>
#include <cstddef>

// Problem dims
#define NR 4096      // batch
#define CDIM 512     // concepts
#define HDIM 128     // hidden
#define TSTEPS 64
#define DDIM 20
#define KTOP 10

// ---------------------------------------------------------------------------
// Generic fp32 tiled GEMM: C[M,N] = A[M,K] @ op(B) (+bias)(+leaky_relu)
// flags: 1 = B is [N,K] (compute A@B^T), else B is [K,N]; 2 = add bias[n];
// 4 = leaky_relu(0.01)
// ---------------------------------------------------------------------------
struct GemmArgs {
    const float* A; const float* B; const float* bias; float* C;
    int N, K, flags;
};

__global__ __launch_bounds__(256) void gemm_multi(GemmArgs g0, GemmArgs g1)
{
    GemmArgs g = (blockIdx.z == 0) ? g0 : g1;
    const int tid = threadIdx.x;
    const int bm = blockIdx.y << 6, bn = blockIdx.x << 6;
    __shared__ float As[32][68];
    __shared__ float Bs[32][68];
    const int tx = tid & 15, ty = tid >> 4;
    const int lc = tid & 31, lr = tid >> 5;
    const int ln = tid & 63, lk = tid >> 6;
    const int K = g.K, N = g.N;
    float acc[4][4] = {};
    for (int k0 = 0; k0 < K; k0 += 32) {
        #pragma unroll
        for (int i = 0; i < 8; i++) {
            int row = lr + (i << 3);
            int k = k0 + lc;
            As[lc][row] = (k < K) ? g.A[(size_t)(bm + row) * K + k] : 0.f;
        }
        if (g.flags & 1) {
            #pragma unroll
            for (int i = 0; i < 8; i++) {
                int row = lr + (i << 3);
                int k = k0 + lc;
                Bs[lc][row] = (k < K) ? g.B[(size_t)(bn + row) * K + k] : 0.f;
            }
        } else {
            #pragma unroll
            for (int i = 0; i < 8; i++) {
                int kk = lk + (i << 2);
                int k = k0 + kk;
                Bs[kk][ln] = (k < K) ? g.B[(size_t)k * N + bn + ln] : 0.f;
            }
        }
        __syncthreads();
        #pragma unroll
        for (int kk = 0; kk < 32; kk++) {
            float a[4], b[4];
            #pragma unroll
            for (int i = 0; i < 4; i++) a[i] = As[kk][(ty << 2) + i];
            #pragma unroll
            for (int j = 0; j < 4; j++) b[j] = Bs[kk][(tx << 2) + j];
            #pragma unroll
            for (int i = 0; i < 4; i++)
                #pragma unroll
                for (int j = 0; j < 4; j++)
                    acc[i][j] += a[i] * b[j];
        }
        __syncthreads();
    }
    #pragma unroll
    for (int i = 0; i < 4; i++) {
        int m = bm + (ty << 2) + i;
        #pragma unroll
        for (int j = 0; j < 4; j++) {
            int n = bn + (tx << 2) + j;
            float v = acc[i][j];
            if (g.flags & 2) v += g.bias[n];
            if (g.flags & 4) v = v > 0.f ? v : 0.01f * v;
            g.C[(size_t)m * N + n] = v;
        }
    }
}

// ---------------------------------------------------------------------------
// Fused 2-layer GRU, v2. 256 blocks x 256 threads; block owns 16 samples for
// all 64 steps. Weights stream from global (L2-resident, ~600 KB total, all
// blocks share) -- NO LDS staging, NO k-split, NO reductions. Only h0/h1/x
// tiles live in LDS. Thread = (col-group cg: 2 cols per gate region,
// sample-group sg: 4 samples); full-K dot products per thread; 3 barriers
// per step.
//   lane = sg*16 + cgl (cgl = lane&15), wave w: cg = w*16 + cgl.
//   Per k: 1 ds_read_b128 (h[k][s0..s0+3]) + 3 global float2 -> 24 FMAs.
// ---------------------------------------------------------------------------
#define GPF 4   // prefetch ring depth

struct MMAcc { float r[2][4], z[2][4], n[2][4]; };

template<int NK>
__device__ __forceinline__ void mm_stream(const float* __restrict__ W, // + 2cg applied
                                          const float* __restrict__ hl, // LDS [k][16]
                                          int s0,
                                          float (&ar)[2][4], float (&az)[2][4],
                                          float (&an)[2][4])
{
    float2 pr[GPF], pz[GPF], pn[GPF];
    float4 ph[GPF];
    #pragma unroll
    for (int p = 0; p < GPF; p++) {
        const float* wr = W + p * 384;
        pr[p] = *(const float2*)(wr);
        pz[p] = *(const float2*)(wr + 128);
        pn[p] = *(const float2*)(wr + 256);
        ph[p] = *(const float4*)(hl + p * 16 + s0);
    }
    #pragma unroll 4
    for (int k = 0; k < NK; k++) {
        const int slot = k & (GPF - 1);
        float2 wr = pr[slot], wz = pz[slot], wn = pn[slot];
        float4 hv = ph[slot];
        if (k + GPF < NK) {
            const float* wnx = W + (k + GPF) * 384;
            pr[slot] = *(const float2*)(wnx);
            pz[slot] = *(const float2*)(wnx + 128);
            pn[slot] = *(const float2*)(wnx + 256);
            ph[slot] = *(const float4*)(hl + (k + GPF) * 16 + s0);
        }
        #pragma unroll
        for (int ss = 0; ss < 4; ss++) {
            float h = (&hv.x)[ss];
            ar[0][ss] += wr.x * h; ar[1][ss] += wr.y * h;
            az[0][ss] += wz.x * h; az[1][ss] += wz.y * h;
            an[0][ss] += wn.x * h; an[1][ss] += wn.y * h;
        }
    }
}

__device__ __forceinline__ float sigm(float v) { return 1.f / (1.f + __expf(-v)); }

__global__ __launch_bounds__(256) void gru_fused2(
    const float* __restrict__ seq,   // [T][NR][D] (pre-transposed)
    const float* __restrict__ wih0T, const float* __restrict__ whh0T,
    const float* __restrict__ wih1T, const float* __restrict__ whh1T,
    const float* __restrict__ bih0, const float* __restrict__ bhh0,
    const float* __restrict__ bih1, const float* __restrict__ bhh1,
    float* __restrict__ xh)
{
    __shared__ float h0s[HDIM * 16];     // [unit][sample] 8 KB
    __shared__ float h1s[HDIM * 16];     // 8 KB
    __shared__ float xs[2][DDIM * 16];   // [buf][d][sample] 2.5 KB

    const int tid = threadIdx.x;
    const int w = tid >> 6;
    const int lane = tid & 63;
    const int cgl = lane & 15;
    const int sg = lane >> 4;
    const int cg = w * 16 + cgl;       // 0..63
    const int c0 = cg * 2;             // first of 2 cols per gate region
    const int s0 = sg * 4;             // first of 4 samples
    const int n0 = blockIdx.x << 4;

    // zero h
    for (int i = tid; i < HDIM * 16; i += 256) { h0s[i] = 0.f; h1s[i] = 0.f; }

    // biases for owned cols
    float br0[2], bz0[2], bni0[2], bnh0[2], br1[2], bz1[2], bni1[2], bnh1[2];
    #pragma unroll
    for (int cc = 0; cc < 2; cc++) {
        int j = c0 + cc;
        br0[cc]  = bih0[j] + bhh0[j];
        bz0[cc]  = bih0[128 + j] + bhh0[128 + j];
        bni0[cc] = bih0[256 + j];
        bnh0[cc] = bhh0[256 + j];
        br1[cc]  = bih1[j] + bhh1[j];
        bz1[cc]  = bih1[128 + j] + bhh1[128 + j];
        bni1[cc] = bih1[256 + j];
        bnh1[cc] = bhh1[256 + j];
    }

    const float* wih0p = wih0T + c0;
    const float* whh0p = whh0T + c0;
    const float* wih1p = wih1T + c0;
    const float* whh1p = whh1T + c0;

    // stage xs for t=0
    {
        const float* src = seq + (size_t)n0 * DDIM;   // t=0: contiguous 320 floats
        int i = tid;
        if (i < DDIM * 16) xs[0][(i % DDIM) * 16 + (i / DDIM)] = src[i];
        i = tid + 256;
        if (i < DDIM * 16) xs[0][(i % DDIM) * 16 + (i / DDIM)] = src[i];
    }
    __syncthreads();

    for (int t = 0; t < TSTEPS; t++) {
        const int buf = t & 1;
        float ar[2][4], az[2][4], ani[2][4], anh[2][4];
        #pragma unroll
        for (int cc = 0; cc < 2; cc++)
            #pragma unroll
            for (int ss = 0; ss < 4; ss++) { ar[cc][ss] = 0.f; az[cc][ss] = 0.f; ani[cc][ss] = 0.f; anh[cc][ss] = 0.f; }

        // ---- layer 0: gx = x @ wih0^T, gh = h0 @ whh0^T ----
        mm_stream<DDIM>(wih0p, xs[buf], s0, ar, az, ani);
        mm_stream<HDIM>(whh0p, h0s, s0, ar, az, anh);
        __syncthreads();                       // all h0/xs reads done
        #pragma unroll
        for (int cc = 0; cc < 2; cc++) {
            float4 hold = *(const float4*)(h0s + (c0 + cc) * 16 + s0);
            float hn[4];
            #pragma unroll
            for (int ss = 0; ss < 4; ss++) {
                float r = sigm(ar[cc][ss] + br0[cc]);
                float z = sigm(az[cc][ss] + bz0[cc]);
                float nn = tanhf(ani[cc][ss] + bni0[cc] + r * (anh[cc][ss] + bnh0[cc]));
                hn[ss] = (1.f - z) * nn + z * (&hold.x)[ss];
            }
            *(float4*)(h0s + (c0 + cc) * 16 + s0) = make_float4(hn[0], hn[1], hn[2], hn[3]);
        }
        __syncthreads();                       // new h0 visible

        // stage xs for t+1 (into other buffer; covered by next barrier)
        if (t + 1 < TSTEPS) {
            const float* src = seq + (size_t)(t + 1) * NR * DDIM + (size_t)n0 * DDIM;
            int i = tid;
            if (i < DDIM * 16) xs[buf ^ 1][(i % DDIM) * 16 + (i / DDIM)] = src[i];
            i = tid + 256;
            if (i < DDIM * 16) xs[buf ^ 1][(i % DDIM) * 16 + (i / DDIM)] = src[i];
        }

        // ---- layer 1: gx = h0new @ wih1^T, gh = h1 @ whh1^T ----
        #pragma unroll
        for (int cc = 0; cc < 2; cc++)
            #pragma unroll
            for (int ss = 0; ss < 4; ss++) { ar[cc][ss] = 0.f; az[cc][ss] = 0.f; ani[cc][ss] = 0.f; anh[cc][ss] = 0.f; }
        mm_stream<HDIM>(wih1p, h0s, s0, ar, az, ani);
        mm_stream<HDIM>(whh1p, h1s, s0, ar, az, anh);
        __syncthreads();                       // all h0/h1 reads + xs writes done
        #pragma unroll
        for (int cc = 0; cc < 2; cc++) {
            float4 hold = *(const float4*)(h1s + (c0 + cc) * 16 + s0);
            float hn[4];
            #pragma unroll
            for (int ss = 0; ss < 4; ss++) {
                float r = sigm(ar[cc][ss] + br1[cc]);
                float z = sigm(az[cc][ss] + bz1[cc]);
                float nn = tanhf(ani[cc][ss] + bni1[cc] + r * (anh[cc][ss] + bnh1[cc]));
                hn[ss] = (1.f - z) * nn + z * (&hold.x)[ss];
            }
            *(float4*)(h1s + (c0 + cc) * 16 + s0) = make_float4(hn[0], hn[1], hn[2], hn[3]);
        }
        // h1 writes ordered before next layer-1 reads by next step's 2 barriers
        if (t + 1 == TSTEPS) break;
        __syncthreads();                       // h1 visible (and keeps step phases aligned)
    }

    // write x_hidden: owned cells
    #pragma unroll
    for (int cc = 0; cc < 2; cc++)
        #pragma unroll
        for (int ss = 0; ss < 4; ss++)
            xh[(size_t)(n0 + s0 + ss) * HDIM + c0 + cc] = h1s[(c0 + cc) * 16 + s0 + ss];
}

// x [N, D*T] -> seq [T, N, D]: seq[t,n,d] = x[n, d*T + t]
__global__ void seq_transpose(const float* __restrict__ x, float* __restrict__ seq)
{
    int idx = blockIdx.x * 256 + threadIdx.x;  // T*N*D = 5,242,880
    int d = idx % DDIM;
    int r = idx / DDIM;
    int n = r & (NR - 1);
    int t = r >> 12;
    seq[idx] = x[(size_t)n * (DDIM * TSTEPS) + d * TSTEPS + t];
}

// w [384][K] -> wT [K][384]
__global__ void transpose_w(const float* __restrict__ w, float* __restrict__ wT, int K)
{
    int idx = blockIdx.x * 256 + threadIdx.x;
    if (idx >= 384 * K) return;
    int k = idx / 384, g = idx % 384;
    wT[idx] = w[g * K + k];
}

// ---------------------------------------------------------------------------
// Phase B/C/D helper kernels (unchanged)
// ---------------------------------------------------------------------------
__global__ void den_kernel(const float* __restrict__ cm, const float* __restrict__ mv,
                           float* __restrict__ den)
{
    int c = blockIdx.x * 64 + (threadIdx.x & 63);
    int rg = threadIdx.x >> 6;
    float acc = 0.f;
    for (int n = rg; n < NR; n += 4) acc += cm[(size_t)n * CDIM + c] * mv[n];
    __shared__ float red[4][64];
    red[rg][threadIdx.x & 63] = acc;
    __syncthreads();
    if (rg == 0)
        den[c] = red[0][threadIdx.x] + red[1][threadIdx.x] + red[2][threadIdx.x] + red[3][threadIdx.x];
}

__global__ void s2ct_kernel(const float* __restrict__ cm, const float* __restrict__ mv,
                            const float* __restrict__ den, float* __restrict__ s2cT)
{
    int idx = blockIdx.x * 256 + threadIdx.x;
    int c = idx >> 12, n = idx & (NR - 1);
    float m = cm[(size_t)n * CDIM + c];
    s2cT[idx] = (m * mv[n]) / (den[c] * m + 1.f);
}

__global__ void row_norm(const float* __restrict__ a, float* __restrict__ out)
{
    int r = blockIdx.x;
    float acc = 0.f;
    for (int h = threadIdx.x; h < HDIM; h += 64) {
        float v = a[(size_t)r * HDIM + h];
        acc += v * v;
    }
    for (int o = 32; o > 0; o >>= 1) acc += __shfl_down(acc, o);
    if (threadIdx.x == 0) out[r] = sqrtf(acc);
}

__global__ void row_nonzero(const float* __restrict__ a, float* __restrict__ out)
{
    int r = blockIdx.x;
    float acc = 0.f;
    for (int h = threadIdx.x; h < HDIM; h += 64) acc += a[(size_t)r * HDIM + h];
    for (int o = 32; o > 0; o >>= 1) acc += __shfl_down(acc, o);
    if (threadIdx.x == 0) out[r] = (acc != 0.f) ? 1.f : 0.f;
}

__global__ __launch_bounds__(256) void cos_softmax_row(float* __restrict__ data, int N,
        const float* __restrict__ rn, const float* __restrict__ cn,
        const float* __restrict__ vmask)
{
    int row = blockIdx.x;
    float* d = data + (size_t)row * N;
    int tid = threadIdx.x;
    __shared__ float red[256];
    float rnv = rn ? rn[row] : 0.f;
    float mx = -INFINITY;
    for (int j = tid; j < N; j += 256) {
        float v = d[j];
        if (cn) v = v / fmaxf(rnv * cn[j], 1e-12f);
        if (vmask && vmask[j] == 0.f) v = -1e9f;
        d[j] = v;
        mx = fmaxf(mx, v);
    }
    red[tid] = mx; __syncthreads();
    for (int sdx = 128; sdx > 0; sdx >>= 1) {
        if (tid < sdx) red[tid] = fmaxf(red[tid], red[tid + sdx]);
        __syncthreads();
    }
    float M = red[0]; __syncthreads();
    float sum = 0.f;
    for (int j = tid; j < N; j += 256) {
        float e = expf(d[j] - M);
        d[j] = e;
        sum += e;
    }
    red[tid] = sum; __syncthreads();
    for (int sdx = 128; sdx > 0; sdx >>= 1) {
        if (tid < sdx) red[tid] += red[tid + sdx];
        __syncthreads();
    }
    float inv = 1.f / red[0];
    for (int j = tid; j < N; j += 256) {
        float v = d[j] * inv;
        if (vmask) v *= vmask[j];
        d[j] = v;
    }
}

__global__ void hs2c_norm(float* __restrict__ S, const float* __restrict__ hn,
                          float* __restrict__ diag)
{
    int idx = blockIdx.x * 256 + threadIdx.x;
    int i = idx >> 12, j = idx & (NR - 1);
    float v = S[idx] / fmaxf(hn[i] * hn[j], 1e-12f);
    if (i == j) { diag[i] = v; v = 0.f; }
    S[idx] = v;
}

__global__ __launch_bounds__(256) void topk_kernel(const float* __restrict__ S,
        float* __restrict__ vals, int* __restrict__ idxs)
{
    int row = blockIdx.x;
    const float* d = S + (size_t)row * NR;
    int tid = threadIdx.x;
    float lv[16]; int li[16];
    #pragma unroll
    for (int i = 0; i < 16; i++) {
        int j = tid + i * 256;
        lv[i] = d[j];
        li[i] = j;
    }
    __shared__ float sv[256];
    __shared__ int si[256];
    for (int k = 0; k < KTOP; k++) {
        float bv = -INFINITY; int bi = 0x7fffffff;
        #pragma unroll
        for (int i = 0; i < 16; i++) {
            if (lv[i] > bv || (lv[i] == bv && li[i] < bi)) { bv = lv[i]; bi = li[i]; }
        }
        sv[tid] = bv; si[tid] = bi;
        __syncthreads();
        for (int sdx = 128; sdx > 0; sdx >>= 1) {
            if (tid < sdx) {
                if (sv[tid + sdx] > sv[tid] || (sv[tid + sdx] == sv[tid] && si[tid + sdx] < si[tid])) {
                    sv[tid] = sv[tid + sdx]; si[tid] = si[tid + sdx];
                }
            }
            __syncthreads();
        }
        if (tid == 0) { vals[row * KTOP + k] = sv[0]; idxs[row * KTOP + k] = si[0]; }
        int w = si[0];
        if ((w & 255) == tid) lv[w >> 8] = -INFINITY;
        __syncthreads();
    }
}

__global__ void colsum_scatter(const float* __restrict__ vals, const int* __restrict__ idxs,
                               float* __restrict__ colsum)
{
    int idx = blockIdx.x * 256 + threadIdx.x;
    if (idx < NR * KTOP) atomicAdd(&colsum[idxs[idx]], vals[idx]);
}

__global__ void hh_scatter(const float* __restrict__ vals, const int* __restrict__ idxs,
                           const float* __restrict__ hsh, float* __restrict__ hh)
{
    int p = blockIdx.x;
    int j = idxs[p];
    float v = vals[p];
    int i = p / KTOP;
    atomicAdd(&hh[(size_t)j * HDIM + threadIdx.x], v * hsh[(size_t)i * HDIM + threadIdx.x]);
}

__global__ void hh_diag(const float* __restrict__ colsum, const float* __restrict__ diag,
                        const float* __restrict__ hsh, float* __restrict__ hh)
{
    int idx = blockIdx.x * 256 + threadIdx.x;
    int j = idx >> 7;
    if (colsum[j] != 0.f) hh[idx] += diag[j] * hsh[idx];
}

__global__ void sub2_kernel(const float* __restrict__ a, const float* __restrict__ b,
                            float* __restrict__ o)
{
    int i = blockIdx.x * 256 + threadIdx.x;
    o[i] = a[i] - b[i];
}

__global__ void sub3_kernel(const float* __restrict__ a, const float* __restrict__ b,
                            const float* __restrict__ c, float* __restrict__ o)
{
    int i = blockIdx.x * 256 + threadIdx.x;
    o[i] = a[i] - b[i] - c[i];
}

__global__ void head_kernel(const float* __restrict__ ps, const float* __restrict__ hs,
                            const float* __restrict__ indi, const float* __restrict__ w,
                            const float* __restrict__ b, float* __restrict__ out)
{
    int n = blockIdx.x;
    int t = threadIdx.x;
    float acc = 0.f;
    for (int h = t; h < HDIM; h += 64) {
        size_t k = (size_t)n * HDIM + h;
        acc += (ps[k] + hs[k] + indi[k]) * w[h];
    }
    for (int o = 32; o > 0; o >>= 1) acc += __shfl_down(acc, o);
    if (t == 0) out[n] = acc + b[0];
}

static inline void launch_gemm(hipStream_t s, const float* A, const float* B,
                               const float* bias, float* C, int M, int N, int K, int flags)
{
    GemmArgs g{A, B, bias, C, N, K, flags};
    gemm_multi<<<dim3(N / 64, M / 64, 1), 256, 0, s>>>(g, g);
}

extern "C" void kernel_launch(void* const* d_in, const int* in_sizes, int n_in,
                              void* d_out, int out_size, void* d_ws, size_t ws_size,
                              hipStream_t stream)
{
    (void)in_sizes; (void)n_in; (void)out_size; (void)ws_size;
    const float* x    = (const float*)d_in[0];
    const float* cm   = (const float*)d_in[1];
    const float* mv   = (const float*)d_in[2];
    const float* wih0 = (const float*)d_in[3];
    const float* whh0 = (const float*)d_in[4];
    const float* bih0 = (const float*)d_in[5];
    const float* bhh0 = (const float*)d_in[6];
    const float* wih1 = (const float*)d_in[7];
    const float* whh1 = (const float*)d_in[8];
    const float* bih1 = (const float*)d_in[9];
    const float* bhh1 = (const float*)d_in[10];
    const float* w_ps = (const float*)d_in[11];
    const float* b_ps = (const float*)d_in[12];
    const float* w_hs = (const float*)d_in[13];
    const float* b_hs = (const float*)d_in[14];
    const float* w_ps_fore = (const float*)d_in[15];
    const float* b_ps_fore = (const float*)d_in[16];
    const float* w_hs_fore = (const float*)d_in[17];
    const float* b_hs_fore = (const float*)d_in[18];
    const float* w_ps_back = (const float*)d_in[19];
    const float* b_ps_back = (const float*)d_in[20];
    const float* w_hs_back = (const float*)d_in[21];
    const float* b_hs_back = (const float*)d_in[22];
    const float* w_indi = (const float*)d_in[23];
    const float* b_indi = (const float*)d_in[24];
    const float* w_out  = (const float*)d_in[25];
    const float* b_out  = (const float*)d_in[26];
    float* out = (float*)d_out;

    // ---- workspace layout (floats) ----
    float* ws = (float*)d_ws;
    float* BIG = ws;                         // 16,777,216 (overlaid)
    float* h0 = ws + 16777216;               // 524288 (unused)
    float* h1 = h0 + 524288;                 // 524288 (= x_hidden)
    float* den = h1 + 524288;                // 512
    float* v1 = den + 512;                   // 512
    float* hidden = v1 + 512;                // 65536
    float* hidden2 = hidden + 65536;         // 65536
    float* xnorm = hidden2 + 65536;          // 4096
    float* h2n = xnorm + 4096;               // 512
    float* p0 = h2n + 512;                   // 524288
    float* p_shared = p0 + 524288;
    float* p_back = p_shared + 524288;
    float* out_ps = p_back + 524288;
    float* h_shared = out_ps + 524288;
    float* hn = h_shared + 524288;           // 4096
    float* diagv = hn + 4096;                // 4096
    float* colsum = diagv + 4096;            // 4096
    float* tvals = colsum + 4096;            // 40960
    int*   tidx = (int*)(tvals + 40960);     // 40960 ints
    float* hidden_h = (float*)(tidx + 40960);
    float* v2 = hidden_h + 524288;           // 4096
    float* hhn = v2 + 4096;                  // 4096
    float* hsi0 = hhn + 4096;                // 524288
    float* h_si = hsi0 + 524288;
    float* h_back = h_si + 524288;
    float* out_hs = h_back + 524288;
    float* indi = out_hs + 524288;
    float* out_indi = indi + 524288;
    // overlays inside BIG:
    float* seqt  = BIG;                      // 5,242,880  (GRU phase)
    float* wih0T = BIG + 5242880;            // 7680
    float* whh0T = wih0T + 7680;             // 49152
    float* wih1T = whh0T + 49152;            // 49152
    float* whh1T = wih1T + 49152;            // 49152
    float* s2cT = BIG;                       // 2,097,152  (concept phase)
    float* L    = BIG + 2097152;             // 2,097,152
    float* c2s  = BIG + 4194304;             // 2,097,152

    // ================= Phase A: fused 2-layer GRU =================
    seq_transpose<<<(TSTEPS * NR * DDIM) / 256, 256, 0, stream>>>(x, seqt);
    transpose_w<<<(384 * DDIM + 255) / 256, 256, 0, stream>>>(wih0, wih0T, DDIM);
    transpose_w<<<(384 * HDIM + 255) / 256, 256, 0, stream>>>(whh0, whh0T, HDIM);
    transpose_w<<<(384 * HDIM + 255) / 256, 256, 0, stream>>>(wih1, wih1T, HDIM);
    transpose_w<<<(384 * HDIM + 255) / 256, 256, 0, stream>>>(whh1, whh1T, HDIM);
    gru_fused2<<<NR / 16, 256, 0, stream>>>(seqt, wih0T, whh0T, wih1T, whh1T,
                                            bih0, bhh0, bih1, bhh1, h1);
    float* x_hidden = h1;

    // ================= Phase B: predefined-concept branch =================
    den_kernel<<<8, 256, 0, stream>>>(cm, mv, den);
    s2ct_kernel<<<(CDIM * NR) / 256, 256, 0, stream>>>(cm, mv, den, s2cT);
    launch_gemm(stream, s2cT, x_hidden, nullptr, hidden, CDIM, HDIM, NR, 0);
    row_nonzero<<<CDIM, 64, 0, stream>>>(hidden, v1);
    launch_gemm(stream, hidden, x_hidden, nullptr, L, CDIM, NR, HDIM, 1);
    cos_softmax_row<<<CDIM, 256, 0, stream>>>(L, NR, nullptr, nullptr, nullptr);
    launch_gemm(stream, L, x_hidden, nullptr, hidden2, CDIM, HDIM, NR, 0);
    row_norm<<<NR, 64, 0, stream>>>(x_hidden, xnorm);
    row_norm<<<CDIM, 64, 0, stream>>>(hidden2, h2n);
    launch_gemm(stream, x_hidden, hidden2, nullptr, c2s, NR, CDIM, HDIM, 1);
    cos_softmax_row<<<NR, 256, 0, stream>>>(c2s, CDIM, xnorm, h2n, v1);
    launch_gemm(stream, c2s, hidden2, nullptr, p0, NR, HDIM, CDIM, 0);
    launch_gemm(stream, p0, w_ps, b_ps, p_shared, NR, HDIM, HDIM, 1 | 2);
    launch_gemm(stream, p_shared, w_ps_back, b_ps_back, p_back, NR, HDIM, HDIM, 1 | 2);
    launch_gemm(stream, p_shared, w_ps_fore, b_ps_fore, out_ps, NR, HDIM, HDIM, 1 | 2 | 4);

    // ================= Phase C: hidden-concept branch =================
    sub2_kernel<<<2048, 256, 0, stream>>>(x_hidden, p_back, h_shared);
    row_norm<<<NR, 64, 0, stream>>>(h_shared, hn);
    launch_gemm(stream, h_shared, h_shared, nullptr, BIG, NR, NR, HDIM, 1);
    hs2c_norm<<<(NR * NR) / 256, 256, 0, stream>>>(BIG, hn, diagv);
    topk_kernel<<<NR, 256, 0, stream>>>(BIG, tvals, tidx);
    hipMemsetAsync(colsum, 0, NR * sizeof(float), stream);
    hipMemsetAsync(hidden_h, 0, 524288 * sizeof(float), stream);
    colsum_scatter<<<(NR * KTOP + 255) / 256, 256, 0, stream>>>(tvals, tidx, colsum);
    hh_scatter<<<NR * KTOP, HDIM, 0, stream>>>(tvals, tidx, h_shared, hidden_h);
    hh_diag<<<2048, 256, 0, stream>>>(colsum, diagv, h_shared, hidden_h);
    row_nonzero<<<NR, 64, 0, stream>>>(hidden_h, v2);
    row_norm<<<NR, 64, 0, stream>>>(hidden_h, hhn);
    launch_gemm(stream, h_shared, hidden_h, nullptr, BIG, NR, NR, HDIM, 1);
    cos_softmax_row<<<NR, 256, 0, stream>>>(BIG, NR, hn, hhn, v2);
    launch_gemm(stream, BIG, hidden_h, nullptr, hsi0, NR, HDIM, NR, 0);
    launch_gemm(stream, hsi0, w_hs, b_hs, h_si, NR, HDIM, HDIM, 1 | 2);
    launch_gemm(stream, h_si, w_hs_back, b_hs_back, h_back, NR, HDIM, HDIM, 1 | 2);
    launch_gemm(stream, h_si, w_hs_fore, b_hs_fore, out_hs, NR, HDIM, HDIM, 1 | 2 | 4);

    // ================= Phase D: individual branch + head =================
    sub3_kernel<<<2048, 256, 0, stream>>>(x_hidden, p_back, h_back, indi);
    launch_gemm(stream, indi, w_indi, b_indi, out_indi, NR, HDIM, HDIM, 1 | 2 | 4);
    head_kernel<<<NR, 64, 0, stream>>>(out_ps, out_hs, out_indi, w_out, b_out, out);
}

// Round 4
// 2989.426 us; speedup vs baseline: 2.4957x; 1.7960x over previous
//
#include <hip/hip_runtime.h>
#include <cstddef>

// Problem dims
#define NR 4096      // batch
#define CDIM 512     // concepts
#define HDIM 128     // hidden
#define TSTEPS 64
#define DDIM 20
#define KTOP 10

typedef __attribute__((ext_vector_type(8))) short short8;
typedef __attribute__((ext_vector_type(4))) float f32x4;

__device__ __forceinline__ unsigned short f2bf(float f) {
    union { float f; unsigned u; } x; x.f = f;
    unsigned r = (x.u + 0x7fffu + ((x.u >> 16) & 1u)) >> 16;
    return (unsigned short)r;
}
__device__ __forceinline__ float bf2f(unsigned short h) {
    union { unsigned u; float f; } x; x.u = ((unsigned)h) << 16;
    return x.f;
}
__device__ __forceinline__ float sigm(float v) { return 1.f / (1.f + expf(-v)); }

#define MFMA16(a, b, c) __builtin_amdgcn_mfma_f32_16x16x32_bf16(a, b, c, 0, 0, 0)

// ---------------------------------------------------------------------------
// Generic fp32 tiled GEMM (Phase B/C/D): C[M,N] = A[M,K] @ op(B) (+bias)(+lrelu)
// flags: 1 = B is [N,K]; 2 = add bias[n]; 4 = leaky_relu(0.01)
// ---------------------------------------------------------------------------
struct GemmArgs {
    const float* A; const float* B; const float* bias; float* C;
    int N, K, flags;
};

__global__ __launch_bounds__(256) void gemm_multi(GemmArgs g0, GemmArgs g1)
{
    GemmArgs g = (blockIdx.z == 0) ? g0 : g1;
    const int tid = threadIdx.x;
    const int bm = blockIdx.y << 6, bn = blockIdx.x << 6;
    __shared__ float As[32][68];
    __shared__ float Bs[32][68];
    const int tx = tid & 15, ty = tid >> 4;
    const int lc = tid & 31, lr = tid >> 5;
    const int ln = tid & 63, lk = tid >> 6;
    const int K = g.K, N = g.N;
    float acc[4][4] = {};
    for (int k0 = 0; k0 < K; k0 += 32) {
        #pragma unroll
        for (int i = 0; i < 8; i++) {
            int row = lr + (i << 3);
            int k = k0 + lc;
            As[lc][row] = (k < K) ? g.A[(size_t)(bm + row) * K + k] : 0.f;
        }
        if (g.flags & 1) {
            #pragma unroll
            for (int i = 0; i < 8; i++) {
                int row = lr + (i << 3);
                int k = k0 + lc;
                Bs[lc][row] = (k < K) ? g.B[(size_t)(bn + row) * K + k] : 0.f;
            }
        } else {
            #pragma unroll
            for (int i = 0; i < 8; i++) {
                int kk = lk + (i << 2);
                int k = k0 + kk;
                Bs[kk][ln] = (k < K) ? g.B[(size_t)k * N + bn + ln] : 0.f;
            }
        }
        __syncthreads();
        #pragma unroll
        for (int kk = 0; kk < 32; kk++) {
            float a[4], b[4];
            #pragma unroll
            for (int i = 0; i < 4; i++) a[i] = As[kk][(ty << 2) + i];
            #pragma unroll
            for (int j = 0; j < 4; j++) b[j] = Bs[kk][(tx << 2) + j];
            #pragma unroll
            for (int i = 0; i < 4; i++)
                #pragma unroll
                for (int j = 0; j < 4; j++)
                    acc[i][j] += a[i] * b[j];
        }
        __syncthreads();
    }
    #pragma unroll
    for (int i = 0; i < 4; i++) {
        int m = bm + (ty << 2) + i;
        #pragma unroll
        for (int j = 0; j < 4; j++) {
            int n = bn + (tx << 2) + j;
            float v = acc[i][j];
            if (g.flags & 2) v += g.bias[n];
            if (g.flags & 4) v = v > 0.f ? v : 0.01f * v;
            g.C[(size_t)m * N + n] = v;
        }
    }
}

// ---------------------------------------------------------------------------
// Weight pack: W [384][K] fp32 -> Wp [24 tiles][nch kchunks][64 lanes][8] bf16
// MFMA B-fragment linear layout: lane holds B[n = t*16 + (lane&15)]
// [k = c*32 + (lane>>4)*8 + j], j=0..7. Zero-pad k >= K.
// ---------------------------------------------------------------------------
__global__ void pack_wb(const float* __restrict__ W, unsigned short* __restrict__ Wp,
                        int K, int nch)
{
    int idx = blockIdx.x * 256 + threadIdx.x;   // 24*nch*64
    if (idx >= 24 * nch * 64) return;
    int lane = idx & 63;
    int c = (idx >> 6) % nch;
    int t = idx / (nch * 64);
    int n = t * 16 + (lane & 15);
    int kb = c * 32 + (lane >> 4) * 8;
    #pragma unroll
    for (int j = 0; j < 8; j++) {
        int k = kb + j;
        float f = (k < K) ? W[(size_t)n * K + k] : 0.f;
        Wp[(size_t)idx * 8 + j] = f2bf(f);
    }
}

// x [N, D*T] -> seq [T, N, D]: seq[t,n,d] = x[n, d*T + t]
__global__ void seq_transpose(const float* __restrict__ x, float* __restrict__ seq)
{
    int idx = blockIdx.x * 256 + threadIdx.x;  // T*N*D
    int d = idx % DDIM;
    int r = idx / DDIM;
    int n = r & (NR - 1);
    int t = r >> 12;
    seq[idx] = x[(size_t)n * (DDIM * TSTEPS) + d * TSTEPS + t];
}

// ---------------------------------------------------------------------------
// MFMA 2-layer GRU. 256 blocks x 256 threads (4 waves); block owns 16 samples.
// A-side (h, x) split hi+lo bf16 (~16-bit mantissa); weights bf16-hi only,
// pre-packed in fragment-linear layout so hot loads are coalesced dwordx4.
// Wave w owns gate cols j = w*32 + st*16 + (lane&15), st in {0,1}:
//   r-tile = w*2+st, z-tile = 8+w*2+st, n-tile = 16+w*2+st.
// h in LDS as [m][136] shorts (pad 8 -> 2-way-free LDS banks). 3 barriers/step.
// ---------------------------------------------------------------------------
__global__ __launch_bounds__(256) void gru_mfma(
    const float* __restrict__ seq,
    const unsigned short* __restrict__ wih0p,  // [24][1][64][8]
    const unsigned short* __restrict__ whh0p,  // [24][4][64][8]
    const unsigned short* __restrict__ wih1p,  // [24][4][64][8]
    const unsigned short* __restrict__ whh1p,  // [24][4][64][8]
    const float* __restrict__ bih0, const float* __restrict__ bhh0,
    const float* __restrict__ bih1, const float* __restrict__ bhh1,
    float* __restrict__ xh)
{
    __shared__ __attribute__((aligned(16))) unsigned short hA[2][2][16 * 136];
    __shared__ __attribute__((aligned(16))) unsigned short xA[2][2][16 * 40];

    const int tid = threadIdx.x;
    const int w = tid >> 6;
    const int lane = tid & 63;
    const int quad = lane >> 4;
    const int lm = lane & 15;
    const int n0 = blockIdx.x << 4;

    for (int i = tid; i < 2 * 2 * 16 * 136; i += 256) ((unsigned short*)hA)[i] = 0;
    for (int i = tid; i < 2 * 2 * 16 * 40; i += 256) ((unsigned short*)xA)[i] = 0;

    // biases for owned cols
    float br0[2], bz0[2], bni0[2], bnh0[2], br1[2], bz1[2], bni1[2], bnh1[2];
    #pragma unroll
    for (int st = 0; st < 2; st++) {
        int j = w * 32 + st * 16 + lm;
        br0[st]  = bih0[j] + bhh0[j];
        bz0[st]  = bih0[128 + j] + bhh0[128 + j];
        bni0[st] = bih0[256 + j];
        bnh0[st] = bhh0[256 + j];
        br1[st]  = bih1[j] + bhh1[j];
        bz1[st]  = bih1[128 + j] + bhh1[128 + j];
        bni1[st] = bih1[256 + j];
        bnh1[st] = bhh1[256 + j];
    }

    const int aoff = lm * 136 + quad * 8;   // A-frag base (shorts), + c*32
    const int xoff = lm * 40 + quad * 8;

    // stage x for t=0
    {
        const float* src = seq + (size_t)n0 * DDIM;
        for (int i = tid; i < 16 * DDIM; i += 256) {
            int m = i / DDIM, d = i % DDIM;
            float v = src[i];
            unsigned short hi = f2bf(v);
            xA[0][0][m * 40 + d] = hi;
            xA[0][1][m * 40 + d] = f2bf(v - bf2f(hi));
        }
    }
    __syncthreads();

    for (int t = 0; t < TSTEPS; t++) {
        const int buf = t & 1;
        f32x4 accr[2], accz[2], accni[2], accnh[2];
        #pragma unroll
        for (int st = 0; st < 2; st++) {
            accr[st] = (f32x4){0.f, 0.f, 0.f, 0.f};
            accz[st] = (f32x4){0.f, 0.f, 0.f, 0.f};
            accni[st] = (f32x4){0.f, 0.f, 0.f, 0.f};
            accnh[st] = (f32x4){0.f, 0.f, 0.f, 0.f};
        }

        // ======== layer 0 ========
        // x-part (K=32 padded)
        {
            short8 axh = *(const short8*)&xA[buf][0][xoff];
            short8 axl = *(const short8*)&xA[buf][1][xoff];
            #pragma unroll
            for (int st = 0; st < 2; st++) {
                int tb = w * 2 + st;
                short8 b;
                b = *(const short8*)&wih0p[(size_t)(tb) * 512 + lane * 8];
                accr[st] = MFMA16(axh, b, accr[st]);
                accr[st] = MFMA16(axl, b, accr[st]);
                b = *(const short8*)&wih0p[(size_t)(8 + tb) * 512 + lane * 8];
                accz[st] = MFMA16(axh, b, accz[st]);
                accz[st] = MFMA16(axl, b, accz[st]);
                b = *(const short8*)&wih0p[(size_t)(16 + tb) * 512 + lane * 8];
                accni[st] = MFMA16(axh, b, accni[st]);
                accni[st] = MFMA16(axl, b, accni[st]);
            }
        }
        // h-part (whh0, K=128)
        #pragma unroll
        for (int c = 0; c < 4; c++) {
            short8 ahh = *(const short8*)&hA[0][0][aoff + c * 32];
            short8 ahl = *(const short8*)&hA[0][1][aoff + c * 32];
            #pragma unroll
            for (int st = 0; st < 2; st++) {
                int tb = w * 2 + st;
                short8 b;
                b = *(const short8*)&whh0p[(size_t)((tb) * 4 + c) * 512 + lane * 8];
                accr[st] = MFMA16(ahh, b, accr[st]);
                accr[st] = MFMA16(ahl, b, accr[st]);
                b = *(const short8*)&whh0p[(size_t)((8 + tb) * 4 + c) * 512 + lane * 8];
                accz[st] = MFMA16(ahh, b, accz[st]);
                accz[st] = MFMA16(ahl, b, accz[st]);
                b = *(const short8*)&whh0p[(size_t)((16 + tb) * 4 + c) * 512 + lane * 8];
                accnh[st] = MFMA16(ahh, b, accnh[st]);
                accnh[st] = MFMA16(ahl, b, accnh[st]);
            }
        }
        // h0_old for owned cells
        float hold[2][4];
        #pragma unroll
        for (int st = 0; st < 2; st++) {
            int j = w * 32 + st * 16 + lm;
            #pragma unroll
            for (int rg = 0; rg < 4; rg++) {
                int off = (quad * 4 + rg) * 136 + j;
                hold[st][rg] = bf2f(hA[0][0][off]) + bf2f(hA[0][1][off]);
            }
        }
        __syncthreads();     // B1: all reads of h0 done
        #pragma unroll
        for (int st = 0; st < 2; st++) {
            int j = w * 32 + st * 16 + lm;
            #pragma unroll
            for (int rg = 0; rg < 4; rg++) {
                float r = sigm(accr[st][rg] + br0[st]);
                float z = sigm(accz[st][rg] + bz0[st]);
                float nc = tanhf(accni[st][rg] + bni0[st] + r * (accnh[st][rg] + bnh0[st]));
                float hnew = (1.f - z) * nc + z * hold[st][rg];
                int off = (quad * 4 + rg) * 136 + j;
                unsigned short hi = f2bf(hnew);
                hA[0][0][off] = hi;
                hA[0][1][off] = f2bf(hnew - bf2f(hi));
            }
        }
        __syncthreads();     // B2: new h0 visible

        // ======== layer 1 ========
        #pragma unroll
        for (int st = 0; st < 2; st++) {
            accr[st] = (f32x4){0.f, 0.f, 0.f, 0.f};
            accz[st] = (f32x4){0.f, 0.f, 0.f, 0.f};
            accni[st] = (f32x4){0.f, 0.f, 0.f, 0.f};
            accnh[st] = (f32x4){0.f, 0.f, 0.f, 0.f};
        }
        #pragma unroll
        for (int c = 0; c < 4; c++) {
            short8 a0h = *(const short8*)&hA[0][0][aoff + c * 32];
            short8 a0l = *(const short8*)&hA[0][1][aoff + c * 32];
            short8 a1h = *(const short8*)&hA[1][0][aoff + c * 32];
            short8 a1l = *(const short8*)&hA[1][1][aoff + c * 32];
            #pragma unroll
            for (int st = 0; st < 2; st++) {
                int tb = w * 2 + st;
                short8 b;
                b = *(const short8*)&wih1p[(size_t)((tb) * 4 + c) * 512 + lane * 8];
                accr[st] = MFMA16(a0h, b, accr[st]);
                accr[st] = MFMA16(a0l, b, accr[st]);
                b = *(const short8*)&whh1p[(size_t)((tb) * 4 + c) * 512 + lane * 8];
                accr[st] = MFMA16(a1h, b, accr[st]);
                accr[st] = MFMA16(a1l, b, accr[st]);
                b = *(const short8*)&wih1p[(size_t)((8 + tb) * 4 + c) * 512 + lane * 8];
                accz[st] = MFMA16(a0h, b, accz[st]);
                accz[st] = MFMA16(a0l, b, accz[st]);
                b = *(const short8*)&whh1p[(size_t)((8 + tb) * 4 + c) * 512 + lane * 8];
                accz[st] = MFMA16(a1h, b, accz[st]);
                accz[st] = MFMA16(a1l, b, accz[st]);
                b = *(const short8*)&wih1p[(size_t)((16 + tb) * 4 + c) * 512 + lane * 8];
                accni[st] = MFMA16(a0h, b, accni[st]);
                accni[st] = MFMA16(a0l, b, accni[st]);
                b = *(const short8*)&whh1p[(size_t)((16 + tb) * 4 + c) * 512 + lane * 8];
                accnh[st] = MFMA16(a1h, b, accnh[st]);
                accnh[st] = MFMA16(a1l, b, accnh[st]);
            }
        }
        // h1_old
        #pragma unroll
        for (int st = 0; st < 2; st++) {
            int j = w * 32 + st * 16 + lm;
            #pragma unroll
            for (int rg = 0; rg < 4; rg++) {
                int off = (quad * 4 + rg) * 136 + j;
                hold[st][rg] = bf2f(hA[1][0][off]) + bf2f(hA[1][1][off]);
            }
        }
        // stage x for t+1 (readers are next step's L0, after B3)
        if (t + 1 < TSTEPS) {
            const float* src = seq + ((size_t)(t + 1) * NR + n0) * DDIM;
            for (int i = tid; i < 16 * DDIM; i += 256) {
                int m = i / DDIM, d = i % DDIM;
                float v = src[i];
                unsigned short hi = f2bf(v);
                xA[buf ^ 1][0][m * 40 + d] = hi;
                xA[buf ^ 1][1][m * 40 + d] = f2bf(v - bf2f(hi));
            }
        }
        __syncthreads();     // B3: h0/h1 reads + x-stage done
        #pragma unroll
        for (int st = 0; st < 2; st++) {
            int j = w * 32 + st * 16 + lm;
            #pragma unroll
            for (int rg = 0; rg < 4; rg++) {
                float r = sigm(accr[st][rg] + br1[st]);
                float z = sigm(accz[st][rg] + bz1[st]);
                float nc = tanhf(accni[st][rg] + bni1[st] + r * (accnh[st][rg] + bnh1[st]));
                float hnew = (1.f - z) * nc + z * hold[st][rg];
                int off = (quad * 4 + rg) * 136 + j;
                unsigned short hi = f2bf(hnew);
                hA[1][0][off] = hi;
                hA[1][1][off] = f2bf(hnew - bf2f(hi));
                if (t + 1 == TSTEPS)
                    xh[(size_t)(n0 + quad * 4 + rg) * HDIM + j] = hnew;
            }
        }
        // h1 writes ordered before next step's L1 reads by B1/B2 of step t+1
    }
}

// ---------------------------------------------------------------------------
// Phase B/C/D helper kernels (unchanged)
// ---------------------------------------------------------------------------
__global__ void den_kernel(const float* __restrict__ cm, const float* __restrict__ mv,
                           float* __restrict__ den)
{
    int c = blockIdx.x * 64 + (threadIdx.x & 63);
    int rg = threadIdx.x >> 6;
    float acc = 0.f;
    for (int n = rg; n < NR; n += 4) acc += cm[(size_t)n * CDIM + c] * mv[n];
    __shared__ float red[4][64];
    red[rg][threadIdx.x & 63] = acc;
    __syncthreads();
    if (rg == 0)
        den[c] = red[0][threadIdx.x] + red[1][threadIdx.x] + red[2][threadIdx.x] + red[3][threadIdx.x];
}

__global__ void s2ct_kernel(const float* __restrict__ cm, const float* __restrict__ mv,
                            const float* __restrict__ den, float* __restrict__ s2cT)
{
    int idx = blockIdx.x * 256 + threadIdx.x;
    int c = idx >> 12, n = idx & (NR - 1);
    float m = cm[(size_t)n * CDIM + c];
    s2cT[idx] = (m * mv[n]) / (den[c] * m + 1.f);
}

__global__ void row_norm(const float* __restrict__ a, float* __restrict__ out)
{
    int r = blockIdx.x;
    float acc = 0.f;
    for (int h = threadIdx.x; h < HDIM; h += 64) {
        float v = a[(size_t)r * HDIM + h];
        acc += v * v;
    }
    for (int o = 32; o > 0; o >>= 1) acc += __shfl_down(acc, o);
    if (threadIdx.x == 0) out[r] = sqrtf(acc);
}

__global__ void row_nonzero(const float* __restrict__ a, float* __restrict__ out)
{
    int r = blockIdx.x;
    float acc = 0.f;
    for (int h = threadIdx.x; h < HDIM; h += 64) acc += a[(size_t)r * HDIM + h];
    for (int o = 32; o > 0; o >>= 1) acc += __shfl_down(acc, o);
    if (threadIdx.x == 0) out[r] = (acc != 0.f) ? 1.f : 0.f;
}

__global__ __launch_bounds__(256) void cos_softmax_row(float* __restrict__ data, int N,
        const float* __restrict__ rn, const float* __restrict__ cn,
        const float* __restrict__ vmask)
{
    int row = blockIdx.x;
    float* d = data + (size_t)row * N;
    int tid = threadIdx.x;
    __shared__ float red[256];
    float rnv = rn ? rn[row] : 0.f;
    float mx = -INFINITY;
    for (int j = tid; j < N; j += 256) {
        float v = d[j];
        if (cn) v = v / fmaxf(rnv * cn[j], 1e-12f);
        if (vmask && vmask[j] == 0.f) v = -1e9f;
        d[j] = v;
        mx = fmaxf(mx, v);
    }
    red[tid] = mx; __syncthreads();
    for (int sdx = 128; sdx > 0; sdx >>= 1) {
        if (tid < sdx) red[tid] = fmaxf(red[tid], red[tid + sdx]);
        __syncthreads();
    }
    float M = red[0]; __syncthreads();
    float sum = 0.f;
    for (int j = tid; j < N; j += 256) {
        float e = expf(d[j] - M);
        d[j] = e;
        sum += e;
    }
    red[tid] = sum; __syncthreads();
    for (int sdx = 128; sdx > 0; sdx >>= 1) {
        if (tid < sdx) red[tid] += red[tid + sdx];
        __syncthreads();
    }
    float inv = 1.f / red[0];
    for (int j = tid; j < N; j += 256) {
        float v = d[j] * inv;
        if (vmask) v *= vmask[j];
        d[j] = v;
    }
}

__global__ void hs2c_norm(float* __restrict__ S, const float* __restrict__ hn,
                          float* __restrict__ diag)
{
    int idx = blockIdx.x * 256 + threadIdx.x;
    int i = idx >> 12, j = idx & (NR - 1);
    float v = S[idx] / fmaxf(hn[i] * hn[j], 1e-12f);
    if (i == j) { diag[i] = v; v = 0.f; }
    S[idx] = v;
}

__global__ __launch_bounds__(256) void topk_kernel(const float* __restrict__ S,
        float* __restrict__ vals, int* __restrict__ idxs)
{
    int row = blockIdx.x;
    const float* d = S + (size_t)row * NR;
    int tid = threadIdx.x;
    float lv[16]; int li[16];
    #pragma unroll
    for (int i = 0; i < 16; i++) {
        int j = tid + i * 256;
        lv[i] = d[j];
        li[i] = j;
    }
    __shared__ float sv[256];
    __shared__ int si[256];
    for (int k = 0; k < KTOP; k++) {
        float bv = -INFINITY; int bi = 0x7fffffff;
        #pragma unroll
        for (int i = 0; i < 16; i++) {
            if (lv[i] > bv || (lv[i] == bv && li[i] < bi)) { bv = lv[i]; bi = li[i]; }
        }
        sv[tid] = bv; si[tid] = bi;
        __syncthreads();
        for (int sdx = 128; sdx > 0; sdx >>= 1) {
            if (tid < sdx) {
                if (sv[tid + sdx] > sv[tid] || (sv[tid + sdx] == sv[tid] && si[tid + sdx] < si[tid])) {
                    sv[tid] = sv[tid + sdx]; si[tid] = si[tid + sdx];
                }
            }
            __syncthreads();
        }
        if (tid == 0) { vals[row * KTOP + k] = sv[0]; idxs[row * KTOP + k] = si[0]; }
        int w = si[0];
        if ((w & 255) == tid) lv[w >> 8] = -INFINITY;
        __syncthreads();
    }
}

__global__ void colsum_scatter(const float* __restrict__ vals, const int* __restrict__ idxs,
                               float* __restrict__ colsum)
{
    int idx = blockIdx.x * 256 + threadIdx.x;
    if (idx < NR * KTOP) atomicAdd(&colsum[idxs[idx]], vals[idx]);
}

__global__ void hh_scatter(const float* __restrict__ vals, const int* __restrict__ idxs,
                           const float* __restrict__ hsh, float* __restrict__ hh)
{
    int p = blockIdx.x;
    int j = idxs[p];
    float v = vals[p];
    int i = p / KTOP;
    atomicAdd(&hh[(size_t)j * HDIM + threadIdx.x], v * hsh[(size_t)i * HDIM + threadIdx.x]);
}

__global__ void hh_diag(const float* __restrict__ colsum, const float* __restrict__ diag,
                        const float* __restrict__ hsh, float* __restrict__ hh)
{
    int idx = blockIdx.x * 256 + threadIdx.x;
    int j = idx >> 7;
    if (colsum[j] != 0.f) hh[idx] += diag[j] * hsh[idx];
}

__global__ void sub2_kernel(const float* __restrict__ a, const float* __restrict__ b,
                            float* __restrict__ o)
{
    int i = blockIdx.x * 256 + threadIdx.x;
    o[i] = a[i] - b[i];
}

__global__ void sub3_kernel(const float* __restrict__ a, const float* __restrict__ b,
                            const float* __restrict__ c, float* __restrict__ o)
{
    int i = blockIdx.x * 256 + threadIdx.x;
    o[i] = a[i] - b[i] - c[i];
}

__global__ void head_kernel(const float* __restrict__ ps, const float* __restrict__ hs,
                            const float* __restrict__ indi, const float* __restrict__ w,
                            const float* __restrict__ b, float* __restrict__ out)
{
    int n = blockIdx.x;
    int t = threadIdx.x;
    float acc = 0.f;
    for (int h = t; h < HDIM; h += 64) {
        size_t k = (size_t)n * HDIM + h;
        acc += (ps[k] + hs[k] + indi[k]) * w[h];
    }
    for (int o = 32; o > 0; o >>= 1) acc += __shfl_down(acc, o);
    if (t == 0) out[n] = acc + b[0];
}

static inline void launch_gemm(hipStream_t s, const float* A, const float* B,
                               const float* bias, float* C, int M, int N, int K, int flags)
{
    GemmArgs g{A, B, bias, C, N, K, flags};
    gemm_multi<<<dim3(N / 64, M / 64, 1), 256, 0, s>>>(g, g);
}

extern "C" void kernel_launch(void* const* d_in, const int* in_sizes, int n_in,
                              void* d_out, int out_size, void* d_ws, size_t ws_size,
                              hipStream_t stream)
{
    (void)in_sizes; (void)n_in; (void)out_size; (void)ws_size;
    const float* x    = (const float*)d_in[0];
    const float* cm   = (const float*)d_in[1];
    const float* mv   = (const float*)d_in[2];
    const float* wih0 = (const float*)d_in[3];
    const float* whh0 = (const float*)d_in[4];
    const float* bih0 = (const float*)d_in[5];
    const float* bhh0 = (const float*)d_in[6];
    const float* wih1 = (const float*)d_in[7];
    const float* whh1 = (const float*)d_in[8];
    const float* bih1 = (const float*)d_in[9];
    const float* bhh1 = (const float*)d_in[10];
    const float* w_ps = (const float*)d_in[11];
    const float* b_ps = (const float*)d_in[12];
    const float* w_hs = (const float*)d_in[13];
    const float* b_hs = (const float*)d_in[14];
    const float* w_ps_fore = (const float*)d_in[15];
    const float* b_ps_fore = (const float*)d_in[16];
    const float* w_hs_fore = (const float*)d_in[17];
    const float* b_hs_fore = (const float*)d_in[18];
    const float* w_ps_back = (const float*)d_in[19];
    const float* b_ps_back = (const float*)d_in[20];
    const float* w_hs_back = (const float*)d_in[21];
    const float* b_hs_back = (const float*)d_in[22];
    const float* w_indi = (const float*)d_in[23];
    const float* b_indi = (const float*)d_in[24];
    const float* w_out  = (const float*)d_in[25];
    const float* b_out  = (const float*)d_in[26];
    float* out = (float*)d_out;

    // ---- workspace layout (floats) ----
    float* ws = (float*)d_ws;
    float* BIG = ws;                         // 16,777,216 (overlaid)
    float* h0 = ws + 16777216;               // 524288 (unused)
    float* h1 = h0 + 524288;                 // 524288 (= x_hidden)
    float* den = h1 + 524288;                // 512
    float* v1 = den + 512;                   // 512
    float* hidden = v1 + 512;                // 65536
    float* hidden2 = hidden + 65536;         // 65536
    float* xnorm = hidden2 + 65536;          // 4096
    float* h2n = xnorm + 4096;               // 512
    float* p0 = h2n + 512;                   // 524288
    float* p_shared = p0 + 524288;
    float* p_back = p_shared + 524288;
    float* out_ps = p_back + 524288;
    float* h_shared = out_ps + 524288;
    float* hn = h_shared + 524288;           // 4096
    float* diagv = hn + 4096;                // 4096
    float* colsum = diagv + 4096;            // 4096
    float* tvals = colsum + 4096;            // 40960
    int*   tidx = (int*)(tvals + 40960);     // 40960 ints
    float* hidden_h = (float*)(tidx + 40960);
    float* v2 = hidden_h + 524288;           // 4096
    float* hhn = v2 + 4096;                  // 4096
    float* hsi0 = hhn + 4096;                // 524288
    float* h_si = hsi0 + 524288;
    float* h_back = h_si + 524288;
    float* out_hs = h_back + 524288;
    float* indi = out_hs + 524288;
    float* out_indi = indi + 524288;
    // overlays inside BIG:
    float* seqt = BIG;                             // 5,242,880 (GRU phase)
    unsigned short* wih0p = (unsigned short*)(BIG + 5242880);   // 12288 sh
    unsigned short* whh0p = wih0p + 12288;         // 49152 sh
    unsigned short* wih1p = whh0p + 49152;         // 49152 sh
    unsigned short* whh1p = wih1p + 49152;         // 49152 sh
    float* s2cT = BIG;                       // 2,097,152 (concept phase)
    float* L    = BIG + 2097152;             // 2,097,152
    float* c2s  = BIG + 4194304;             // 2,097,152

    // ================= Phase A: MFMA 2-layer GRU =================
    seq_transpose<<<(TSTEPS * NR * DDIM) / 256, 256, 0, stream>>>(x, seqt);
    pack_wb<<<6, 256, 0, stream>>>(wih0, wih0p, DDIM, 1);
    pack_wb<<<24, 256, 0, stream>>>(whh0, whh0p, HDIM, 4);
    pack_wb<<<24, 256, 0, stream>>>(wih1, wih1p, HDIM, 4);
    pack_wb<<<24, 256, 0, stream>>>(whh1, whh1p, HDIM, 4);
    gru_mfma<<<NR / 16, 256, 0, stream>>>(seqt, wih0p, whh0p, wih1p, whh1p,
                                          bih0, bhh0, bih1, bhh1, h1);
    float* x_hidden = h1;

    // ================= Phase B: predefined-concept branch =================
    den_kernel<<<8, 256, 0, stream>>>(cm, mv, den);
    s2ct_kernel<<<(CDIM * NR) / 256, 256, 0, stream>>>(cm, mv, den, s2cT);
    launch_gemm(stream, s2cT, x_hidden, nullptr, hidden, CDIM, HDIM, NR, 0);
    row_nonzero<<<CDIM, 64, 0, stream>>>(hidden, v1);
    launch_gemm(stream, hidden, x_hidden, nullptr, L, CDIM, NR, HDIM, 1);
    cos_softmax_row<<<CDIM, 256, 0, stream>>>(L, NR, nullptr, nullptr, nullptr);
    launch_gemm(stream, L, x_hidden, nullptr, hidden2, CDIM, HDIM, NR, 0);
    row_norm<<<NR, 64, 0, stream>>>(x_hidden, xnorm);
    row_norm<<<CDIM, 64, 0, stream>>>(hidden2, h2n);
    launch_gemm(stream, x_hidden, hidden2, nullptr, c2s, NR, CDIM, HDIM, 1);
    cos_softmax_row<<<NR, 256, 0, stream>>>(c2s, CDIM, xnorm, h2n, v1);
    launch_gemm(stream, c2s, hidden2, nullptr, p0, NR, HDIM, CDIM, 0);
    launch_gemm(stream, p0, w_ps, b_ps, p_shared, NR, HDIM, HDIM, 1 | 2);
    launch_gemm(stream, p_shared, w_ps_back, b_ps_back, p_back, NR, HDIM, HDIM, 1 | 2);
    launch_gemm(stream, p_shared, w_ps_fore, b_ps_fore, out_ps, NR, HDIM, HDIM, 1 | 2 | 4);

    // ================= Phase C: hidden-concept branch =================
    sub2_kernel<<<2048, 256, 0, stream>>>(x_hidden, p_back, h_shared);
    row_norm<<<NR, 64, 0, stream>>>(h_shared, hn);
    launch_gemm(stream, h_shared, h_shared, nullptr, BIG, NR, NR, HDIM, 1);
    hs2c_norm<<<(NR * NR) / 256, 256, 0, stream>>>(BIG, hn, diagv);
    topk_kernel<<<NR, 256, 0, stream>>>(BIG, tvals, tidx);
    hipMemsetAsync(colsum, 0, NR * sizeof(float), stream);
    hipMemsetAsync(hidden_h, 0, 524288 * sizeof(float), stream);
    colsum_scatter<<<(NR * KTOP + 255) / 256, 256, 0, stream>>>(tvals, tidx, colsum);
    hh_scatter<<<NR * KTOP, HDIM, 0, stream>>>(tvals, tidx, h_shared, hidden_h);
    hh_diag<<<2048, 256, 0, stream>>>(colsum, diagv, h_shared, hidden_h);
    row_nonzero<<<NR, 64, 0, stream>>>(hidden_h, v2);
    row_norm<<<NR, 64, 0, stream>>>(hidden_h, hhn);
    launch_gemm(stream, h_shared, hidden_h, nullptr, BIG, NR, NR, HDIM, 1);
    cos_softmax_row<<<NR, 256, 0, stream>>>(BIG, NR, hn, hhn, v2);
    launch_gemm(stream, BIG, hidden_h, nullptr, hsi0, NR, HDIM, NR, 0);
    launch_gemm(stream, hsi0, w_hs, b_hs, h_si, NR, HDIM, HDIM, 1 | 2);
    launch_gemm(stream, h_si, w_hs_back, b_hs_back, h_back, NR, HDIM, HDIM, 1 | 2);
    launch_gemm(stream, h_si, w_hs_fore, b_hs_fore, out_hs, NR, HDIM, HDIM, 1 | 2 | 4);

    // ================= Phase D: individual branch + head =================
    sub3_kernel<<<2048, 256, 0, stream>>>(x_hidden, p_back, h_back, indi);
    launch_gemm(stream, indi, w_indi, b_indi, out_indi, NR, HDIM, HDIM, 1 | 2 | 4);
    head_kernel<<<NR, 64, 0, stream>>>(out_ps, out_hs, out_indi, w_out, b_out, out);
}

// Round 5
// 1904.198 us; speedup vs baseline: 3.9180x; 1.5699x over previous
//
#include <hip/hip_runtime.h>
#include <cstddef>

// Problem dims
#define NR 4096      // batch
#define CDIM 512     // concepts
#define HDIM 128     // hidden
#define TSTEPS 64
#define DDIM 20
#define KTOP 10

typedef __attribute__((ext_vector_type(8))) short short8;
typedef __attribute__((ext_vector_type(4))) float f32x4;

__device__ __forceinline__ unsigned short f2bf(float f) {
    union { float f; unsigned u; } x; x.f = f;
    unsigned r = (x.u + 0x7fffu + ((x.u >> 16) & 1u)) >> 16;
    return (unsigned short)r;
}
__device__ __forceinline__ float bf2f(unsigned short h) {
    union { unsigned u; float f; } x; x.u = ((unsigned)h) << 16;
    return x.f;
}
__device__ __forceinline__ float sigm(float v) { return 1.f / (1.f + expf(-v)); }

#define MFMA16(a, b, c) __builtin_amdgcn_mfma_f32_16x16x32_bf16(a, b, c, 0, 0, 0)

// ---------------------------------------------------------------------------
// Generic fp32 tiled GEMM: C[M,N] = A[M,K] @ op(B) (+bias)(+leaky_relu)
// flags: 1 = B is [N,K]; 2 = add bias[n]; 4 = leaky_relu(0.01)
// ---------------------------------------------------------------------------
struct GemmArgs {
    const float* A; const float* B; const float* bias; float* C;
    int N, K, flags;
};

__global__ __launch_bounds__(256) void gemm_multi(GemmArgs g0, GemmArgs g1)
{
    GemmArgs g = (blockIdx.z == 0) ? g0 : g1;
    const int tid = threadIdx.x;
    const int bm = blockIdx.y << 6, bn = blockIdx.x << 6;
    __shared__ float As[32][68];
    __shared__ float Bs[32][68];
    const int tx = tid & 15, ty = tid >> 4;
    const int lc = tid & 31, lr = tid >> 5;
    const int ln = tid & 63, lk = tid >> 6;
    const int K = g.K, N = g.N;
    float acc[4][4] = {};
    for (int k0 = 0; k0 < K; k0 += 32) {
        #pragma unroll
        for (int i = 0; i < 8; i++) {
            int row = lr + (i << 3);
            int k = k0 + lc;
            As[lc][row] = (k < K) ? g.A[(size_t)(bm + row) * K + k] : 0.f;
        }
        if (g.flags & 1) {
            #pragma unroll
            for (int i = 0; i < 8; i++) {
                int row = lr + (i << 3);
                int k = k0 + lc;
                Bs[lc][row] = (k < K) ? g.B[(size_t)(bn + row) * K + k] : 0.f;
            }
        } else {
            #pragma unroll
            for (int i = 0; i < 8; i++) {
                int kk = lk + (i << 2);
                int k = k0 + kk;
                Bs[kk][ln] = (k < K) ? g.B[(size_t)k * N + bn + ln] : 0.f;
            }
        }
        __syncthreads();
        #pragma unroll
        for (int kk = 0; kk < 32; kk++) {
            float a[4], b[4];
            #pragma unroll
            for (int i = 0; i < 4; i++) a[i] = As[kk][(ty << 2) + i];
            #pragma unroll
            for (int j = 0; j < 4; j++) b[j] = Bs[kk][(tx << 2) + j];
            #pragma unroll
            for (int i = 0; i < 4; i++)
                #pragma unroll
                for (int j = 0; j < 4; j++)
                    acc[i][j] += a[i] * b[j];
        }
        __syncthreads();
    }
    #pragma unroll
    for (int i = 0; i < 4; i++) {
        int m = bm + (ty << 2) + i;
        #pragma unroll
        for (int j = 0; j < 4; j++) {
            int n = bn + (tx << 2) + j;
            float v = acc[i][j];
            if (g.flags & 2) v += g.bias[n];
            if (g.flags & 4) v = v > 0.f ? v : 0.01f * v;
            g.C[(size_t)m * N + n] = v;
        }
    }
}

// ---------------------------------------------------------------------------
// Split-K GEMM, N fixed = 128: C[M,128] += A[M,K]@B[K,128], grid (M/64, K/chunk).
// C must be zeroed first; partial sums via atomicAdd. VALU-bound micro 4x8.
// ---------------------------------------------------------------------------
__global__ __launch_bounds__(256) void gemm_splitk(const float* __restrict__ A,
        const float* __restrict__ B, float* __restrict__ C, int K, int chunk)
{
    __shared__ float As[32][68];
    __shared__ float Bs[32][132];
    const int tid = threadIdx.x;
    const int bm = blockIdx.x << 6;
    const int k0 = blockIdx.y * chunk;
    const int ty = tid >> 4, tx = tid & 15;
    const int lc = tid & 31, lr = tid >> 5;
    float acc[4][8] = {};
    for (int kt = 0; kt < chunk; kt += 32) {
        #pragma unroll
        for (int i = 0; i < 8; i++)
            As[lc][lr + (i << 3)] = A[(size_t)(bm + lr + (i << 3)) * K + k0 + kt + lc];
        {
            int col = tid & 127, kr = tid >> 7;
            #pragma unroll
            for (int i = 0; i < 16; i++) {
                int kk = (kr << 4) + i;
                Bs[kk][col] = B[(size_t)(k0 + kt + kk) * 128 + col];
            }
        }
        __syncthreads();
        #pragma unroll
        for (int kk = 0; kk < 32; kk++) {
            float a[4], b[8];
            #pragma unroll
            for (int i = 0; i < 4; i++) a[i] = As[kk][(ty << 2) + i];
            #pragma unroll
            for (int j = 0; j < 8; j++) b[j] = Bs[kk][(tx << 3) + j];
            #pragma unroll
            for (int i = 0; i < 4; i++)
                #pragma unroll
                for (int j = 0; j < 8; j++)
                    acc[i][j] += a[i] * b[j];
        }
        __syncthreads();
    }
    #pragma unroll
    for (int i = 0; i < 4; i++)
        #pragma unroll
        for (int j = 0; j < 8; j++)
            atomicAdd(&C[(size_t)(bm + (ty << 2) + i) * 128 + (tx << 3) + j], acc[i][j]);
}

// ---------------------------------------------------------------------------
// Fused cosine-dots + diag-capture + zero-diag + exact streaming top-10.
// Block: 32 rows x 2048 cols (col-split cs = blockIdx.x in {0,1}); 32 tiles of
// 64 cols. Thread micro 2 rows x 4 cols. Per-thread sorted top-10 (tie ->
// lowest index, matching lax.top_k), shfl_xor butterfly merge across 16 lanes.
// ---------------------------------------------------------------------------
__device__ __forceinline__ void tk_insert(float v, int i, float (&lv)[10], int (&li)[10])
{
    #pragma unroll
    for (int k = 0; k < 10; k++) {
        bool beat = (v > lv[k]) || (v == lv[k] && i < li[k]);
        float tv = lv[k]; int ti = li[k];
        if (beat) { lv[k] = v; li[k] = i; v = tv; i = ti; }
    }
}

__global__ __launch_bounds__(256) void dots_topk(
    const float* __restrict__ hsh, const float* __restrict__ hn,
    float* __restrict__ diagv, float* __restrict__ pv, int* __restrict__ pi)
{
    __shared__ float As[128][36];
    __shared__ float Bs[128][68];
    const int tid = threadIdx.x;
    const int cs = blockIdx.x;            // col split
    const int bm = blockIdx.y << 5;       // 32 rows
    const int ty = tid >> 4, tx = tid & 15;
    // stage As[k][r] once (transposed 32x128 row block)
    #pragma unroll
    for (int p = 0; p < 4; p++) {
        int idx = p * 256 + tid;          // 1024 float4s
        int r = idx >> 5, k4 = idx & 31;
        float4 vq = *(const float4*)&hsh[(size_t)(bm + r) * HDIM + (k4 << 2)];
        As[(k4 << 2) + 0][r] = vq.x; As[(k4 << 2) + 1][r] = vq.y;
        As[(k4 << 2) + 2][r] = vq.z; As[(k4 << 2) + 3][r] = vq.w;
    }
    float hnr[2];
    hnr[0] = hn[bm + (ty << 1)];
    hnr[1] = hn[bm + (ty << 1) + 1];
    float lv[2][10]; int li[2][10];
    #pragma unroll
    for (int r = 0; r < 2; r++)
        #pragma unroll
        for (int k = 0; k < 10; k++) { lv[r][k] = -INFINITY; li[r][k] = 0x7fffffff; }

    for (int tile = 0; tile < 32; tile++) {
        int jb = (cs << 11) + (tile << 6);
        __syncthreads();                  // prev tile's Bs reads done (covers As stage on tile 0)
        #pragma unroll
        for (int p = 0; p < 8; p++) {
            int idx = p * 256 + tid;      // 2048 float4s
            int j = idx >> 5, k4 = idx & 31;
            float4 vq = *(const float4*)&hsh[(size_t)(jb + j) * HDIM + (k4 << 2)];
            Bs[(k4 << 2) + 0][j] = vq.x; Bs[(k4 << 2) + 1][j] = vq.y;
            Bs[(k4 << 2) + 2][j] = vq.z; Bs[(k4 << 2) + 3][j] = vq.w;
        }
        __syncthreads();
        float acc[2][4] = {};
        #pragma unroll 4
        for (int kk = 0; kk < 128; kk++) {
            float2 a = *(const float2*)&As[kk][ty << 1];
            float4 b = *(const float4*)&Bs[kk][tx << 2];
            acc[0][0] += a.x * b.x; acc[0][1] += a.x * b.y;
            acc[0][2] += a.x * b.z; acc[0][3] += a.x * b.w;
            acc[1][0] += a.y * b.x; acc[1][1] += a.y * b.y;
            acc[1][2] += a.y * b.z; acc[1][3] += a.y * b.w;
        }
        #pragma unroll
        for (int c = 0; c < 4; c++) {
            int gc = jb + (tx << 2) + c;
            float hc = hn[gc];
            #pragma unroll
            for (int r = 0; r < 2; r++) {
                int gr = bm + (ty << 1) + r;
                float v = acc[r][c] / fmaxf(hnr[r] * hc, 1e-12f);
                if (gc == gr) { diagv[gr] = v; v = 0.f; }
                tk_insert(v, gc, lv[r], li[r]);
            }
        }
    }
    // butterfly merge across the 16 tx lanes
    #pragma unroll
    for (int m = 1; m < 16; m <<= 1) {
        #pragma unroll
        for (int r = 0; r < 2; r++) {
            float ov[10]; int oi[10];
            #pragma unroll
            for (int k = 0; k < 10; k++) {
                ov[k] = __shfl_xor(lv[r][k], m);
                oi[k] = __shfl_xor(li[r][k], m);
            }
            #pragma unroll
            for (int k = 0; k < 10; k++) tk_insert(ov[k], oi[k], lv[r], li[r]);
        }
    }
    if (tx == 0) {
        #pragma unroll
        for (int r = 0; r < 2; r++) {
            int gr = bm + (ty << 1) + r;
            size_t base = ((size_t)cs * NR + gr) * KTOP;
            #pragma unroll
            for (int k = 0; k < 10; k++) { pv[base + k] = lv[r][k]; pi[base + k] = li[r][k]; }
        }
    }
}

__global__ void topk_merge(const float* __restrict__ pv, const int* __restrict__ pi,
                           float* __restrict__ tvals, int* __restrict__ tidx)
{
    int row = blockIdx.x * 256 + threadIdx.x;   // 4096
    float lv[10]; int li[10];
    size_t b0 = (size_t)row * KTOP;
    #pragma unroll
    for (int k = 0; k < 10; k++) { lv[k] = pv[b0 + k]; li[k] = pi[b0 + k]; }
    size_t b1 = ((size_t)NR + row) * KTOP;
    #pragma unroll
    for (int k = 0; k < 10; k++) tk_insert(pv[b1 + k], pi[b1 + k], lv, li);
    #pragma unroll
    for (int k = 0; k < 10; k++) { tvals[b0 + k] = lv[k]; tidx[b0 + k] = li[k]; }
}

// ---------------------------------------------------------------------------
// Weight pack for GRU MFMA (B-fragment linear layout)
// ---------------------------------------------------------------------------
__global__ void pack_wb(const float* __restrict__ W, unsigned short* __restrict__ Wp,
                        int K, int nch)
{
    int idx = blockIdx.x * 256 + threadIdx.x;   // 24*nch*64
    if (idx >= 24 * nch * 64) return;
    int lane = idx & 63;
    int c = (idx >> 6) % nch;
    int t = idx / (nch * 64);
    int n = t * 16 + (lane & 15);
    int kb = c * 32 + (lane >> 4) * 8;
    #pragma unroll
    for (int j = 0; j < 8; j++) {
        int k = kb + j;
        float f = (k < K) ? W[(size_t)n * K + k] : 0.f;
        Wp[(size_t)idx * 8 + j] = f2bf(f);
    }
}

// x [N, D*T] -> seq [T, N, D]
__global__ void seq_transpose(const float* __restrict__ x, float* __restrict__ seq)
{
    int idx = blockIdx.x * 256 + threadIdx.x;
    int d = idx % DDIM;
    int r = idx / DDIM;
    int n = r & (NR - 1);
    int t = r >> 12;
    seq[idx] = x[(size_t)n * (DDIM * TSTEPS) + d * TSTEPS + t];
}

// ---------------------------------------------------------------------------
// MFMA 2-layer GRU (unchanged from round 4)
// ---------------------------------------------------------------------------
__global__ __launch_bounds__(256) void gru_mfma(
    const float* __restrict__ seq,
    const unsigned short* __restrict__ wih0p,
    const unsigned short* __restrict__ whh0p,
    const unsigned short* __restrict__ wih1p,
    const unsigned short* __restrict__ whh1p,
    const float* __restrict__ bih0, const float* __restrict__ bhh0,
    const float* __restrict__ bih1, const float* __restrict__ bhh1,
    float* __restrict__ xh)
{
    __shared__ __attribute__((aligned(16))) unsigned short hA[2][2][16 * 136];
    __shared__ __attribute__((aligned(16))) unsigned short xA[2][2][16 * 40];

    const int tid = threadIdx.x;
    const int w = tid >> 6;
    const int lane = tid & 63;
    const int quad = lane >> 4;
    const int lm = lane & 15;
    const int n0 = blockIdx.x << 4;

    for (int i = tid; i < 2 * 2 * 16 * 136; i += 256) ((unsigned short*)hA)[i] = 0;
    for (int i = tid; i < 2 * 2 * 16 * 40; i += 256) ((unsigned short*)xA)[i] = 0;

    float br0[2], bz0[2], bni0[2], bnh0[2], br1[2], bz1[2], bni1[2], bnh1[2];
    #pragma unroll
    for (int st = 0; st < 2; st++) {
        int j = w * 32 + st * 16 + lm;
        br0[st]  = bih0[j] + bhh0[j];
        bz0[st]  = bih0[128 + j] + bhh0[128 + j];
        bni0[st] = bih0[256 + j];
        bnh0[st] = bhh0[256 + j];
        br1[st]  = bih1[j] + bhh1[j];
        bz1[st]  = bih1[128 + j] + bhh1[128 + j];
        bni1[st] = bih1[256 + j];
        bnh1[st] = bhh1[256 + j];
    }

    const int aoff = lm * 136 + quad * 8;
    const int xoff = lm * 40 + quad * 8;

    {
        const float* src = seq + (size_t)n0 * DDIM;
        for (int i = tid; i < 16 * DDIM; i += 256) {
            int m = i / DDIM, d = i % DDIM;
            float v = src[i];
            unsigned short hi = f2bf(v);
            xA[0][0][m * 40 + d] = hi;
            xA[0][1][m * 40 + d] = f2bf(v - bf2f(hi));
        }
    }
    __syncthreads();

    for (int t = 0; t < TSTEPS; t++) {
        const int buf = t & 1;
        f32x4 accr[2], accz[2], accni[2], accnh[2];
        #pragma unroll
        for (int st = 0; st < 2; st++) {
            accr[st] = (f32x4){0.f, 0.f, 0.f, 0.f};
            accz[st] = (f32x4){0.f, 0.f, 0.f, 0.f};
            accni[st] = (f32x4){0.f, 0.f, 0.f, 0.f};
            accnh[st] = (f32x4){0.f, 0.f, 0.f, 0.f};
        }

        // layer 0
        {
            short8 axh = *(const short8*)&xA[buf][0][xoff];
            short8 axl = *(const short8*)&xA[buf][1][xoff];
            #pragma unroll
            for (int st = 0; st < 2; st++) {
                int tb = w * 2 + st;
                short8 b;
                b = *(const short8*)&wih0p[(size_t)(tb) * 512 + lane * 8];
                accr[st] = MFMA16(axh, b, accr[st]);
                accr[st] = MFMA16(axl, b, accr[st]);
                b = *(const short8*)&wih0p[(size_t)(8 + tb) * 512 + lane * 8];
                accz[st] = MFMA16(axh, b, accz[st]);
                accz[st] = MFMA16(axl, b, accz[st]);
                b = *(const short8*)&wih0p[(size_t)(16 + tb) * 512 + lane * 8];
                accni[st] = MFMA16(axh, b, accni[st]);
                accni[st] = MFMA16(axl, b, accni[st]);
            }
        }
        #pragma unroll
        for (int c = 0; c < 4; c++) {
            short8 ahh = *(const short8*)&hA[0][0][aoff + c * 32];
            short8 ahl = *(const short8*)&hA[0][1][aoff + c * 32];
            #pragma unroll
            for (int st = 0; st < 2; st++) {
                int tb = w * 2 + st;
                short8 b;
                b = *(const short8*)&whh0p[(size_t)((tb) * 4 + c) * 512 + lane * 8];
                accr[st] = MFMA16(ahh, b, accr[st]);
                accr[st] = MFMA16(ahl, b, accr[st]);
                b = *(const short8*)&whh0p[(size_t)((8 + tb) * 4 + c) * 512 + lane * 8];
                accz[st] = MFMA16(ahh, b, accz[st]);
                accz[st] = MFMA16(ahl, b, accz[st]);
                b = *(const short8*)&whh0p[(size_t)((16 + tb) * 4 + c) * 512 + lane * 8];
                accnh[st] = MFMA16(ahh, b, accnh[st]);
                accnh[st] = MFMA16(ahl, b, accnh[st]);
            }
        }
        float hold[2][4];
        #pragma unroll
        for (int st = 0; st < 2; st++) {
            int j = w * 32 + st * 16 + lm;
            #pragma unroll
            for (int rg = 0; rg < 4; rg++) {
                int off = (quad * 4 + rg) * 136 + j;
                hold[st][rg] = bf2f(hA[0][0][off]) + bf2f(hA[0][1][off]);
            }
        }
        __syncthreads();
        #pragma unroll
        for (int st = 0; st < 2; st++) {
            int j = w * 32 + st * 16 + lm;
            #pragma unroll
            for (int rg = 0; rg < 4; rg++) {
                float r = sigm(accr[st][rg] + br0[st]);
                float z = sigm(accz[st][rg] + bz0[st]);
                float nc = tanhf(accni[st][rg] + bni0[st] + r * (accnh[st][rg] + bnh0[st]));
                float hnew = (1.f - z) * nc + z * hold[st][rg];
                int off = (quad * 4 + rg) * 136 + j;
                unsigned short hi = f2bf(hnew);
                hA[0][0][off] = hi;
                hA[0][1][off] = f2bf(hnew - bf2f(hi));
            }
        }
        __syncthreads();

        // layer 1
        #pragma unroll
        for (int st = 0; st < 2; st++) {
            accr[st] = (f32x4){0.f, 0.f, 0.f, 0.f};
            accz[st] = (f32x4){0.f, 0.f, 0.f, 0.f};
            accni[st] = (f32x4){0.f, 0.f, 0.f, 0.f};
            accnh[st] = (f32x4){0.f, 0.f, 0.f, 0.f};
        }
        #pragma unroll
        for (int c = 0; c < 4; c++) {
            short8 a0h = *(const short8*)&hA[0][0][aoff + c * 32];
            short8 a0l = *(const short8*)&hA[0][1][aoff + c * 32];
            short8 a1h = *(const short8*)&hA[1][0][aoff + c * 32];
            short8 a1l = *(const short8*)&hA[1][1][aoff + c * 32];
            #pragma unroll
            for (int st = 0; st < 2; st++) {
                int tb = w * 2 + st;
                short8 b;
                b = *(const short8*)&wih1p[(size_t)((tb) * 4 + c) * 512 + lane * 8];
                accr[st] = MFMA16(a0h, b, accr[st]);
                accr[st] = MFMA16(a0l, b, accr[st]);
                b = *(const short8*)&whh1p[(size_t)((tb) * 4 + c) * 512 + lane * 8];
                accr[st] = MFMA16(a1h, b, accr[st]);
                accr[st] = MFMA16(a1l, b, accr[st]);
                b = *(const short8*)&wih1p[(size_t)((8 + tb) * 4 + c) * 512 + lane * 8];
                accz[st] = MFMA16(a0h, b, accz[st]);
                accz[st] = MFMA16(a0l, b, accz[st]);
                b = *(const short8*)&whh1p[(size_t)((8 + tb) * 4 + c) * 512 + lane * 8];
                accz[st] = MFMA16(a1h, b, accz[st]);
                accz[st] = MFMA16(a1l, b, accz[st]);
                b = *(const short8*)&wih1p[(size_t)((16 + tb) * 4 + c) * 512 + lane * 8];
                accni[st] = MFMA16(a0h, b, accni[st]);
                accni[st] = MFMA16(a0l, b, accni[st]);
                b = *(const short8*)&whh1p[(size_t)((16 + tb) * 4 + c) * 512 + lane * 8];
                accnh[st] = MFMA16(a1h, b, accnh[st]);
                accnh[st] = MFMA16(a1l, b, accnh[st]);
            }
        }
        #pragma unroll
        for (int st = 0; st < 2; st++) {
            int j = w * 32 + st * 16 + lm;
            #pragma unroll
            for (int rg = 0; rg < 4; rg++) {
                int off = (quad * 4 + rg) * 136 + j;
                hold[st][rg] = bf2f(hA[1][0][off]) + bf2f(hA[1][1][off]);
            }
        }
        if (t + 1 < TSTEPS) {
            const float* src = seq + ((size_t)(t + 1) * NR + n0) * DDIM;
            for (int i = tid; i < 16 * DDIM; i += 256) {
                int m = i / DDIM, d = i % DDIM;
                float v = src[i];
                unsigned short hi = f2bf(v);
                xA[buf ^ 1][0][m * 40 + d] = hi;
                xA[buf ^ 1][1][m * 40 + d] = f2bf(v - bf2f(hi));
            }
        }
        __syncthreads();
        #pragma unroll
        for (int st = 0; st < 2; st++) {
            int j = w * 32 + st * 16 + lm;
            #pragma unroll
            for (int rg = 0; rg < 4; rg++) {
                float r = sigm(accr[st][rg] + br1[st]);
                float z = sigm(accz[st][rg] + bz1[st]);
                float nc = tanhf(accni[st][rg] + bni1[st] + r * (accnh[st][rg] + bnh1[st]));
                float hnew = (1.f - z) * nc + z * hold[st][rg];
                int off = (quad * 4 + rg) * 136 + j;
                unsigned short hi = f2bf(hnew);
                hA[1][0][off] = hi;
                hA[1][1][off] = f2bf(hnew - bf2f(hi));
                if (t + 1 == TSTEPS)
                    xh[(size_t)(n0 + quad * 4 + rg) * HDIM + j] = hnew;
            }
        }
    }
}

// ---------------------------------------------------------------------------
// Phase B/C/D helpers
// ---------------------------------------------------------------------------
__global__ void den_kernel(const float* __restrict__ cm, const float* __restrict__ mv,
                           float* __restrict__ den)
{
    int c = blockIdx.x * 64 + (threadIdx.x & 63);
    int rg = threadIdx.x >> 6;
    float acc = 0.f;
    for (int n = rg; n < NR; n += 4) acc += cm[(size_t)n * CDIM + c] * mv[n];
    __shared__ float red[4][64];
    red[rg][threadIdx.x & 63] = acc;
    __syncthreads();
    if (rg == 0)
        den[c] = red[0][threadIdx.x] + red[1][threadIdx.x] + red[2][threadIdx.x] + red[3][threadIdx.x];
}

__global__ void s2ct_kernel(const float* __restrict__ cm, const float* __restrict__ mv,
                            const float* __restrict__ den, float* __restrict__ s2cT)
{
    int idx = blockIdx.x * 256 + threadIdx.x;
    int c = idx >> 12, n = idx & (NR - 1);
    float m = cm[(size_t)n * CDIM + c];
    s2cT[idx] = (m * mv[n]) / (den[c] * m + 1.f);
}

__global__ void row_norm(const float* __restrict__ a, float* __restrict__ out)
{
    int r = blockIdx.x;
    float acc = 0.f;
    for (int h = threadIdx.x; h < HDIM; h += 64) {
        float v = a[(size_t)r * HDIM + h];
        acc += v * v;
    }
    for (int o = 32; o > 0; o >>= 1) acc += __shfl_down(acc, o);
    if (threadIdx.x == 0) out[r] = sqrtf(acc);
}

__global__ void row_nonzero(const float* __restrict__ a, float* __restrict__ out)
{
    int r = blockIdx.x;
    float acc = 0.f;
    for (int h = threadIdx.x; h < HDIM; h += 64) acc += a[(size_t)r * HDIM + h];
    for (int o = 32; o > 0; o >>= 1) acc += __shfl_down(acc, o);
    if (threadIdx.x == 0) out[r] = (acc != 0.f) ? 1.f : 0.f;
}

__global__ __launch_bounds__(256) void cos_softmax_row(float* __restrict__ data, int N,
        const float* __restrict__ rn, const float* __restrict__ cn,
        const float* __restrict__ vmask)
{
    int row = blockIdx.x;
    float* d = data + (size_t)row * N;
    int tid = threadIdx.x;
    __shared__ float red[256];
    float rnv = rn ? rn[row] : 0.f;
    float mx = -INFINITY;
    for (int j = tid; j < N; j += 256) {
        float v = d[j];
        if (cn) v = v / fmaxf(rnv * cn[j], 1e-12f);
        if (vmask && vmask[j] == 0.f) v = -1e9f;
        d[j] = v;
        mx = fmaxf(mx, v);
    }
    red[tid] = mx; __syncthreads();
    for (int sdx = 128; sdx > 0; sdx >>= 1) {
        if (tid < sdx) red[tid] = fmaxf(red[tid], red[tid + sdx]);
        __syncthreads();
    }
    float M = red[0]; __syncthreads();
    float sum = 0.f;
    for (int j = tid; j < N; j += 256) {
        float e = expf(d[j] - M);
        d[j] = e;
        sum += e;
    }
    red[tid] = sum; __syncthreads();
    for (int sdx = 128; sdx > 0; sdx >>= 1) {
        if (tid < sdx) red[tid] += red[tid + sdx];
        __syncthreads();
    }
    float inv = 1.f / red[0];
    for (int j = tid; j < N; j += 256) {
        float v = d[j] * inv;
        if (vmask) v *= vmask[j];
        d[j] = v;
    }
}

__global__ void colsum_scatter(const float* __restrict__ vals, const int* __restrict__ idxs,
                               float* __restrict__ colsum)
{
    int idx = blockIdx.x * 256 + threadIdx.x;
    if (idx < NR * KTOP) atomicAdd(&colsum[idxs[idx]], vals[idx]);
}

__global__ void hh_scatter(const float* __restrict__ vals, const int* __restrict__ idxs,
                           const float* __restrict__ hsh, float* __restrict__ hh)
{
    int p = blockIdx.x;
    int j = idxs[p];
    float v = vals[p];
    int i = p / KTOP;
    atomicAdd(&hh[(size_t)j * HDIM + threadIdx.x], v * hsh[(size_t)i * HDIM + threadIdx.x]);
}

__global__ void hh_diag(const float* __restrict__ colsum, const float* __restrict__ diag,
                        const float* __restrict__ hsh, float* __restrict__ hh)
{
    int idx = blockIdx.x * 256 + threadIdx.x;
    int j = idx >> 7;
    if (colsum[j] != 0.f) hh[idx] += diag[j] * hsh[idx];
}

__global__ void sub2_kernel(const float* __restrict__ a, const float* __restrict__ b,
                            float* __restrict__ o)
{
    int i = blockIdx.x * 256 + threadIdx.x;
    o[i] = a[i] - b[i];
}

__global__ void sub3_kernel(const float* __restrict__ a, const float* __restrict__ b,
                            const float* __restrict__ c, float* __restrict__ o)
{
    int i = blockIdx.x * 256 + threadIdx.x;
    o[i] = a[i] - b[i] - c[i];
}

__global__ void head_kernel(const float* __restrict__ ps, const float* __restrict__ hs,
                            const float* __restrict__ indi, const float* __restrict__ w,
                            const float* __restrict__ b, float* __restrict__ out)
{
    int n = blockIdx.x;
    int t = threadIdx.x;
    float acc = 0.f;
    for (int h = t; h < HDIM; h += 64) {
        size_t k = (size_t)n * HDIM + h;
        acc += (ps[k] + hs[k] + indi[k]) * w[h];
    }
    for (int o = 32; o > 0; o >>= 1) acc += __shfl_down(acc, o);
    if (t == 0) out[n] = acc + b[0];
}

static inline void launch_gemm(hipStream_t s, const float* A, const float* B,
                               const float* bias, float* C, int M, int N, int K, int flags)
{
    GemmArgs g{A, B, bias, C, N, K, flags};
    gemm_multi<<<dim3(N / 64, M / 64, 1), 256, 0, s>>>(g, g);
}

static inline void launch_gemm2(hipStream_t s, GemmArgs g0, GemmArgs g1, int M, int N)
{
    gemm_multi<<<dim3(N / 64, M / 64, 2), 256, 0, s>>>(g0, g1);
}

extern "C" void kernel_launch(void* const* d_in, const int* in_sizes, int n_in,
                              void* d_out, int out_size, void* d_ws, size_t ws_size,
                              hipStream_t stream)
{
    (void)in_sizes; (void)n_in; (void)out_size; (void)ws_size;
    const float* x    = (const float*)d_in[0];
    const float* cm   = (const float*)d_in[1];
    const float* mv   = (const float*)d_in[2];
    const float* wih0 = (const float*)d_in[3];
    const float* whh0 = (const float*)d_in[4];
    const float* bih0 = (const float*)d_in[5];
    const float* bhh0 = (const float*)d_in[6];
    const float* wih1 = (const float*)d_in[7];
    const float* whh1 = (const float*)d_in[8];
    const float* bih1 = (const float*)d_in[9];
    const float* bhh1 = (const float*)d_in[10];
    const float* w_ps = (const float*)d_in[11];
    const float* b_ps = (const float*)d_in[12];
    const float* w_hs = (const float*)d_in[13];
    const float* b_hs = (const float*)d_in[14];
    const float* w_ps_fore = (const float*)d_in[15];
    const float* b_ps_fore = (const float*)d_in[16];
    const float* w_hs_fore = (const float*)d_in[17];
    const float* b_hs_fore = (const float*)d_in[18];
    const float* w_ps_back = (const float*)d_in[19];
    const float* b_ps_back = (const float*)d_in[20];
    const float* w_hs_back = (const float*)d_in[21];
    const float* b_hs_back = (const float*)d_in[22];
    const float* w_indi = (const float*)d_in[23];
    const float* b_indi = (const float*)d_in[24];
    const float* w_out  = (const float*)d_in[25];
    const float* b_out  = (const float*)d_in[26];
    float* out = (float*)d_out;

    // ---- workspace layout (floats) ----
    float* ws = (float*)d_ws;
    float* BIG = ws;                         // 16,777,216 (overlaid)
    float* h0 = ws + 16777216;               // 524288 (unused)
    float* h1 = h0 + 524288;                 // 524288 (= x_hidden)
    float* den = h1 + 524288;                // 512
    float* v1 = den + 512;                   // 512
    float* hidden = v1 + 512;                // 65536
    float* hidden2 = hidden + 65536;         // 65536
    float* xnorm = hidden2 + 65536;          // 4096
    float* h2n = xnorm + 4096;               // 512
    float* p0 = h2n + 512;                   // 524288
    float* p_shared = p0 + 524288;
    float* p_back = p_shared + 524288;
    float* out_ps = p_back + 524288;
    float* h_shared = out_ps + 524288;
    float* hn = h_shared + 524288;           // 4096
    float* diagv = hn + 4096;                // 4096
    float* colsum = diagv + 4096;            // 4096
    float* tvals = colsum + 4096;            // 40960
    int*   tidx = (int*)(tvals + 40960);     // 40960 ints
    float* hidden_h = (float*)(tidx + 40960);
    float* v2 = hidden_h + 524288;           // 4096
    float* hhn = v2 + 4096;                  // 4096
    float* hsi0 = hhn + 4096;                // 524288
    float* h_si = hsi0 + 524288;
    float* h_back = h_si + 524288;
    float* out_hs = h_back + 524288;
    float* indi = out_hs + 524288;
    float* out_indi = indi + 524288;
    // overlays inside BIG:
    float* seqt = BIG;                             // GRU phase
    unsigned short* wih0p = (unsigned short*)(BIG + 5242880);
    unsigned short* whh0p = wih0p + 12288;
    unsigned short* wih1p = whh0p + 49152;
    unsigned short* whh1p = wih1p + 49152;
    float* s2cT = BIG;                       // concept phase
    float* L    = BIG + 2097152;
    float* c2s  = BIG + 4194304;
    // topk partials overlay p0 (dead after p_shared is computed)
    float* pv = p0;                          // 2*4096*10 = 81920
    int*   pi = (int*)(p0 + 81920);          // 81920

    // ================= Phase A: MFMA 2-layer GRU =================
    seq_transpose<<<(TSTEPS * NR * DDIM) / 256, 256, 0, stream>>>(x, seqt);
    pack_wb<<<6, 256, 0, stream>>>(wih0, wih0p, DDIM, 1);
    pack_wb<<<24, 256, 0, stream>>>(whh0, whh0p, HDIM, 4);
    pack_wb<<<24, 256, 0, stream>>>(wih1, wih1p, HDIM, 4);
    pack_wb<<<24, 256, 0, stream>>>(whh1, whh1p, HDIM, 4);
    gru_mfma<<<NR / 16, 256, 0, stream>>>(seqt, wih0p, whh0p, wih1p, whh1p,
                                          bih0, bhh0, bih1, bhh1, h1);
    float* x_hidden = h1;

    // ================= Phase B: predefined-concept branch =================
    den_kernel<<<8, 256, 0, stream>>>(cm, mv, den);
    s2ct_kernel<<<(CDIM * NR) / 256, 256, 0, stream>>>(cm, mv, den, s2cT);
    hipMemsetAsync(hidden, 0, 65536 * sizeof(float), stream);
    gemm_splitk<<<dim3(CDIM / 64, 32), 256, 0, stream>>>(s2cT, x_hidden, hidden, NR, 128);
    row_nonzero<<<CDIM, 64, 0, stream>>>(hidden, v1);
    launch_gemm(stream, hidden, x_hidden, nullptr, L, CDIM, NR, HDIM, 1);
    cos_softmax_row<<<CDIM, 256, 0, stream>>>(L, NR, nullptr, nullptr, nullptr);
    hipMemsetAsync(hidden2, 0, 65536 * sizeof(float), stream);
    gemm_splitk<<<dim3(CDIM / 64, 32), 256, 0, stream>>>(L, x_hidden, hidden2, NR, 128);
    row_norm<<<NR, 64, 0, stream>>>(x_hidden, xnorm);
    row_norm<<<CDIM, 64, 0, stream>>>(hidden2, h2n);
    launch_gemm(stream, x_hidden, hidden2, nullptr, c2s, NR, CDIM, HDIM, 1);
    cos_softmax_row<<<NR, 256, 0, stream>>>(c2s, CDIM, xnorm, h2n, v1);
    hipMemsetAsync(p0, 0, 524288 * sizeof(float), stream);
    gemm_splitk<<<dim3(NR / 64, 4), 256, 0, stream>>>(c2s, hidden2, p0, CDIM, 128);
    launch_gemm(stream, p0, w_ps, b_ps, p_shared, NR, HDIM, HDIM, 1 | 2);
    {
        GemmArgs gb{p_shared, w_ps_back, b_ps_back, p_back, HDIM, HDIM, 1 | 2};
        GemmArgs gf{p_shared, w_ps_fore, b_ps_fore, out_ps, HDIM, HDIM, 1 | 2 | 4};
        launch_gemm2(stream, gb, gf, NR, HDIM);
    }

    // ================= Phase C: hidden-concept branch =================
    sub2_kernel<<<2048, 256, 0, stream>>>(x_hidden, p_back, h_shared);
    row_norm<<<NR, 64, 0, stream>>>(h_shared, hn);
    dots_topk<<<dim3(2, NR / 32), 256, 0, stream>>>(h_shared, hn, diagv, pv, pi);
    topk_merge<<<NR / 256, 256, 0, stream>>>(pv, pi, tvals, tidx);
    hipMemsetAsync(colsum, 0, NR * sizeof(float), stream);
    hipMemsetAsync(hidden_h, 0, 524288 * sizeof(float), stream);
    colsum_scatter<<<(NR * KTOP + 255) / 256, 256, 0, stream>>>(tvals, tidx, colsum);
    hh_scatter<<<NR * KTOP, HDIM, 0, stream>>>(tvals, tidx, h_shared, hidden_h);
    hh_diag<<<2048, 256, 0, stream>>>(colsum, diagv, h_shared, hidden_h);
    row_nonzero<<<NR, 64, 0, stream>>>(hidden_h, v2);
    row_norm<<<NR, 64, 0, stream>>>(hidden_h, hhn);
    launch_gemm(stream, h_shared, hidden_h, nullptr, BIG, NR, NR, HDIM, 1);
    cos_softmax_row<<<NR, 256, 0, stream>>>(BIG, NR, hn, hhn, v2);
    hipMemsetAsync(hsi0, 0, 524288 * sizeof(float), stream);
    gemm_splitk<<<dim3(NR / 64, 8), 256, 0, stream>>>(BIG, hidden_h, hsi0, NR, 512);
    launch_gemm(stream, hsi0, w_hs, b_hs, h_si, NR, HDIM, HDIM, 1 | 2);
    {
        GemmArgs gb{h_si, w_hs_back, b_hs_back, h_back, HDIM, HDIM, 1 | 2};
        GemmArgs gf{h_si, w_hs_fore, b_hs_fore, out_hs, HDIM, HDIM, 1 | 2 | 4};
        launch_gemm2(stream, gb, gf, NR, HDIM);
    }

    // ================= Phase D: individual branch + head =================
    sub3_kernel<<<2048, 256, 0, stream>>>(x_hidden, p_back, h_back, indi);
    launch_gemm(stream, indi, w_indi, b_indi, out_indi, NR, HDIM, HDIM, 1 | 2 | 4);
    head_kernel<<<NR, 64, 0, stream>>>(out_ps, out_hs, out_indi, w_out, b_out, out);
}

// Round 6
// 1315.581 us; speedup vs baseline: 5.6710x; 1.4474x over previous
//
#include <hip/hip_runtime.h>
#include <cstddef>

// Problem dims
#define NR 4096      // batch
#define CDIM 512     // concepts
#define HDIM 128     // hidden
#define TSTEPS 64
#define DDIM 20
#define KTOP 10

typedef __attribute__((ext_vector_type(8))) short short8;
typedef __attribute__((ext_vector_type(4))) float f32x4;

__device__ __forceinline__ unsigned short f2bf(float f) {
    union { float f; unsigned u; } x; x.f = f;
    unsigned r = (x.u + 0x7fffu + ((x.u >> 16) & 1u)) >> 16;
    return (unsigned short)r;
}
__device__ __forceinline__ float bf2f(unsigned short h) {
    union { unsigned u; float f; } x; x.u = ((unsigned)h) << 16;
    return x.f;
}
// fast sigmoid/tanh via v_exp (clamped; safe, ~1e-7 rel err)
__device__ __forceinline__ float sigm(float v) {
    float c = fminf(fmaxf(v, -30.f), 30.f);
    return __fdividef(1.f, 1.f + __expf(-c));
}
__device__ __forceinline__ float tanh_f(float v) {
    float c = fminf(fmaxf(v, -10.f), 10.f);
    float e = __expf(2.f * c);
    return __fdividef(e - 1.f, e + 1.f);
}

#define MFMA16(a, b, c) __builtin_amdgcn_mfma_f32_16x16x32_bf16(a, b, c, 0, 0, 0)

// ---------------------------------------------------------------------------
// Generic MFMA GEMM: C[M,N] (+)= A[M,K] @ Bpacked (+bias)(+lrelu)
// A fp32, inline hi/lo bf16 split; B pre-packed fragment-linear (hi/lo planes).
// 3-product hi/lo: error ~2^-18 relative (fp32-grade).
// Block 256 thr / 4 waves; wave w = rows bm+w*16..+15, block N-extent 64.
// flags: 1 bias, 2 leaky_relu, 4 atomicAdd epilogue (split-K via blockIdx.z).
// ---------------------------------------------------------------------------
struct MG {
    const float* A; const unsigned short* Bh; const unsigned short* Bl;
    const float* bias; float* C; int N, K, kchunk, flags;
};

__global__ __launch_bounds__(256) void mfma_gemm(MG g)
{
    const int tid = threadIdx.x;
    const int w = tid >> 6, lane = tid & 63, quad = lane >> 4, lm = lane & 15;
    const int bm = (blockIdx.y << 6) + (w << 4);
    const int bn = blockIdx.x << 6;
    const int NC = g.K >> 5;
    const int c0 = (blockIdx.z * g.kchunk) >> 5;
    const int c1 = c0 + (g.kchunk >> 5);
    const float* arow = g.A + (size_t)(bm + lm) * g.K;
    f32x4 acc[4];
    #pragma unroll
    for (int t = 0; t < 4; t++) acc[t] = (f32x4){0.f, 0.f, 0.f, 0.f};

    for (int c = c0; c < c1; c++) {
        const float* ap = arow + (c << 5) + (quad << 3);
        float4 a0 = *(const float4*)ap;
        float4 a1 = *(const float4*)(ap + 4);
        short8 ah, al;
        #pragma unroll
        for (int j = 0; j < 4; j++) {
            float f = (&a0.x)[j];
            unsigned short h = f2bf(f);
            ah[j] = h; al[j] = f2bf(f - bf2f(h));
            f = (&a1.x)[j];
            h = f2bf(f);
            ah[4 + j] = h; al[4 + j] = f2bf(f - bf2f(h));
        }
        #pragma unroll
        for (int t = 0; t < 4; t++) {
            size_t bidx = ((size_t)(((bn >> 4) + t) * NC + c) * 64 + lane) * 8;
            short8 bh = *(const short8*)(g.Bh + bidx);
            short8 bl = *(const short8*)(g.Bl + bidx);
            acc[t] = MFMA16(ah, bh, acc[t]);
            acc[t] = MFMA16(ah, bl, acc[t]);
            acc[t] = MFMA16(al, bh, acc[t]);
        }
    }
    #pragma unroll
    for (int t = 0; t < 4; t++) {
        #pragma unroll
        for (int rg = 0; rg < 4; rg++) {
            int row = bm + (quad << 2) + rg;
            int col = bn + (t << 4) + lm;
            float v = acc[t][rg];
            if (g.flags & 1) v += g.bias[col];
            if (g.flags & 2) v = v > 0.f ? v : 0.01f * v;
            if (g.flags & 4) atomicAdd(&g.C[(size_t)row * g.N + col], v);
            else g.C[(size_t)row * g.N + col] = v;
        }
    }
}

// B-pack from [N,K] rows (B^T GEMM). out layout [nt][c][lane][8], hi/lo planes.
__global__ void pack_bt(const float* __restrict__ src, unsigned short* __restrict__ hi,
                        unsigned short* __restrict__ lo, int K, int total)
{
    int idx = blockIdx.x * 256 + threadIdx.x;
    if (idx >= total) return;
    int NC = K >> 5;
    int lane = idx & 63;
    int c = (idx >> 6) % NC;
    int t = idx / (NC * 64);
    int n = (t << 4) + (lane & 15);
    int kb = (c << 5) + ((lane >> 4) << 3);
    #pragma unroll
    for (int j = 0; j < 8; j++) {
        float f = src[(size_t)n * K + kb + j];
        unsigned short h = f2bf(f);
        hi[(size_t)idx * 8 + j] = h;
        lo[(size_t)idx * 8 + j] = f2bf(f - bf2f(h));
    }
}

// B-pack from [K,N] (plain GEMM, column n)
__global__ void pack_kn(const float* __restrict__ src, unsigned short* __restrict__ hi,
                        unsigned short* __restrict__ lo, int K, int N, int total)
{
    int idx = blockIdx.x * 256 + threadIdx.x;
    if (idx >= total) return;
    int NC = K >> 5;
    int lane = idx & 63;
    int c = (idx >> 6) % NC;
    int t = idx / (NC * 64);
    int n = (t << 4) + (lane & 15);
    int kb = (c << 5) + ((lane >> 4) << 3);
    #pragma unroll
    for (int j = 0; j < 8; j++) {
        float f = src[(size_t)(kb + j) * N + n];
        unsigned short h = f2bf(f);
        hi[(size_t)idx * 8 + j] = h;
        lo[(size_t)idx * 8 + j] = f2bf(f - bf2f(h));
    }
}

// ---------------------------------------------------------------------------
// scan_topk: per row of S [NR,NR]: v = S/max(hn_i*hn_j,1e-12), capture diag,
// zero diag, exact top-10 (tie -> lowest index) via 10 extract-max rounds.
// ---------------------------------------------------------------------------
__global__ __launch_bounds__(256) void scan_topk(const float* __restrict__ S,
        const float* __restrict__ hn, float* __restrict__ diagv,
        float* __restrict__ tvals, int* __restrict__ tidx)
{
    int row = blockIdx.x;
    const float* d = S + (size_t)row * NR;
    int tid = threadIdx.x;
    float hi_ = hn[row];
    float lv[16]; int li[16];
    #pragma unroll
    for (int i = 0; i < 16; i++) {
        int j = tid + i * 256;
        float v = d[j] / fmaxf(hi_ * hn[j], 1e-12f);
        if (j == row) { diagv[row] = v; v = 0.f; }
        lv[i] = v;
        li[i] = j;
    }
    __shared__ float sv[256];
    __shared__ int si[256];
    for (int k = 0; k < KTOP; k++) {
        float bv = -INFINITY; int bi = 0x7fffffff;
        #pragma unroll
        for (int i = 0; i < 16; i++) {
            if (lv[i] > bv || (lv[i] == bv && li[i] < bi)) { bv = lv[i]; bi = li[i]; }
        }
        sv[tid] = bv; si[tid] = bi;
        __syncthreads();
        for (int sdx = 128; sdx > 0; sdx >>= 1) {
            if (tid < sdx) {
                if (sv[tid + sdx] > sv[tid] || (sv[tid + sdx] == sv[tid] && si[tid + sdx] < si[tid])) {
                    sv[tid] = sv[tid + sdx]; si[tid] = si[tid + sdx];
                }
            }
            __syncthreads();
        }
        if (tid == 0) { tvals[row * KTOP + k] = sv[0]; tidx[row * KTOP + k] = si[0]; }
        int wn = si[0];
        if ((wn & 255) == tid) lv[wn >> 8] = -INFINITY;
        __syncthreads();
    }
}

// ---------------------------------------------------------------------------
// GRU weight pack (B-fragment linear layout)
// ---------------------------------------------------------------------------
__global__ void pack_wb(const float* __restrict__ W, unsigned short* __restrict__ Wp,
                        int K, int nch)
{
    int idx = blockIdx.x * 256 + threadIdx.x;
    if (idx >= 24 * nch * 64) return;
    int lane = idx & 63;
    int c = (idx >> 6) % nch;
    int t = idx / (nch * 64);
    int n = t * 16 + (lane & 15);
    int kb = c * 32 + (lane >> 4) * 8;
    #pragma unroll
    for (int j = 0; j < 8; j++) {
        int k = kb + j;
        float f = (k < K) ? W[(size_t)n * K + k] : 0.f;
        Wp[(size_t)idx * 8 + j] = f2bf(f);
    }
}

// x [N, D*T] -> seq [T, N, D]
__global__ void seq_transpose(const float* __restrict__ x, float* __restrict__ seq)
{
    int idx = blockIdx.x * 256 + threadIdx.x;
    int d = idx % DDIM;
    int r = idx / DDIM;
    int n = r & (NR - 1);
    int t = r >> 12;
    seq[idx] = x[(size_t)n * (DDIM * TSTEPS) + d * TSTEPS + t];
}

// ---------------------------------------------------------------------------
// MFMA 2-layer GRU (round-4 structure; fast transcendentals)
// ---------------------------------------------------------------------------
__global__ __launch_bounds__(256) void gru_mfma(
    const float* __restrict__ seq,
    const unsigned short* __restrict__ wih0p,
    const unsigned short* __restrict__ whh0p,
    const unsigned short* __restrict__ wih1p,
    const unsigned short* __restrict__ whh1p,
    const float* __restrict__ bih0, const float* __restrict__ bhh0,
    const float* __restrict__ bih1, const float* __restrict__ bhh1,
    float* __restrict__ xh)
{
    __shared__ __attribute__((aligned(16))) unsigned short hA[2][2][16 * 136];
    __shared__ __attribute__((aligned(16))) unsigned short xA[2][2][16 * 40];

    const int tid = threadIdx.x;
    const int w = tid >> 6;
    const int lane = tid & 63;
    const int quad = lane >> 4;
    const int lm = lane & 15;
    const int n0 = blockIdx.x << 4;

    for (int i = tid; i < 2 * 2 * 16 * 136; i += 256) ((unsigned short*)hA)[i] = 0;
    for (int i = tid; i < 2 * 2 * 16 * 40; i += 256) ((unsigned short*)xA)[i] = 0;

    float br0[2], bz0[2], bni0[2], bnh0[2], br1[2], bz1[2], bni1[2], bnh1[2];
    #pragma unroll
    for (int st = 0; st < 2; st++) {
        int j = w * 32 + st * 16 + lm;
        br0[st]  = bih0[j] + bhh0[j];
        bz0[st]  = bih0[128 + j] + bhh0[128 + j];
        bni0[st] = bih0[256 + j];
        bnh0[st] = bhh0[256 + j];
        br1[st]  = bih1[j] + bhh1[j];
        bz1[st]  = bih1[128 + j] + bhh1[128 + j];
        bni1[st] = bih1[256 + j];
        bnh1[st] = bhh1[256 + j];
    }

    const int aoff = lm * 136 + quad * 8;
    const int xoff = lm * 40 + quad * 8;

    {
        const float* src = seq + (size_t)n0 * DDIM;
        for (int i = tid; i < 16 * DDIM; i += 256) {
            int m = i / DDIM, d = i % DDIM;
            float v = src[i];
            unsigned short hi = f2bf(v);
            xA[0][0][m * 40 + d] = hi;
            xA[0][1][m * 40 + d] = f2bf(v - bf2f(hi));
        }
    }
    __syncthreads();

    for (int t = 0; t < TSTEPS; t++) {
        const int buf = t & 1;
        f32x4 accr[2], accz[2], accni[2], accnh[2];
        #pragma unroll
        for (int st = 0; st < 2; st++) {
            accr[st] = (f32x4){0.f, 0.f, 0.f, 0.f};
            accz[st] = (f32x4){0.f, 0.f, 0.f, 0.f};
            accni[st] = (f32x4){0.f, 0.f, 0.f, 0.f};
            accnh[st] = (f32x4){0.f, 0.f, 0.f, 0.f};
        }

        // layer 0
        {
            short8 axh = *(const short8*)&xA[buf][0][xoff];
            short8 axl = *(const short8*)&xA[buf][1][xoff];
            #pragma unroll
            for (int st = 0; st < 2; st++) {
                int tb = w * 2 + st;
                short8 b;
                b = *(const short8*)&wih0p[(size_t)(tb) * 512 + lane * 8];
                accr[st] = MFMA16(axh, b, accr[st]);
                accr[st] = MFMA16(axl, b, accr[st]);
                b = *(const short8*)&wih0p[(size_t)(8 + tb) * 512 + lane * 8];
                accz[st] = MFMA16(axh, b, accz[st]);
                accz[st] = MFMA16(axl, b, accz[st]);
                b = *(const short8*)&wih0p[(size_t)(16 + tb) * 512 + lane * 8];
                accni[st] = MFMA16(axh, b, accni[st]);
                accni[st] = MFMA16(axl, b, accni[st]);
            }
        }
        #pragma unroll
        for (int c = 0; c < 4; c++) {
            short8 ahh = *(const short8*)&hA[0][0][aoff + c * 32];
            short8 ahl = *(const short8*)&hA[0][1][aoff + c * 32];
            #pragma unroll
            for (int st = 0; st < 2; st++) {
                int tb = w * 2 + st;
                short8 b;
                b = *(const short8*)&whh0p[(size_t)((tb) * 4 + c) * 512 + lane * 8];
                accr[st] = MFMA16(ahh, b, accr[st]);
                accr[st] = MFMA16(ahl, b, accr[st]);
                b = *(const short8*)&whh0p[(size_t)((8 + tb) * 4 + c) * 512 + lane * 8];
                accz[st] = MFMA16(ahh, b, accz[st]);
                accz[st] = MFMA16(ahl, b, accz[st]);
                b = *(const short8*)&whh0p[(size_t)((16 + tb) * 4 + c) * 512 + lane * 8];
                accnh[st] = MFMA16(ahh, b, accnh[st]);
                accnh[st] = MFMA16(ahl, b, accnh[st]);
            }
        }
        float hold[2][4];
        #pragma unroll
        for (int st = 0; st < 2; st++) {
            int j = w * 32 + st * 16 + lm;
            #pragma unroll
            for (int rg = 0; rg < 4; rg++) {
                int off = (quad * 4 + rg) * 136 + j;
                hold[st][rg] = bf2f(hA[0][0][off]) + bf2f(hA[0][1][off]);
            }
        }
        __syncthreads();
        #pragma unroll
        for (int st = 0; st < 2; st++) {
            int j = w * 32 + st * 16 + lm;
            #pragma unroll
            for (int rg = 0; rg < 4; rg++) {
                float r = sigm(accr[st][rg] + br0[st]);
                float z = sigm(accz[st][rg] + bz0[st]);
                float nc = tanh_f(accni[st][rg] + bni0[st] + r * (accnh[st][rg] + bnh0[st]));
                float hnew = (1.f - z) * nc + z * hold[st][rg];
                int off = (quad * 4 + rg) * 136 + j;
                unsigned short hi = f2bf(hnew);
                hA[0][0][off] = hi;
                hA[0][1][off] = f2bf(hnew - bf2f(hi));
            }
        }
        __syncthreads();

        // layer 1
        #pragma unroll
        for (int st = 0; st < 2; st++) {
            accr[st] = (f32x4){0.f, 0.f, 0.f, 0.f};
            accz[st] = (f32x4){0.f, 0.f, 0.f, 0.f};
            accni[st] = (f32x4){0.f, 0.f, 0.f, 0.f};
            accnh[st] = (f32x4){0.f, 0.f, 0.f, 0.f};
        }
        #pragma unroll
        for (int c = 0; c < 4; c++) {
            short8 a0h = *(const short8*)&hA[0][0][aoff + c * 32];
            short8 a0l = *(const short8*)&hA[0][1][aoff + c * 32];
            short8 a1h = *(const short8*)&hA[1][0][aoff + c * 32];
            short8 a1l = *(const short8*)&hA[1][1][aoff + c * 32];
            #pragma unroll
            for (int st = 0; st < 2; st++) {
                int tb = w * 2 + st;
                short8 b;
                b = *(const short8*)&wih1p[(size_t)((tb) * 4 + c) * 512 + lane * 8];
                accr[st] = MFMA16(a0h, b, accr[st]);
                accr[st] = MFMA16(a0l, b, accr[st]);
                b = *(const short8*)&whh1p[(size_t)((tb) * 4 + c) * 512 + lane * 8];
                accr[st] = MFMA16(a1h, b, accr[st]);
                accr[st] = MFMA16(a1l, b, accr[st]);
                b = *(const short8*)&wih1p[(size_t)((8 + tb) * 4 + c) * 512 + lane * 8];
                accz[st] = MFMA16(a0h, b, accz[st]);
                accz[st] = MFMA16(a0l, b, accz[st]);
                b = *(const short8*)&whh1p[(size_t)((8 + tb) * 4 + c) * 512 + lane * 8];
                accz[st] = MFMA16(a1h, b, accz[st]);
                accz[st] = MFMA16(a1l, b, accz[st]);
                b = *(const short8*)&wih1p[(size_t)((16 + tb) * 4 + c) * 512 + lane * 8];
                accni[st] = MFMA16(a0h, b, accni[st]);
                accni[st] = MFMA16(a0l, b, accni[st]);
                b = *(const short8*)&whh1p[(size_t)((16 + tb) * 4 + c) * 512 + lane * 8];
                accnh[st] = MFMA16(a1h, b, accnh[st]);
                accnh[st] = MFMA16(a1l, b, accnh[st]);
            }
        }
        #pragma unroll
        for (int st = 0; st < 2; st++) {
            int j = w * 32 + st * 16 + lm;
            #pragma unroll
            for (int rg = 0; rg < 4; rg++) {
                int off = (quad * 4 + rg) * 136 + j;
                hold[st][rg] = bf2f(hA[1][0][off]) + bf2f(hA[1][1][off]);
            }
        }
        if (t + 1 < TSTEPS) {
            const float* src = seq + ((size_t)(t + 1) * NR + n0) * DDIM;
            for (int i = tid; i < 16 * DDIM; i += 256) {
                int m = i / DDIM, d = i % DDIM;
                float v = src[i];
                unsigned short hi = f2bf(v);
                xA[buf ^ 1][0][m * 40 + d] = hi;
                xA[buf ^ 1][1][m * 40 + d] = f2bf(v - bf2f(hi));
            }
        }
        __syncthreads();
        #pragma unroll
        for (int st = 0; st < 2; st++) {
            int j = w * 32 + st * 16 + lm;
            #pragma unroll
            for (int rg = 0; rg < 4; rg++) {
                float r = sigm(accr[st][rg] + br1[st]);
                float z = sigm(accz[st][rg] + bz1[st]);
                float nc = tanh_f(accni[st][rg] + bni1[st] + r * (accnh[st][rg] + bnh1[st]));
                float hnew = (1.f - z) * nc + z * hold[st][rg];
                int off = (quad * 4 + rg) * 136 + j;
                unsigned short hi = f2bf(hnew);
                hA[1][0][off] = hi;
                hA[1][1][off] = f2bf(hnew - bf2f(hi));
                if (t + 1 == TSTEPS)
                    xh[(size_t)(n0 + quad * 4 + rg) * HDIM + j] = hnew;
            }
        }
    }
}

// ---------------------------------------------------------------------------
// Small helpers
// ---------------------------------------------------------------------------
__global__ void den_kernel(const float* __restrict__ cm, const float* __restrict__ mv,
                           float* __restrict__ den)
{
    int c = blockIdx.x * 64 + (threadIdx.x & 63);
    int rg = threadIdx.x >> 6;
    float acc = 0.f;
    for (int n = rg; n < NR; n += 4) acc += cm[(size_t)n * CDIM + c] * mv[n];
    __shared__ float red[4][64];
    red[rg][threadIdx.x & 63] = acc;
    __syncthreads();
    if (rg == 0)
        den[c] = red[0][threadIdx.x] + red[1][threadIdx.x] + red[2][threadIdx.x] + red[3][threadIdx.x];
}

__global__ void s2ct_kernel(const float* __restrict__ cm, const float* __restrict__ mv,
                            const float* __restrict__ den, float* __restrict__ s2cT)
{
    int idx = blockIdx.x * 256 + threadIdx.x;
    int c = idx >> 12, n = idx & (NR - 1);
    float m = cm[(size_t)n * CDIM + c];
    s2cT[idx] = (m * mv[n]) / (den[c] * m + 1.f);
}

__global__ void row_norm(const float* __restrict__ a, float* __restrict__ out)
{
    int r = blockIdx.x;
    float acc = 0.f;
    for (int h = threadIdx.x; h < HDIM; h += 64) {
        float v = a[(size_t)r * HDIM + h];
        acc += v * v;
    }
    for (int o = 32; o > 0; o >>= 1) acc += __shfl_down(acc, o);
    if (threadIdx.x == 0) out[r] = sqrtf(acc);
}

__global__ void row_nonzero(const float* __restrict__ a, float* __restrict__ out)
{
    int r = blockIdx.x;
    float acc = 0.f;
    for (int h = threadIdx.x; h < HDIM; h += 64) acc += a[(size_t)r * HDIM + h];
    for (int o = 32; o > 0; o >>= 1) acc += __shfl_down(acc, o);
    if (threadIdx.x == 0) out[r] = (acc != 0.f) ? 1.f : 0.f;
}

__global__ __launch_bounds__(256) void cos_softmax_row(float* __restrict__ data, int N,
        const float* __restrict__ rn, const float* __restrict__ cn,
        const float* __restrict__ vmask)
{
    int row = blockIdx.x;
    float* d = data + (size_t)row * N;
    int tid = threadIdx.x;
    __shared__ float red[256];
    float rnv = rn ? rn[row] : 0.f;
    float mx = -INFINITY;
    for (int j = tid; j < N; j += 256) {
        float v = d[j];
        if (cn) v = v / fmaxf(rnv * cn[j], 1e-12f);
        if (vmask && vmask[j] == 0.f) v = -1e9f;
        d[j] = v;
        mx = fmaxf(mx, v);
    }
    red[tid] = mx; __syncthreads();
    for (int sdx = 128; sdx > 0; sdx >>= 1) {
        if (tid < sdx) red[tid] = fmaxf(red[tid], red[tid + sdx]);
        __syncthreads();
    }
    float M = red[0]; __syncthreads();
    float sum = 0.f;
    for (int j = tid; j < N; j += 256) {
        float e = expf(d[j] - M);
        d[j] = e;
        sum += e;
    }
    red[tid] = sum; __syncthreads();
    for (int sdx = 128; sdx > 0; sdx >>= 1) {
        if (tid < sdx) red[tid] += red[tid + sdx];
        __syncthreads();
    }
    float inv = 1.f / red[0];
    for (int j = tid; j < N; j += 256) {
        float v = d[j] * inv;
        if (vmask) v *= vmask[j];
        d[j] = v;
    }
}

__global__ void colsum_scatter(const float* __restrict__ vals, const int* __restrict__ idxs,
                               float* __restrict__ colsum)
{
    int idx = blockIdx.x * 256 + threadIdx.x;
    if (idx < NR * KTOP) atomicAdd(&colsum[idxs[idx]], vals[idx]);
}

__global__ void hh_scatter(const float* __restrict__ vals, const int* __restrict__ idxs,
                           const float* __restrict__ hsh, float* __restrict__ hh)
{
    int p = blockIdx.x;
    int j = idxs[p];
    float v = vals[p];
    int i = p / KTOP;
    atomicAdd(&hh[(size_t)j * HDIM + threadIdx.x], v * hsh[(size_t)i * HDIM + threadIdx.x]);
}

__global__ void hh_diag(const float* __restrict__ colsum, const float* __restrict__ diag,
                        const float* __restrict__ hsh, float* __restrict__ hh)
{
    int idx = blockIdx.x * 256 + threadIdx.x;
    int j = idx >> 7;
    if (colsum[j] != 0.f) hh[idx] += diag[j] * hsh[idx];
}

__global__ void sub2_kernel(const float* __restrict__ a, const float* __restrict__ b,
                            float* __restrict__ o)
{
    int i = blockIdx.x * 256 + threadIdx.x;
    o[i] = a[i] - b[i];
}

__global__ void sub3_kernel(const float* __restrict__ a, const float* __restrict__ b,
                            const float* __restrict__ c, float* __restrict__ o)
{
    int i = blockIdx.x * 256 + threadIdx.x;
    o[i] = a[i] - b[i] - c[i];
}

__global__ void head_kernel(const float* __restrict__ ps, const float* __restrict__ hs,
                            const float* __restrict__ indi, const float* __restrict__ w,
                            const float* __restrict__ b, float* __restrict__ out)
{
    int n = blockIdx.x;
    int t = threadIdx.x;
    float acc = 0.f;
    for (int h = t; h < HDIM; h += 64) {
        size_t k = (size_t)n * HDIM + h;
        acc += (ps[k] + hs[k] + indi[k]) * w[h];
    }
    for (int o = 32; o > 0; o >>= 1) acc += __shfl_down(acc, o);
    if (t == 0) out[n] = acc + b[0];
}

// ---------------------------------------------------------------------------
// host-side helpers
// ---------------------------------------------------------------------------
static inline void mg(hipStream_t s, const float* A, const unsigned short* Bh,
                      const unsigned short* Bl, const float* bias, float* C,
                      int M, int N, int K, int z, int flags)
{
    MG g{A, Bh, Bl, bias, C, N, K, K / z, flags | (z > 1 ? 4 : 0)};
    mfma_gemm<<<dim3(N / 64, M / 64, z), 256, 0, s>>>(g);
}
static inline void pbt(hipStream_t s, const float* src, unsigned short* hi,
                       unsigned short* lo, int N, int K)
{
    int total = (N / 16) * (K / 32) * 64;
    pack_bt<<<(total + 255) / 256, 256, 0, s>>>(src, hi, lo, K, total);
}
static inline void pkn(hipStream_t s, const float* src, unsigned short* hi,
                       unsigned short* lo, int K, int N)
{
    int total = (N / 16) * (K / 32) * 64;
    pack_kn<<<(total + 255) / 256, 256, 0, s>>>(src, hi, lo, K, N, total);
}

extern "C" void kernel_launch(void* const* d_in, const int* in_sizes, int n_in,
                              void* d_out, int out_size, void* d_ws, size_t ws_size,
                              hipStream_t stream)
{
    (void)in_sizes; (void)n_in; (void)out_size; (void)ws_size;
    const float* x    = (const float*)d_in[0];
    const float* cm   = (const float*)d_in[1];
    const float* mv   = (const float*)d_in[2];
    const float* wih0 = (const float*)d_in[3];
    const float* whh0 = (const float*)d_in[4];
    const float* bih0 = (const float*)d_in[5];
    const float* bhh0 = (const float*)d_in[6];
    const float* wih1 = (const float*)d_in[7];
    const float* whh1 = (const float*)d_in[8];
    const float* bih1 = (const float*)d_in[9];
    const float* bhh1 = (const float*)d_in[10];
    const float* w_ps = (const float*)d_in[11];
    const float* b_ps = (const float*)d_in[12];
    const float* w_hs = (const float*)d_in[13];
    const float* b_hs = (const float*)d_in[14];
    const float* w_ps_fore = (const float*)d_in[15];
    const float* b_ps_fore = (const float*)d_in[16];
    const float* w_hs_fore = (const float*)d_in[17];
    const float* b_hs_fore = (const float*)d_in[18];
    const float* w_ps_back = (const float*)d_in[19];
    const float* b_ps_back = (const float*)d_in[20];
    const float* w_hs_back = (const float*)d_in[21];
    const float* b_hs_back = (const float*)d_in[22];
    const float* w_indi = (const float*)d_in[23];
    const float* b_indi = (const float*)d_in[24];
    const float* w_out  = (const float*)d_in[25];
    const float* b_out  = (const float*)d_in[26];
    float* out = (float*)d_out;

    // ---- workspace layout (floats) ----
    float* ws = (float*)d_ws;
    float* BIG = ws;                         // 16,777,216 (overlaid)
    float* h0 = ws + 16777216;               // 524288 (unused)
    float* h1 = h0 + 524288;                 // x_hidden
    float* den = h1 + 524288;                // 512
    float* v1 = den + 512;                   // 512
    float* hidden = v1 + 512;                // 65536
    float* hidden2 = hidden + 65536;         // 65536
    float* xnorm = hidden2 + 65536;          // 4096
    float* h2n = xnorm + 4096;               // 512
    float* p0 = h2n + 512;                   // 524288
    float* p_shared = p0 + 524288;
    float* p_back = p_shared + 524288;
    float* out_ps = p_back + 524288;
    float* h_shared = out_ps + 524288;
    float* hn = h_shared + 524288;           // 4096
    float* diagv = hn + 4096;                // 4096
    float* colsum = diagv + 4096;            // 4096
    float* tvals = colsum + 4096;            // 40960
    int*   tidx = (int*)(tvals + 40960);     // 40960 ints
    float* hidden_h = (float*)(tidx + 40960);
    float* v2 = hidden_h + 524288;           // 4096
    float* hhn = v2 + 4096;                  // 4096
    float* hsi0 = hhn + 4096;                // 524288
    float* h_si = hsi0 + 524288;
    float* h_back = h_si + 524288;
    float* out_hs = h_back + 524288;
    float* indi = out_hs + 524288;
    float* out_indi = indi + 524288;
    float* extra = out_indi + 524288;        // small phase-C/D weight packs

    // GRU-phase overlays inside BIG:
    float* seqt = BIG;
    unsigned short* wih0p = (unsigned short*)(BIG + 5242880);
    unsigned short* whh0p = wih0p + 12288;
    unsigned short* wih1p = whh0p + 49152;
    unsigned short* whh1p = wih1p + 49152;
    // concept-phase overlays inside BIG:
    float* s2cT = BIG;                       // [0 .. 2M)
    float* L    = BIG + 2097152;             // [2M .. 4M)
    float* c2s  = BIG + 4194304;             // [4M .. 6M)
    // phase-B pack area inside BIG [6M ..): all dead before the big S GEMMs
    unsigned short* PB = (unsigned short*)(BIG + 6291456);
    unsigned short* pbt_xh_hi = PB;                  // 524288
    unsigned short* pbt_xh_lo = pbt_xh_hi + 524288;
    unsigned short* pkn_xh_hi = pbt_xh_lo + 524288;
    unsigned short* pkn_xh_lo = pkn_xh_hi + 524288;
    unsigned short* pbt_h2_hi = pkn_xh_lo + 524288;  // 65536
    unsigned short* pbt_h2_lo = pbt_h2_hi + 65536;
    unsigned short* pkn_h2_hi = pbt_h2_lo + 65536;
    unsigned short* pkn_h2_lo = pkn_h2_hi + 65536;
    unsigned short* wps_hi  = pkn_h2_lo + 65536;     // 16384 each
    unsigned short* wps_lo  = wps_hi + 16384;
    unsigned short* wpsb_hi = wps_lo + 16384;
    unsigned short* wpsb_lo = wpsb_hi + 16384;
    unsigned short* wpsf_hi = wpsb_lo + 16384;
    unsigned short* wpsf_lo = wpsf_hi + 16384;
    // phase-C packs overlay dead fp32 buffers:
    unsigned short* pbt_hsh_hi = (unsigned short*)p0;         // p0 dead after p_shared
    unsigned short* pbt_hsh_lo = pbt_hsh_hi + 524288;
    unsigned short* pbt_hh_hi = (unsigned short*)indi;        // dead until sub3
    unsigned short* pbt_hh_lo = pbt_hh_hi + 524288;
    unsigned short* pkn_hh_hi = (unsigned short*)out_indi;    // dead until w_indi gemm
    unsigned short* pkn_hh_lo = pkn_hh_hi + 524288;
    unsigned short* EX = (unsigned short*)extra;
    unsigned short* whs_hi  = EX;            unsigned short* whs_lo  = EX + 16384;
    unsigned short* whsb_hi = EX + 32768;    unsigned short* whsb_lo = EX + 49152;
    unsigned short* whsf_hi = EX + 65536;    unsigned short* whsf_lo = EX + 81920;
    unsigned short* wind_hi = EX + 98304;    unsigned short* wind_lo = EX + 114688;

    // ================= Phase A: MFMA 2-layer GRU =================
    seq_transpose<<<(TSTEPS * NR * DDIM) / 256, 256, 0, stream>>>(x, seqt);
    pack_wb<<<6, 256, 0, stream>>>(wih0, wih0p, DDIM, 1);
    pack_wb<<<24, 256, 0, stream>>>(whh0, whh0p, HDIM, 4);
    pack_wb<<<24, 256, 0, stream>>>(wih1, wih1p, HDIM, 4);
    pack_wb<<<24, 256, 0, stream>>>(whh1, whh1p, HDIM, 4);
    gru_mfma<<<NR / 16, 256, 0, stream>>>(seqt, wih0p, whh0p, wih1p, whh1p,
                                          bih0, bhh0, bih1, bhh1, h1);
    float* x_hidden = h1;

    // ================= Phase B: predefined-concept branch =================
    den_kernel<<<8, 256, 0, stream>>>(cm, mv, den);
    s2ct_kernel<<<(CDIM * NR) / 256, 256, 0, stream>>>(cm, mv, den, s2cT);
    pkn(stream, x_hidden, pkn_xh_hi, pkn_xh_lo, NR, HDIM);       // B[k=sample][n]
    pbt(stream, x_hidden, pbt_xh_hi, pbt_xh_lo, NR, HDIM);       // B[n=sample][k]
    hipMemsetAsync(hidden, 0, 65536 * sizeof(float), stream);
    mg(stream, s2cT, pkn_xh_hi, pkn_xh_lo, nullptr, hidden, CDIM, HDIM, NR, 8, 0);
    row_nonzero<<<CDIM, 64, 0, stream>>>(hidden, v1);
    mg(stream, hidden, pbt_xh_hi, pbt_xh_lo, nullptr, L, CDIM, NR, HDIM, 1, 0);
    cos_softmax_row<<<CDIM, 256, 0, stream>>>(L, NR, nullptr, nullptr, nullptr);
    hipMemsetAsync(hidden2, 0, 65536 * sizeof(float), stream);
    mg(stream, L, pkn_xh_hi, pkn_xh_lo, nullptr, hidden2, CDIM, HDIM, NR, 8, 0);
    row_norm<<<NR, 64, 0, stream>>>(x_hidden, xnorm);
    row_norm<<<CDIM, 64, 0, stream>>>(hidden2, h2n);
    pbt(stream, hidden2, pbt_h2_hi, pbt_h2_lo, CDIM, HDIM);
    pkn(stream, hidden2, pkn_h2_hi, pkn_h2_lo, CDIM, HDIM);
    mg(stream, x_hidden, pbt_h2_hi, pbt_h2_lo, nullptr, c2s, NR, CDIM, HDIM, 1, 0);
    cos_softmax_row<<<NR, 256, 0, stream>>>(c2s, CDIM, xnorm, h2n, v1);
    hipMemsetAsync(p0, 0, 524288 * sizeof(float), stream);
    mg(stream, c2s, pkn_h2_hi, pkn_h2_lo, nullptr, p0, NR, HDIM, CDIM, 2, 0);
    pbt(stream, w_ps, wps_hi, wps_lo, HDIM, HDIM);
    pbt(stream, w_ps_back, wpsb_hi, wpsb_lo, HDIM, HDIM);
    pbt(stream, w_ps_fore, wpsf_hi, wpsf_lo, HDIM, HDIM);
    mg(stream, p0, wps_hi, wps_lo, b_ps, p_shared, NR, HDIM, HDIM, 1, 1);
    mg(stream, p_shared, wpsb_hi, wpsb_lo, b_ps_back, p_back, NR, HDIM, HDIM, 1, 1);
    mg(stream, p_shared, wpsf_hi, wpsf_lo, b_ps_fore, out_ps, NR, HDIM, HDIM, 1, 1 | 2);

    // ================= Phase C: hidden-concept branch =================
    sub2_kernel<<<2048, 256, 0, stream>>>(x_hidden, p_back, h_shared);
    row_norm<<<NR, 64, 0, stream>>>(h_shared, hn);
    pbt(stream, h_shared, pbt_hsh_hi, pbt_hsh_lo, NR, HDIM);
    mg(stream, h_shared, pbt_hsh_hi, pbt_hsh_lo, nullptr, BIG, NR, NR, HDIM, 1, 0);
    scan_topk<<<NR, 256, 0, stream>>>(BIG, hn, diagv, tvals, tidx);
    hipMemsetAsync(colsum, 0, NR * sizeof(float), stream);
    hipMemsetAsync(hidden_h, 0, 524288 * sizeof(float), stream);
    colsum_scatter<<<(NR * KTOP + 255) / 256, 256, 0, stream>>>(tvals, tidx, colsum);
    hh_scatter<<<NR * KTOP, HDIM, 0, stream>>>(tvals, tidx, h_shared, hidden_h);
    hh_diag<<<2048, 256, 0, stream>>>(colsum, diagv, h_shared, hidden_h);
    row_nonzero<<<NR, 64, 0, stream>>>(hidden_h, v2);
    row_norm<<<NR, 64, 0, stream>>>(hidden_h, hhn);
    pbt(stream, hidden_h, pbt_hh_hi, pbt_hh_lo, NR, HDIM);
    pkn(stream, hidden_h, pkn_hh_hi, pkn_hh_lo, NR, HDIM);
    mg(stream, h_shared, pbt_hh_hi, pbt_hh_lo, nullptr, BIG, NR, NR, HDIM, 1, 0);
    cos_softmax_row<<<NR, 256, 0, stream>>>(BIG, NR, hn, hhn, v2);
    hipMemsetAsync(hsi0, 0, 524288 * sizeof(float), stream);
    mg(stream, BIG, pkn_hh_hi, pkn_hh_lo, nullptr, hsi0, NR, HDIM, NR, 4, 0);
    pbt(stream, w_hs, whs_hi, whs_lo, HDIM, HDIM);
    pbt(stream, w_hs_back, whsb_hi, whsb_lo, HDIM, HDIM);
    pbt(stream, w_hs_fore, whsf_hi, whsf_lo, HDIM, HDIM);
    mg(stream, hsi0, whs_hi, whs_lo, b_hs, h_si, NR, HDIM, HDIM, 1, 1);
    mg(stream, h_si, whsb_hi, whsb_lo, b_hs_back, h_back, NR, HDIM, HDIM, 1, 1);
    mg(stream, h_si, whsf_hi, whsf_lo, b_hs_fore, out_hs, NR, HDIM, HDIM, 1, 1 | 2);

    // ================= Phase D: individual branch + head =================
    sub3_kernel<<<2048, 256, 0, stream>>>(x_hidden, p_back, h_back, indi);
    pbt(stream, w_indi, wind_hi, wind_lo, HDIM, HDIM);
    mg(stream, indi, wind_hi, wind_lo, b_indi, out_indi, NR, HDIM, HDIM, 1, 1 | 2);
    head_kernel<<<NR, 64, 0, stream>>>(out_ps, out_hs, out_indi, w_out, b_out, out);
}

// Round 7
// 1206.331 us; speedup vs baseline: 6.1846x; 1.0906x over previous
//
#include <hip/hip_runtime.h>
#include <cstddef>

// Problem dims
#define NR 4096      // batch
#define CDIM 512     // concepts
#define HDIM 128     // hidden
#define TSTEPS 64
#define DDIM 20
#define KTOP 10

typedef __attribute__((ext_vector_type(8))) short short8;
typedef __attribute__((ext_vector_type(4))) float f32x4;

__device__ __forceinline__ unsigned short f2bf(float f) {
    union { float f; unsigned u; } x; x.f = f;
    unsigned r = (x.u + 0x7fffu + ((x.u >> 16) & 1u)) >> 16;
    return (unsigned short)r;
}
__device__ __forceinline__ float bf2f(unsigned short h) {
    union { unsigned u; float f; } x; x.u = ((unsigned)h) << 16;
    return x.f;
}
__device__ __forceinline__ float sigm(float v) {
    float c = fminf(fmaxf(v, -30.f), 30.f);
    return __fdividef(1.f, 1.f + __expf(-c));
}
__device__ __forceinline__ float tanh_f(float v) {
    float c = fminf(fmaxf(v, -10.f), 10.f);
    float e = __expf(2.f * c);
    return __fdividef(e - 1.f, e + 1.f);
}

#define MFMA16(a, b, c) __builtin_amdgcn_mfma_f32_16x16x32_bf16(a, b, c, 0, 0, 0)

// ---------------------------------------------------------------------------
// Generic MFMA GEMM (unchanged from round 6)
// ---------------------------------------------------------------------------
struct MG {
    const float* A; const unsigned short* Bh; const unsigned short* Bl;
    const float* bias; float* C; int N, K, kchunk, flags;
};

__global__ __launch_bounds__(256) void mfma_gemm(MG g)
{
    const int tid = threadIdx.x;
    const int w = tid >> 6, lane = tid & 63, quad = lane >> 4, lm = lane & 15;
    const int bm = (blockIdx.y << 6) + (w << 4);
    const int bn = blockIdx.x << 6;
    const int NC = g.K >> 5;
    const int c0 = (blockIdx.z * g.kchunk) >> 5;
    const int c1 = c0 + (g.kchunk >> 5);
    const float* arow = g.A + (size_t)(bm + lm) * g.K;
    f32x4 acc[4];
    #pragma unroll
    for (int t = 0; t < 4; t++) acc[t] = (f32x4){0.f, 0.f, 0.f, 0.f};

    for (int c = c0; c < c1; c++) {
        const float* ap = arow + (c << 5) + (quad << 3);
        float4 a0 = *(const float4*)ap;
        float4 a1 = *(const float4*)(ap + 4);
        short8 ah, al;
        #pragma unroll
        for (int j = 0; j < 4; j++) {
            float f = (&a0.x)[j];
            unsigned short h = f2bf(f);
            ah[j] = h; al[j] = f2bf(f - bf2f(h));
            f = (&a1.x)[j];
            h = f2bf(f);
            ah[4 + j] = h; al[4 + j] = f2bf(f - bf2f(h));
        }
        #pragma unroll
        for (int t = 0; t < 4; t++) {
            size_t bidx = ((size_t)(((bn >> 4) + t) * NC + c) * 64 + lane) * 8;
            short8 bh = *(const short8*)(g.Bh + bidx);
            short8 bl = *(const short8*)(g.Bl + bidx);
            acc[t] = MFMA16(ah, bh, acc[t]);
            acc[t] = MFMA16(ah, bl, acc[t]);
            acc[t] = MFMA16(al, bh, acc[t]);
        }
    }
    #pragma unroll
    for (int t = 0; t < 4; t++) {
        #pragma unroll
        for (int rg = 0; rg < 4; rg++) {
            int row = bm + (quad << 2) + rg;
            int col = bn + (t << 4) + lm;
            float v = acc[t][rg];
            if (g.flags & 1) v += g.bias[col];
            if (g.flags & 2) v = v > 0.f ? v : 0.01f * v;
            if (g.flags & 4) atomicAdd(&g.C[(size_t)row * g.N + col], v);
            else g.C[(size_t)row * g.N + col] = v;
        }
    }
}

// B-pack from [N,K] rows; layout [nt][c][lane][8], hi/lo planes.
__global__ void pack_bt(const float* __restrict__ src, unsigned short* __restrict__ hi,
                        unsigned short* __restrict__ lo, int K, int total)
{
    int idx = blockIdx.x * 256 + threadIdx.x;
    if (idx >= total) return;
    int NC = K >> 5;
    int lane = idx & 63;
    int c = (idx >> 6) % NC;
    int t = idx / (NC * 64);
    int n = (t << 4) + (lane & 15);
    int kb = (c << 5) + ((lane >> 4) << 3);
    #pragma unroll
    for (int j = 0; j < 8; j++) {
        float f = src[(size_t)n * K + kb + j];
        unsigned short h = f2bf(f);
        hi[(size_t)idx * 8 + j] = h;
        lo[(size_t)idx * 8 + j] = f2bf(f - bf2f(h));
    }
}

// B-pack from [K,N]
__global__ void pack_kn(const float* __restrict__ src, unsigned short* __restrict__ hi,
                        unsigned short* __restrict__ lo, int K, int N, int total)
{
    int idx = blockIdx.x * 256 + threadIdx.x;
    if (idx >= total) return;
    int NC = K >> 5;
    int lane = idx & 63;
    int c = (idx >> 6) % NC;
    int t = idx / (NC * 64);
    int n = (t << 4) + (lane & 15);
    int kb = (c << 5) + ((lane >> 4) << 3);
    #pragma unroll
    for (int j = 0; j < 8; j++) {
        float f = src[(size_t)(kb + j) * N + n];
        unsigned short h = f2bf(f);
        hi[(size_t)idx * 8 + j] = h;
        lo[(size_t)idx * 8 + j] = f2bf(f - bf2f(h));
    }
}

// ---------------------------------------------------------------------------
// scan_topk (unchanged)
// ---------------------------------------------------------------------------
__global__ __launch_bounds__(256) void scan_topk(const float* __restrict__ S,
        const float* __restrict__ hn, float* __restrict__ diagv,
        float* __restrict__ tvals, int* __restrict__ tidx)
{
    int row = blockIdx.x;
    const float* d = S + (size_t)row * NR;
    int tid = threadIdx.x;
    float hi_ = hn[row];
    float lv[16]; int li[16];
    #pragma unroll
    for (int i = 0; i < 16; i++) {
        int j = tid + i * 256;
        float v = d[j] / fmaxf(hi_ * hn[j], 1e-12f);
        if (j == row) { diagv[row] = v; v = 0.f; }
        lv[i] = v;
        li[i] = j;
    }
    __shared__ float sv[256];
    __shared__ int si[256];
    for (int k = 0; k < KTOP; k++) {
        float bv = -INFINITY; int bi = 0x7fffffff;
        #pragma unroll
        for (int i = 0; i < 16; i++) {
            if (lv[i] > bv || (lv[i] == bv && li[i] < bi)) { bv = lv[i]; bi = li[i]; }
        }
        sv[tid] = bv; si[tid] = bi;
        __syncthreads();
        for (int sdx = 128; sdx > 0; sdx >>= 1) {
            if (tid < sdx) {
                if (sv[tid + sdx] > sv[tid] || (sv[tid + sdx] == sv[tid] && si[tid + sdx] < si[tid])) {
                    sv[tid] = sv[tid + sdx]; si[tid] = si[tid + sdx];
                }
            }
            __syncthreads();
        }
        if (tid == 0) { tvals[row * KTOP + k] = sv[0]; tidx[row * KTOP + k] = si[0]; }
        int wn = si[0];
        if ((wn & 255) == tid) lv[wn >> 8] = -INFINITY;
        __syncthreads();
    }
}

// ---------------------------------------------------------------------------
// hc2s_flash: fused cos-sim + v2-mask + online softmax + (P @ hidden_h).
// Block = 16 rows (grid 256), 4 waves; wave wv owns S cols wv*16..+15 of each
// 64-col tile and V-tiles vt = wv*2, wv*2+1. P turns C-layout -> A-layout
// through LDS (hi/lo bf16 planes). Masked cols get -1e9 -> exp underflow -> 0,
// which implements the reference's trailing "* v2".
// ---------------------------------------------------------------------------
__global__ __launch_bounds__(256) void hc2s_flash(
    const float* __restrict__ hsh, const float* __restrict__ hn,
    const float* __restrict__ hhn, const float* __restrict__ v2,
    const unsigned short* __restrict__ Bh, const unsigned short* __restrict__ Bl,
    const unsigned short* __restrict__ Vh, const unsigned short* __restrict__ Vl,
    float* __restrict__ O)
{
    __shared__ __attribute__((aligned(16))) unsigned short Ph[16 * 72];
    __shared__ __attribute__((aligned(16))) unsigned short Pl[16 * 72];
    __shared__ float redmax[4][16];
    __shared__ float redsum[4][16];

    const int tid = threadIdx.x;
    const int wv = tid >> 6, lane = tid & 63, quad = lane >> 4, lm = lane & 15;
    const int bm = blockIdx.x << 4;

    // preload A-frags (rows bm..bm+15 of h_shared), hi/lo split
    short8 ahh[4], ahl[4];
    #pragma unroll
    for (int c = 0; c < 4; c++) {
        const float* ap = hsh + (size_t)(bm + lm) * HDIM + (c << 5) + (quad << 3);
        float4 a0 = *(const float4*)ap;
        float4 a1 = *(const float4*)(ap + 4);
        #pragma unroll
        for (int j = 0; j < 4; j++) {
            float f = (&a0.x)[j];
            unsigned short h = f2bf(f);
            ahh[c][j] = h; ahl[c][j] = f2bf(f - bf2f(h));
            f = (&a1.x)[j];
            h = f2bf(f);
            ahh[c][4 + j] = h; ahl[c][4 + j] = f2bf(f - bf2f(h));
        }
    }
    float hnr[4];
    #pragma unroll
    for (int rg = 0; rg < 4; rg++) hnr[rg] = hn[bm + (quad << 2) + rg];

    float m_old[4], l_old[4];
    #pragma unroll
    for (int rg = 0; rg < 4; rg++) { m_old[rg] = -INFINITY; l_old[rg] = 0.f; }
    f32x4 o0 = (f32x4){0.f, 0.f, 0.f, 0.f};
    f32x4 o1 = (f32x4){0.f, 0.f, 0.f, 0.f};

    for (int jt = 0; jt < NR / 64; jt++) {
        // ---- S tile (16 x 16 per wave) ----
        f32x4 s = (f32x4){0.f, 0.f, 0.f, 0.f};
        int nt = (jt << 2) + wv;
        #pragma unroll
        for (int c = 0; c < 4; c++) {
            size_t bidx = ((size_t)(nt * 4 + c) * 64 + lane) * 8;
            short8 bh = *(const short8*)(Bh + bidx);
            short8 bl = *(const short8*)(Bl + bidx);
            s = MFMA16(ahh[c], bh, s);
            s = MFMA16(ahh[c], bl, s);
            s = MFMA16(ahl[c], bh, s);
        }
        int col = (jt << 6) + (wv << 4) + lm;
        float hc = hhn[col];
        float vm = v2[col];
        float sv[4];
        #pragma unroll
        for (int rg = 0; rg < 4; rg++) {
            float v = s[rg] / fmaxf(hnr[rg] * hc, 1e-12f);
            sv[rg] = (vm == 0.f) ? -1e9f : v;
        }
        // row max across the 16 lm lanes
        float mx[4];
        #pragma unroll
        for (int rg = 0; rg < 4; rg++) {
            float m = sv[rg];
            #pragma unroll
            for (int d = 1; d < 16; d <<= 1) m = fmaxf(m, __shfl_xor(m, d));
            mx[rg] = m;
        }
        if (lm == 0) {
            #pragma unroll
            for (int rg = 0; rg < 4; rg++) redmax[wv][(quad << 2) + rg] = mx[rg];
        }
        __syncthreads();
        float m_new[4], alpha[4];
        #pragma unroll
        for (int rg = 0; rg < 4; rg++) {
            int r = (quad << 2) + rg;
            float mt = fmaxf(fmaxf(redmax[0][r], redmax[1][r]),
                             fmaxf(redmax[2][r], redmax[3][r]));
            m_new[rg] = fmaxf(m_old[rg], mt);
            alpha[rg] = __expf(m_old[rg] - m_new[rg]);
        }
        // P + partial row sums + LDS store (A-layout turn)
        float psum[4];
        #pragma unroll
        for (int rg = 0; rg < 4; rg++) {
            float p = __expf(sv[rg] - m_new[rg]);
            float ssum = p;
            #pragma unroll
            for (int d = 1; d < 16; d <<= 1) ssum += __shfl_xor(ssum, d);
            psum[rg] = ssum;
            int off = ((quad << 2) + rg) * 72 + (wv << 4) + lm;
            unsigned short h = f2bf(p);
            Ph[off] = h;
            Pl[off] = f2bf(p - bf2f(h));
        }
        if (lm == 0) {
            #pragma unroll
            for (int rg = 0; rg < 4; rg++) redsum[wv][(quad << 2) + rg] = psum[rg];
        }
        __syncthreads();
        // l update + O rescale
        #pragma unroll
        for (int rg = 0; rg < 4; rg++) {
            int r = (quad << 2) + rg;
            float ts = redsum[0][r] + redsum[1][r] + redsum[2][r] + redsum[3][r];
            l_old[rg] = l_old[rg] * alpha[rg] + ts;
            m_old[rg] = m_new[rg];
            o0[rg] *= alpha[rg];
            o1[rg] *= alpha[rg];
        }
        // PV: O += P(16x64) @ V(64x32 for this wave's two V-tiles)
        int vt0 = wv << 1;
        #pragma unroll
        for (int c2 = 0; c2 < 2; c2++) {
            int poff = lm * 72 + (c2 << 5) + (quad << 3);
            short8 pah = *(const short8*)&Ph[poff];
            short8 pal = *(const short8*)&Pl[poff];
            int cg = (jt << 1) + c2;      // global k-chunk (over NR)
            size_t b0 = ((size_t)(vt0 * 128 + cg) * 64 + lane) * 8;
            size_t b1 = ((size_t)((vt0 + 1) * 128 + cg) * 64 + lane) * 8;
            short8 vh0 = *(const short8*)(Vh + b0);
            short8 vl0 = *(const short8*)(Vl + b0);
            short8 vh1 = *(const short8*)(Vh + b1);
            short8 vl1 = *(const short8*)(Vl + b1);
            o0 = MFMA16(pah, vh0, o0);
            o0 = MFMA16(pah, vl0, o0);
            o0 = MFMA16(pal, vh0, o0);
            o1 = MFMA16(pah, vh1, o1);
            o1 = MFMA16(pah, vl1, o1);
            o1 = MFMA16(pal, vh1, o1);
        }
        __syncthreads();   // protect Ph/Pl + redmax before next tile
    }
    // epilogue: divide by l, write
    #pragma unroll
    for (int rg = 0; rg < 4; rg++) {
        int row = bm + (quad << 2) + rg;
        float inv = __fdividef(1.f, l_old[rg]);
        O[(size_t)row * HDIM + (wv << 5) + lm] = o0[rg] * inv;
        O[(size_t)row * HDIM + (wv << 5) + 16 + lm] = o1[rg] * inv;
    }
}

// ---------------------------------------------------------------------------
// GRU weight pack
// ---------------------------------------------------------------------------
__global__ void pack_wb(const float* __restrict__ W, unsigned short* __restrict__ Wp,
                        int K, int nch)
{
    int idx = blockIdx.x * 256 + threadIdx.x;
    if (idx >= 24 * nch * 64) return;
    int lane = idx & 63;
    int c = (idx >> 6) % nch;
    int t = idx / (nch * 64);
    int n = t * 16 + (lane & 15);
    int kb = c * 32 + (lane >> 4) * 8;
    #pragma unroll
    for (int j = 0; j < 8; j++) {
        int k = kb + j;
        float f = (k < K) ? W[(size_t)n * K + k] : 0.f;
        Wp[(size_t)idx * 8 + j] = f2bf(f);
    }
}

// x [N, D*T] -> seq [T, N, D]
__global__ void seq_transpose(const float* __restrict__ x, float* __restrict__ seq)
{
    int idx = blockIdx.x * 256 + threadIdx.x;
    int d = idx % DDIM;
    int r = idx / DDIM;
    int n = r & (NR - 1);
    int t = r >> 12;
    seq[idx] = x[(size_t)n * (DDIM * TSTEPS) + d * TSTEPS + t];
}

// ---------------------------------------------------------------------------
// MFMA 2-layer GRU, 8 waves (512 thr). Wave w2 owns gate-col tile w2 in each
// of the r/z/n regions (cols j = w2*16+lm). 2 waves/SIMD for latency hiding.
// ---------------------------------------------------------------------------
__global__ __launch_bounds__(512) void gru_mfma(
    const float* __restrict__ seq,
    const unsigned short* __restrict__ wih0p,
    const unsigned short* __restrict__ whh0p,
    const unsigned short* __restrict__ wih1p,
    const unsigned short* __restrict__ whh1p,
    const float* __restrict__ bih0, const float* __restrict__ bhh0,
    const float* __restrict__ bih1, const float* __restrict__ bhh1,
    float* __restrict__ xh)
{
    __shared__ __attribute__((aligned(16))) unsigned short hA[2][2][16 * 136];
    __shared__ __attribute__((aligned(16))) unsigned short xA[2][2][16 * 40];

    const int tid = threadIdx.x;
    const int w2 = tid >> 6;            // 0..7
    const int lane = tid & 63;
    const int quad = lane >> 4;
    const int lm = lane & 15;
    const int n0 = blockIdx.x << 4;
    const int j = (w2 << 4) + lm;       // owned gate column 0..127

    for (int i = tid; i < 2 * 2 * 16 * 136; i += 512) ((unsigned short*)hA)[i] = 0;
    for (int i = tid; i < 2 * 2 * 16 * 40; i += 512) ((unsigned short*)xA)[i] = 0;

    float br0 = bih0[j] + bhh0[j];
    float bz0 = bih0[128 + j] + bhh0[128 + j];
    float bni0 = bih0[256 + j];
    float bnh0 = bhh0[256 + j];
    float br1 = bih1[j] + bhh1[j];
    float bz1 = bih1[128 + j] + bhh1[128 + j];
    float bni1 = bih1[256 + j];
    float bnh1 = bhh1[256 + j];

    const int aoff = lm * 136 + quad * 8;
    const int xoff = lm * 40 + quad * 8;

    {
        const float* src = seq + (size_t)n0 * DDIM;
        for (int i = tid; i < 16 * DDIM; i += 512) {
            int m = i / DDIM, d = i % DDIM;
            float v = src[i];
            unsigned short hi = f2bf(v);
            xA[0][0][m * 40 + d] = hi;
            xA[0][1][m * 40 + d] = f2bf(v - bf2f(hi));
        }
    }
    __syncthreads();

    for (int t = 0; t < TSTEPS; t++) {
        const int buf = t & 1;
        f32x4 accr = (f32x4){0.f, 0.f, 0.f, 0.f};
        f32x4 accz = (f32x4){0.f, 0.f, 0.f, 0.f};
        f32x4 accni = (f32x4){0.f, 0.f, 0.f, 0.f};
        f32x4 accnh = (f32x4){0.f, 0.f, 0.f, 0.f};

        // ---- layer 0 ----
        {
            short8 axh = *(const short8*)&xA[buf][0][xoff];
            short8 axl = *(const short8*)&xA[buf][1][xoff];
            short8 b;
            b = *(const short8*)&wih0p[(size_t)(w2) * 512 + lane * 8];
            accr = MFMA16(axh, b, accr);
            accr = MFMA16(axl, b, accr);
            b = *(const short8*)&wih0p[(size_t)(8 + w2) * 512 + lane * 8];
            accz = MFMA16(axh, b, accz);
            accz = MFMA16(axl, b, accz);
            b = *(const short8*)&wih0p[(size_t)(16 + w2) * 512 + lane * 8];
            accni = MFMA16(axh, b, accni);
            accni = MFMA16(axl, b, accni);
        }
        #pragma unroll
        for (int c = 0; c < 4; c++) {
            short8 ahh = *(const short8*)&hA[0][0][aoff + c * 32];
            short8 ahl = *(const short8*)&hA[0][1][aoff + c * 32];
            short8 b;
            b = *(const short8*)&whh0p[(size_t)((w2) * 4 + c) * 512 + lane * 8];
            accr = MFMA16(ahh, b, accr);
            accr = MFMA16(ahl, b, accr);
            b = *(const short8*)&whh0p[(size_t)((8 + w2) * 4 + c) * 512 + lane * 8];
            accz = MFMA16(ahh, b, accz);
            accz = MFMA16(ahl, b, accz);
            b = *(const short8*)&whh0p[(size_t)((16 + w2) * 4 + c) * 512 + lane * 8];
            accnh = MFMA16(ahh, b, accnh);
            accnh = MFMA16(ahl, b, accnh);
        }
        float hold[4];
        #pragma unroll
        for (int rg = 0; rg < 4; rg++) {
            int off = (quad * 4 + rg) * 136 + j;
            hold[rg] = bf2f(hA[0][0][off]) + bf2f(hA[0][1][off]);
        }
        __syncthreads();     // B1: all reads of h0 done
        #pragma unroll
        for (int rg = 0; rg < 4; rg++) {
            float r = sigm(accr[rg] + br0);
            float z = sigm(accz[rg] + bz0);
            float nc = tanh_f(accni[rg] + bni0 + r * (accnh[rg] + bnh0));
            float hnew = (1.f - z) * nc + z * hold[rg];
            int off = (quad * 4 + rg) * 136 + j;
            unsigned short hi = f2bf(hnew);
            hA[0][0][off] = hi;
            hA[0][1][off] = f2bf(hnew - bf2f(hi));
        }
        __syncthreads();     // B2: new h0 visible

        // ---- layer 1 ----
        accr = (f32x4){0.f, 0.f, 0.f, 0.f};
        accz = (f32x4){0.f, 0.f, 0.f, 0.f};
        accni = (f32x4){0.f, 0.f, 0.f, 0.f};
        accnh = (f32x4){0.f, 0.f, 0.f, 0.f};
        #pragma unroll
        for (int c = 0; c < 4; c++) {
            short8 a0h = *(const short8*)&hA[0][0][aoff + c * 32];
            short8 a0l = *(const short8*)&hA[0][1][aoff + c * 32];
            short8 a1h = *(const short8*)&hA[1][0][aoff + c * 32];
            short8 a1l = *(const short8*)&hA[1][1][aoff + c * 32];
            short8 b;
            b = *(const short8*)&wih1p[(size_t)((w2) * 4 + c) * 512 + lane * 8];
            accr = MFMA16(a0h, b, accr);
            accr = MFMA16(a0l, b, accr);
            b = *(const short8*)&whh1p[(size_t)((w2) * 4 + c) * 512 + lane * 8];
            accr = MFMA16(a1h, b, accr);
            accr = MFMA16(a1l, b, accr);
            b = *(const short8*)&wih1p[(size_t)((8 + w2) * 4 + c) * 512 + lane * 8];
            accz = MFMA16(a0h, b, accz);
            accz = MFMA16(a0l, b, accz);
            b = *(const short8*)&whh1p[(size_t)((8 + w2) * 4 + c) * 512 + lane * 8];
            accz = MFMA16(a1h, b, accz);
            accz = MFMA16(a1l, b, accz);
            b = *(const short8*)&wih1p[(size_t)((16 + w2) * 4 + c) * 512 + lane * 8];
            accni = MFMA16(a0h, b, accni);
            accni = MFMA16(a0l, b, accni);
            b = *(const short8*)&whh1p[(size_t)((16 + w2) * 4 + c) * 512 + lane * 8];
            accnh = MFMA16(a1h, b, accnh);
            accnh = MFMA16(a1l, b, accnh);
        }
        #pragma unroll
        for (int rg = 0; rg < 4; rg++) {
            int off = (quad * 4 + rg) * 136 + j;
            hold[rg] = bf2f(hA[1][0][off]) + bf2f(hA[1][1][off]);
        }
        if (t + 1 < TSTEPS) {
            const float* src = seq + ((size_t)(t + 1) * NR + n0) * DDIM;
            for (int i = tid; i < 16 * DDIM; i += 512) {
                int m = i / DDIM, d = i % DDIM;
                float v = src[i];
                unsigned short hi = f2bf(v);
                xA[buf ^ 1][0][m * 40 + d] = hi;
                xA[buf ^ 1][1][m * 40 + d] = f2bf(v - bf2f(hi));
            }
        }
        __syncthreads();     // B3: h0/h1 reads + x-stage done
        #pragma unroll
        for (int rg = 0; rg < 4; rg++) {
            float r = sigm(accr[rg] + br1);
            float z = sigm(accz[rg] + bz1);
            float nc = tanh_f(accni[rg] + bni1 + r * (accnh[rg] + bnh1));
            float hnew = (1.f - z) * nc + z * hold[rg];
            int off = (quad * 4 + rg) * 136 + j;
            unsigned short hi = f2bf(hnew);
            hA[1][0][off] = hi;
            hA[1][1][off] = f2bf(hnew - bf2f(hi));
            if (t + 1 == TSTEPS)
                xh[(size_t)(n0 + quad * 4 + rg) * HDIM + j] = hnew;
        }
    }
}

// ---------------------------------------------------------------------------
// Small helpers (unchanged)
// ---------------------------------------------------------------------------
__global__ void den_kernel(const float* __restrict__ cm, const float* __restrict__ mv,
                           float* __restrict__ den)
{
    int c = blockIdx.x * 64 + (threadIdx.x & 63);
    int rg = threadIdx.x >> 6;
    float acc = 0.f;
    for (int n = rg; n < NR; n += 4) acc += cm[(size_t)n * CDIM + c] * mv[n];
    __shared__ float red[4][64];
    red[rg][threadIdx.x & 63] = acc;
    __syncthreads();
    if (rg == 0)
        den[c] = red[0][threadIdx.x] + red[1][threadIdx.x] + red[2][threadIdx.x] + red[3][threadIdx.x];
}

__global__ void s2ct_kernel(const float* __restrict__ cm, const float* __restrict__ mv,
                            const float* __restrict__ den, float* __restrict__ s2cT)
{
    int idx = blockIdx.x * 256 + threadIdx.x;
    int c = idx >> 12, n = idx & (NR - 1);
    float m = cm[(size_t)n * CDIM + c];
    s2cT[idx] = (m * mv[n]) / (den[c] * m + 1.f);
}

__global__ void row_norm(const float* __restrict__ a, float* __restrict__ out)
{
    int r = blockIdx.x;
    float acc = 0.f;
    for (int h = threadIdx.x; h < HDIM; h += 64) {
        float v = a[(size_t)r * HDIM + h];
        acc += v * v;
    }
    for (int o = 32; o > 0; o >>= 1) acc += __shfl_down(acc, o);
    if (threadIdx.x == 0) out[r] = sqrtf(acc);
}

__global__ void row_nonzero(const float* __restrict__ a, float* __restrict__ out)
{
    int r = blockIdx.x;
    float acc = 0.f;
    for (int h = threadIdx.x; h < HDIM; h += 64) acc += a[(size_t)r * HDIM + h];
    for (int o = 32; o > 0; o >>= 1) acc += __shfl_down(acc, o);
    if (threadIdx.x == 0) out[r] = (acc != 0.f) ? 1.f : 0.f;
}

__global__ __launch_bounds__(256) void cos_softmax_row(float* __restrict__ data, int N,
        const float* __restrict__ rn, const float* __restrict__ cn,
        const float* __restrict__ vmask)
{
    int row = blockIdx.x;
    float* d = data + (size_t)row * N;
    int tid = threadIdx.x;
    __shared__ float red[256];
    float rnv = rn ? rn[row] : 0.f;
    float mx = -INFINITY;
    for (int j = tid; j < N; j += 256) {
        float v = d[j];
        if (cn) v = v / fmaxf(rnv * cn[j], 1e-12f);
        if (vmask && vmask[j] == 0.f) v = -1e9f;
        d[j] = v;
        mx = fmaxf(mx, v);
    }
    red[tid] = mx; __syncthreads();
    for (int sdx = 128; sdx > 0; sdx >>= 1) {
        if (tid < sdx) red[tid] = fmaxf(red[tid], red[tid + sdx]);
        __syncthreads();
    }
    float M = red[0]; __syncthreads();
    float sum = 0.f;
    for (int j = tid; j < N; j += 256) {
        float e = expf(d[j] - M);
        d[j] = e;
        sum += e;
    }
    red[tid] = sum; __syncthreads();
    for (int sdx = 128; sdx > 0; sdx >>= 1) {
        if (tid < sdx) red[tid] += red[tid + sdx];
        __syncthreads();
    }
    float inv = 1.f / red[0];
    for (int j = tid; j < N; j += 256) {
        float v = d[j] * inv;
        if (vmask) v *= vmask[j];
        d[j] = v;
    }
}

__global__ void colsum_scatter(const float* __restrict__ vals, const int* __restrict__ idxs,
                               float* __restrict__ colsum)
{
    int idx = blockIdx.x * 256 + threadIdx.x;
    if (idx < NR * KTOP) atomicAdd(&colsum[idxs[idx]], vals[idx]);
}

__global__ void hh_scatter(const float* __restrict__ vals, const int* __restrict__ idxs,
                           const float* __restrict__ hsh, float* __restrict__ hh)
{
    int p = blockIdx.x;
    int j = idxs[p];
    float v = vals[p];
    int i = p / KTOP;
    atomicAdd(&hh[(size_t)j * HDIM + threadIdx.x], v * hsh[(size_t)i * HDIM + threadIdx.x]);
}

__global__ void hh_diag(const float* __restrict__ colsum, const float* __restrict__ diag,
                        const float* __restrict__ hsh, float* __restrict__ hh)
{
    int idx = blockIdx.x * 256 + threadIdx.x;
    int j = idx >> 7;
    if (colsum[j] != 0.f) hh[idx] += diag[j] * hsh[idx];
}

__global__ void sub2_kernel(const float* __restrict__ a, const float* __restrict__ b,
                            float* __restrict__ o)
{
    int i = blockIdx.x * 256 + threadIdx.x;
    o[i] = a[i] - b[i];
}

__global__ void sub3_kernel(const float* __restrict__ a, const float* __restrict__ b,
                            const float* __restrict__ c, float* __restrict__ o)
{
    int i = blockIdx.x * 256 + threadIdx.x;
    o[i] = a[i] - b[i] - c[i];
}

__global__ void head_kernel(const float* __restrict__ ps, const float* __restrict__ hs,
                            const float* __restrict__ indi, const float* __restrict__ w,
                            const float* __restrict__ b, float* __restrict__ out)
{
    int n = blockIdx.x;
    int t = threadIdx.x;
    float acc = 0.f;
    for (int h = t; h < HDIM; h += 64) {
        size_t k = (size_t)n * HDIM + h;
        acc += (ps[k] + hs[k] + indi[k]) * w[h];
    }
    for (int o = 32; o > 0; o >>= 1) acc += __shfl_down(acc, o);
    if (t == 0) out[n] = acc + b[0];
}

// ---------------------------------------------------------------------------
// host-side helpers
// ---------------------------------------------------------------------------
static inline void mg(hipStream_t s, const float* A, const unsigned short* Bh,
                      const unsigned short* Bl, const float* bias, float* C,
                      int M, int N, int K, int z, int flags)
{
    MG g{A, Bh, Bl, bias, C, N, K, K / z, flags | (z > 1 ? 4 : 0)};
    mfma_gemm<<<dim3(N / 64, M / 64, z), 256, 0, s>>>(g);
}
static inline void pbt(hipStream_t s, const float* src, unsigned short* hi,
                       unsigned short* lo, int N, int K)
{
    int total = (N / 16) * (K / 32) * 64;
    pack_bt<<<(total + 255) / 256, 256, 0, s>>>(src, hi, lo, K, total);
}
static inline void pkn(hipStream_t s, const float* src, unsigned short* hi,
                       unsigned short* lo, int K, int N)
{
    int total = (N / 16) * (K / 32) * 64;
    pack_kn<<<(total + 255) / 256, 256, 0, s>>>(src, hi, lo, K, N, total);
}

extern "C" void kernel_launch(void* const* d_in, const int* in_sizes, int n_in,
                              void* d_out, int out_size, void* d_ws, size_t ws_size,
                              hipStream_t stream)
{
    (void)in_sizes; (void)n_in; (void)out_size; (void)ws_size;
    const float* x    = (const float*)d_in[0];
    const float* cm   = (const float*)d_in[1];
    const float* mv   = (const float*)d_in[2];
    const float* wih0 = (const float*)d_in[3];
    const float* whh0 = (const float*)d_in[4];
    const float* bih0 = (const float*)d_in[5];
    const float* bhh0 = (const float*)d_in[6];
    const float* wih1 = (const float*)d_in[7];
    const float* whh1 = (const float*)d_in[8];
    const float* bih1 = (const float*)d_in[9];
    const float* bhh1 = (const float*)d_in[10];
    const float* w_ps = (const float*)d_in[11];
    const float* b_ps = (const float*)d_in[12];
    const float* w_hs = (const float*)d_in[13];
    const float* b_hs = (const float*)d_in[14];
    const float* w_ps_fore = (const float*)d_in[15];
    const float* b_ps_fore = (const float*)d_in[16];
    const float* w_hs_fore = (const float*)d_in[17];
    const float* b_hs_fore = (const float*)d_in[18];
    const float* w_ps_back = (const float*)d_in[19];
    const float* b_ps_back = (const float*)d_in[20];
    const float* w_hs_back = (const float*)d_in[21];
    const float* b_hs_back = (const float*)d_in[22];
    const float* w_indi = (const float*)d_in[23];
    const float* b_indi = (const float*)d_in[24];
    const float* w_out  = (const float*)d_in[25];
    const float* b_out  = (const float*)d_in[26];
    float* out = (float*)d_out;

    // ---- workspace layout (floats) ----
    float* ws = (float*)d_ws;
    float* BIG = ws;                         // 16,777,216 (overlaid)
    float* h0 = ws + 16777216;               // 524288 (unused)
    float* h1 = h0 + 524288;                 // x_hidden
    float* den = h1 + 524288;                // 512
    float* v1 = den + 512;                   // 512
    float* hidden = v1 + 512;                // 65536
    float* hidden2 = hidden + 65536;         // 65536
    float* xnorm = hidden2 + 65536;          // 4096
    float* h2n = xnorm + 4096;               // 512
    float* p0 = h2n + 512;                   // 524288
    float* p_shared = p0 + 524288;
    float* p_back = p_shared + 524288;
    float* out_ps = p_back + 524288;
    float* h_shared = out_ps + 524288;
    float* hn = h_shared + 524288;           // 4096
    float* diagv = hn + 4096;                // 4096
    float* colsum = diagv + 4096;            // 4096
    float* tvals = colsum + 4096;            // 40960
    int*   tidx = (int*)(tvals + 40960);     // 40960 ints
    float* hidden_h = (float*)(tidx + 40960);
    float* v2 = hidden_h + 524288;           // 4096
    float* hhn = v2 + 4096;                  // 4096
    float* hsi0 = hhn + 4096;                // 524288
    float* h_si = hsi0 + 524288;
    float* h_back = h_si + 524288;
    float* out_hs = h_back + 524288;
    float* indi = out_hs + 524288;
    float* out_indi = indi + 524288;
    float* extra = out_indi + 524288;        // small phase-C/D weight packs

    // GRU-phase overlays inside BIG:
    float* seqt = BIG;
    unsigned short* wih0p = (unsigned short*)(BIG + 5242880);
    unsigned short* whh0p = wih0p + 12288;
    unsigned short* wih1p = whh0p + 49152;
    unsigned short* whh1p = wih1p + 49152;
    // concept-phase overlays inside BIG:
    float* s2cT = BIG;                       // [0 .. 2M)
    float* L    = BIG + 2097152;             // [2M .. 4M)
    float* c2s  = BIG + 4194304;             // [4M .. 6M)
    // phase-B pack area inside BIG [6M ..): dead before the big S GEMM
    unsigned short* PB = (unsigned short*)(BIG + 6291456);
    unsigned short* pbt_xh_hi = PB;                  // 524288
    unsigned short* pbt_xh_lo = pbt_xh_hi + 524288;
    unsigned short* pkn_xh_hi = pbt_xh_lo + 524288;
    unsigned short* pkn_xh_lo = pkn_xh_hi + 524288;
    unsigned short* pbt_h2_hi = pkn_xh_lo + 524288;  // 65536
    unsigned short* pbt_h2_lo = pbt_h2_hi + 65536;
    unsigned short* pkn_h2_hi = pbt_h2_lo + 65536;
    unsigned short* pkn_h2_lo = pkn_h2_hi + 65536;
    unsigned short* wps_hi  = pkn_h2_lo + 65536;     // 16384 each
    unsigned short* wps_lo  = wps_hi + 16384;
    unsigned short* wpsb_hi = wps_lo + 16384;
    unsigned short* wpsb_lo = wpsb_hi + 16384;
    unsigned short* wpsf_hi = wpsb_lo + 16384;
    unsigned short* wpsf_lo = wpsf_hi + 16384;
    // phase-C packs overlay dead fp32 buffers:
    unsigned short* pbt_hsh_hi = (unsigned short*)p0;         // p0 dead after p_shared
    unsigned short* pbt_hsh_lo = pbt_hsh_hi + 524288;
    unsigned short* pbt_hh_hi = (unsigned short*)indi;        // dead until sub3
    unsigned short* pbt_hh_lo = pbt_hh_hi + 524288;
    unsigned short* pkn_hh_hi = (unsigned short*)out_indi;    // dead until w_indi gemm
    unsigned short* pkn_hh_lo = pkn_hh_hi + 524288;
    unsigned short* EX = (unsigned short*)extra;
    unsigned short* whs_hi  = EX;            unsigned short* whs_lo  = EX + 16384;
    unsigned short* whsb_hi = EX + 32768;    unsigned short* whsb_lo = EX + 49152;
    unsigned short* whsf_hi = EX + 65536;    unsigned short* whsf_lo = EX + 81920;
    unsigned short* wind_hi = EX + 98304;    unsigned short* wind_lo = EX + 114688;

    // ================= Phase A: MFMA 2-layer GRU =================
    seq_transpose<<<(TSTEPS * NR * DDIM) / 256, 256, 0, stream>>>(x, seqt);
    pack_wb<<<6, 256, 0, stream>>>(wih0, wih0p, DDIM, 1);
    pack_wb<<<24, 256, 0, stream>>>(whh0, whh0p, HDIM, 4);
    pack_wb<<<24, 256, 0, stream>>>(wih1, wih1p, HDIM, 4);
    pack_wb<<<24, 256, 0, stream>>>(whh1, whh1p, HDIM, 4);
    gru_mfma<<<NR / 16, 512, 0, stream>>>(seqt, wih0p, whh0p, wih1p, whh1p,
                                          bih0, bhh0, bih1, bhh1, h1);
    float* x_hidden = h1;

    // ================= Phase B: predefined-concept branch =================
    den_kernel<<<8, 256, 0, stream>>>(cm, mv, den);
    s2ct_kernel<<<(CDIM * NR) / 256, 256, 0, stream>>>(cm, mv, den, s2cT);
    pkn(stream, x_hidden, pkn_xh_hi, pkn_xh_lo, NR, HDIM);
    pbt(stream, x_hidden, pbt_xh_hi, pbt_xh_lo, NR, HDIM);
    hipMemsetAsync(hidden, 0, 65536 * sizeof(float), stream);
    mg(stream, s2cT, pkn_xh_hi, pkn_xh_lo, nullptr, hidden, CDIM, HDIM, NR, 8, 0);
    row_nonzero<<<CDIM, 64, 0, stream>>>(hidden, v1);
    mg(stream, hidden, pbt_xh_hi, pbt_xh_lo, nullptr, L, CDIM, NR, HDIM, 1, 0);
    cos_softmax_row<<<CDIM, 256, 0, stream>>>(L, NR, nullptr, nullptr, nullptr);
    hipMemsetAsync(hidden2, 0, 65536 * sizeof(float), stream);
    mg(stream, L, pkn_xh_hi, pkn_xh_lo, nullptr, hidden2, CDIM, HDIM, NR, 8, 0);
    row_norm<<<NR, 64, 0, stream>>>(x_hidden, xnorm);
    row_norm<<<CDIM, 64, 0, stream>>>(hidden2, h2n);
    pbt(stream, hidden2, pbt_h2_hi, pbt_h2_lo, CDIM, HDIM);
    pkn(stream, hidden2, pkn_h2_hi, pkn_h2_lo, CDIM, HDIM);
    mg(stream, x_hidden, pbt_h2_hi, pbt_h2_lo, nullptr, c2s, NR, CDIM, HDIM, 1, 0);
    cos_softmax_row<<<NR, 256, 0, stream>>>(c2s, CDIM, xnorm, h2n, v1);
    hipMemsetAsync(p0, 0, 524288 * sizeof(float), stream);
    mg(stream, c2s, pkn_h2_hi, pkn_h2_lo, nullptr, p0, NR, HDIM, CDIM, 2, 0);
    pbt(stream, w_ps, wps_hi, wps_lo, HDIM, HDIM);
    pbt(stream, w_ps_back, wpsb_hi, wpsb_lo, HDIM, HDIM);
    pbt(stream, w_ps_fore, wpsf_hi, wpsf_lo, HDIM, HDIM);
    mg(stream, p0, wps_hi, wps_lo, b_ps, p_shared, NR, HDIM, HDIM, 1, 1);
    mg(stream, p_shared, wpsb_hi, wpsb_lo, b_ps_back, p_back, NR, HDIM, HDIM, 1, 1);
    mg(stream, p_shared, wpsf_hi, wpsf_lo, b_ps_fore, out_ps, NR, HDIM, HDIM, 1, 1 | 2);

    // ================= Phase C: hidden-concept branch =================
    sub2_kernel<<<2048, 256, 0, stream>>>(x_hidden, p_back, h_shared);
    row_norm<<<NR, 64, 0, stream>>>(h_shared, hn);
    pbt(stream, h_shared, pbt_hsh_hi, pbt_hsh_lo, NR, HDIM);
    mg(stream, h_shared, pbt_hsh_hi, pbt_hsh_lo, nullptr, BIG, NR, NR, HDIM, 1, 0);
    scan_topk<<<NR, 256, 0, stream>>>(BIG, hn, diagv, tvals, tidx);
    hipMemsetAsync(colsum, 0, NR * sizeof(float), stream);
    hipMemsetAsync(hidden_h, 0, 524288 * sizeof(float), stream);
    colsum_scatter<<<(NR * KTOP + 255) / 256, 256, 0, stream>>>(tvals, tidx, colsum);
    hh_scatter<<<NR * KTOP, HDIM, 0, stream>>>(tvals, tidx, h_shared, hidden_h);
    hh_diag<<<2048, 256, 0, stream>>>(colsum, diagv, h_shared, hidden_h);
    row_nonzero<<<NR, 64, 0, stream>>>(hidden_h, v2);
    row_norm<<<NR, 64, 0, stream>>>(hidden_h, hhn);
    pbt(stream, hidden_h, pbt_hh_hi, pbt_hh_lo, NR, HDIM);
    pkn(stream, hidden_h, pkn_hh_hi, pkn_hh_lo, NR, HDIM);
    hc2s_flash<<<NR / 16, 256, 0, stream>>>(h_shared, hn, hhn, v2,
                                            pbt_hh_hi, pbt_hh_lo,
                                            pkn_hh_hi, pkn_hh_lo, hsi0);
    pbt(stream, w_hs, whs_hi, whs_lo, HDIM, HDIM);
    pbt(stream, w_hs_back, whsb_hi, whsb_lo, HDIM, HDIM);
    pbt(stream, w_hs_fore, whsf_hi, whsf_lo, HDIM, HDIM);
    mg(stream, hsi0, whs_hi, whs_lo, b_hs, h_si, NR, HDIM, HDIM, 1, 1);
    mg(stream, h_si, whsb_hi, whsb_lo, b_hs_back, h_back, NR, HDIM, HDIM, 1, 1);
    mg(stream, h_si, whsf_hi, whsf_lo, b_hs_fore, out_hs, NR, HDIM, HDIM, 1, 1 | 2);

    // ================= Phase D: individual branch + head =================
    sub3_kernel<<<2048, 256, 0, stream>>>(x_hidden, p_back, h_back, indi);
    pbt(stream, w_indi, wind_hi, wind_lo, HDIM, HDIM);
    mg(stream, indi, wind_hi, wind_lo, b_indi, out_indi, NR, HDIM, HDIM, 1, 1 | 2);
    head_kernel<<<NR, 64, 0, stream>>>(out_ps, out_hs, out_indi, w_out, b_out, out);
}

// Round 8
// 967.571 us; speedup vs baseline: 7.7107x; 1.2468x over previous
//
#include <hip/hip_runtime.h>
#include <cstddef>

// Problem dims
#define NR 4096      // batch
#define CDIM 512     // concepts
#define HDIM 128     // hidden
#define TSTEPS 64
#define DDIM 20
#define KTOP 10

typedef __attribute__((ext_vector_type(8))) short short8;
typedef __attribute__((ext_vector_type(4))) float f32x4;

__device__ __forceinline__ unsigned short f2bf(float f) {
    union { float f; unsigned u; } x; x.f = f;
    unsigned r = (x.u + 0x7fffu + ((x.u >> 16) & 1u)) >> 16;
    return (unsigned short)r;
}
__device__ __forceinline__ float bf2f(unsigned short h) {
    union { unsigned u; float f; } x; x.u = ((unsigned)h) << 16;
    return x.f;
}
__device__ __forceinline__ float sigm(float v) {
    float c = fminf(fmaxf(v, -30.f), 30.f);
    return __fdividef(1.f, 1.f + __expf(-c));
}
__device__ __forceinline__ float tanh_f(float v) {
    float c = fminf(fmaxf(v, -10.f), 10.f);
    float e = __expf(2.f * c);
    return __fdividef(e - 1.f, e + 1.f);
}

#define MFMA16(a, b, c) __builtin_amdgcn_mfma_f32_16x16x32_bf16(a, b, c, 0, 0, 0)

// ---------------------------------------------------------------------------
// Generic MFMA GEMM (unchanged)
// ---------------------------------------------------------------------------
struct MG {
    const float* A; const unsigned short* Bh; const unsigned short* Bl;
    const float* bias; float* C; int N, K, kchunk, flags;
};

__global__ __launch_bounds__(256) void mfma_gemm(MG g)
{
    const int tid = threadIdx.x;
    const int w = tid >> 6, lane = tid & 63, quad = lane >> 4, lm = lane & 15;
    const int bm = (blockIdx.y << 6) + (w << 4);
    const int bn = blockIdx.x << 6;
    const int NC = g.K >> 5;
    const int c0 = (blockIdx.z * g.kchunk) >> 5;
    const int c1 = c0 + (g.kchunk >> 5);
    const float* arow = g.A + (size_t)(bm + lm) * g.K;
    f32x4 acc[4];
    #pragma unroll
    for (int t = 0; t < 4; t++) acc[t] = (f32x4){0.f, 0.f, 0.f, 0.f};

    for (int c = c0; c < c1; c++) {
        const float* ap = arow + (c << 5) + (quad << 3);
        float4 a0 = *(const float4*)ap;
        float4 a1 = *(const float4*)(ap + 4);
        short8 ah, al;
        #pragma unroll
        for (int j = 0; j < 4; j++) {
            float f = (&a0.x)[j];
            unsigned short h = f2bf(f);
            ah[j] = h; al[j] = f2bf(f - bf2f(h));
            f = (&a1.x)[j];
            h = f2bf(f);
            ah[4 + j] = h; al[4 + j] = f2bf(f - bf2f(h));
        }
        #pragma unroll
        for (int t = 0; t < 4; t++) {
            size_t bidx = ((size_t)(((bn >> 4) + t) * NC + c) * 64 + lane) * 8;
            short8 bh = *(const short8*)(g.Bh + bidx);
            short8 bl = *(const short8*)(g.Bl + bidx);
            acc[t] = MFMA16(ah, bh, acc[t]);
            acc[t] = MFMA16(ah, bl, acc[t]);
            acc[t] = MFMA16(al, bh, acc[t]);
        }
    }
    #pragma unroll
    for (int t = 0; t < 4; t++) {
        #pragma unroll
        for (int rg = 0; rg < 4; rg++) {
            int row = bm + (quad << 2) + rg;
            int col = bn + (t << 4) + lm;
            float v = acc[t][rg];
            if (g.flags & 1) v += g.bias[col];
            if (g.flags & 2) v = v > 0.f ? v : 0.01f * v;
            if (g.flags & 4) atomicAdd(&g.C[(size_t)row * g.N + col], v);
            else g.C[(size_t)row * g.N + col] = v;
        }
    }
}

// B-pack from [N,K] rows; layout [nt][c][lane][8], hi/lo planes.
__global__ void pack_bt(const float* __restrict__ src, unsigned short* __restrict__ hi,
                        unsigned short* __restrict__ lo, int K, int total)
{
    int idx = blockIdx.x * 256 + threadIdx.x;
    if (idx >= total) return;
    int NC = K >> 5;
    int lane = idx & 63;
    int c = (idx >> 6) % NC;
    int t = idx / (NC * 64);
    int n = (t << 4) + (lane & 15);
    int kb = (c << 5) + ((lane >> 4) << 3);
    #pragma unroll
    for (int j = 0; j < 8; j++) {
        float f = src[(size_t)n * K + kb + j];
        unsigned short h = f2bf(f);
        hi[(size_t)idx * 8 + j] = h;
        lo[(size_t)idx * 8 + j] = f2bf(f - bf2f(h));
    }
}

// B-pack from [K,N]
__global__ void pack_kn(const float* __restrict__ src, unsigned short* __restrict__ hi,
                        unsigned short* __restrict__ lo, int K, int N, int total)
{
    int idx = blockIdx.x * 256 + threadIdx.x;
    if (idx >= total) return;
    int NC = K >> 5;
    int lane = idx & 63;
    int c = (idx >> 6) % NC;
    int t = idx / (NC * 64);
    int n = (t << 4) + (lane & 15);
    int kb = (c << 5) + ((lane >> 4) << 3);
    #pragma unroll
    for (int j = 0; j < 8; j++) {
        float f = src[(size_t)(kb + j) * N + n];
        unsigned short h = f2bf(f);
        hi[(size_t)idx * 8 + j] = h;
        lo[(size_t)idx * 8 + j] = f2bf(f - bf2f(h));
    }
}

// ---------------------------------------------------------------------------
// scan_topk (unchanged)
// ---------------------------------------------------------------------------
__global__ __launch_bounds__(256) void scan_topk(const float* __restrict__ S,
        const float* __restrict__ hn, float* __restrict__ diagv,
        float* __restrict__ tvals, int* __restrict__ tidx)
{
    int row = blockIdx.x;
    const float* d = S + (size_t)row * NR;
    int tid = threadIdx.x;
    float hi_ = hn[row];
    float lv[16]; int li[16];
    #pragma unroll
    for (int i = 0; i < 16; i++) {
        int j = tid + i * 256;
        float v = d[j] / fmaxf(hi_ * hn[j], 1e-12f);
        if (j == row) { diagv[row] = v; v = 0.f; }
        lv[i] = v;
        li[i] = j;
    }
    __shared__ float sv[256];
    __shared__ int si[256];
    for (int k = 0; k < KTOP; k++) {
        float bv = -INFINITY; int bi = 0x7fffffff;
        #pragma unroll
        for (int i = 0; i < 16; i++) {
            if (lv[i] > bv || (lv[i] == bv && li[i] < bi)) { bv = lv[i]; bi = li[i]; }
        }
        sv[tid] = bv; si[tid] = bi;
        __syncthreads();
        for (int sdx = 128; sdx > 0; sdx >>= 1) {
            if (tid < sdx) {
                if (sv[tid + sdx] > sv[tid] || (sv[tid + sdx] == sv[tid] && si[tid + sdx] < si[tid])) {
                    sv[tid] = sv[tid + sdx]; si[tid] = si[tid + sdx];
                }
            }
            __syncthreads();
        }
        if (tid == 0) { tvals[row * KTOP + k] = sv[0]; tidx[row * KTOP + k] = si[0]; }
        int wn = si[0];
        if ((wn & 255) == tid) lv[wn >> 8] = -INFINITY;
        __syncthreads();
    }
}

// ---------------------------------------------------------------------------
// hc2s_flash (unchanged from round 7)
// ---------------------------------------------------------------------------
__global__ __launch_bounds__(256) void hc2s_flash(
    const float* __restrict__ hsh, const float* __restrict__ hn,
    const float* __restrict__ hhn, const float* __restrict__ v2,
    const unsigned short* __restrict__ Bh, const unsigned short* __restrict__ Bl,
    const unsigned short* __restrict__ Vh, const unsigned short* __restrict__ Vl,
    float* __restrict__ O)
{
    __shared__ __attribute__((aligned(16))) unsigned short Ph[16 * 72];
    __shared__ __attribute__((aligned(16))) unsigned short Pl[16 * 72];
    __shared__ float redmax[4][16];
    __shared__ float redsum[4][16];

    const int tid = threadIdx.x;
    const int wv = tid >> 6, lane = tid & 63, quad = lane >> 4, lm = lane & 15;
    const int bm = blockIdx.x << 4;

    short8 ahh[4], ahl[4];
    #pragma unroll
    for (int c = 0; c < 4; c++) {
        const float* ap = hsh + (size_t)(bm + lm) * HDIM + (c << 5) + (quad << 3);
        float4 a0 = *(const float4*)ap;
        float4 a1 = *(const float4*)(ap + 4);
        #pragma unroll
        for (int j = 0; j < 4; j++) {
            float f = (&a0.x)[j];
            unsigned short h = f2bf(f);
            ahh[c][j] = h; ahl[c][j] = f2bf(f - bf2f(h));
            f = (&a1.x)[j];
            h = f2bf(f);
            ahh[c][4 + j] = h; ahl[c][4 + j] = f2bf(f - bf2f(h));
        }
    }
    float hnr[4];
    #pragma unroll
    for (int rg = 0; rg < 4; rg++) hnr[rg] = hn[bm + (quad << 2) + rg];

    float m_old[4], l_old[4];
    #pragma unroll
    for (int rg = 0; rg < 4; rg++) { m_old[rg] = -INFINITY; l_old[rg] = 0.f; }
    f32x4 o0 = (f32x4){0.f, 0.f, 0.f, 0.f};
    f32x4 o1 = (f32x4){0.f, 0.f, 0.f, 0.f};

    for (int jt = 0; jt < NR / 64; jt++) {
        f32x4 s = (f32x4){0.f, 0.f, 0.f, 0.f};
        int nt = (jt << 2) + wv;
        #pragma unroll
        for (int c = 0; c < 4; c++) {
            size_t bidx = ((size_t)(nt * 4 + c) * 64 + lane) * 8;
            short8 bh = *(const short8*)(Bh + bidx);
            short8 bl = *(const short8*)(Bl + bidx);
            s = MFMA16(ahh[c], bh, s);
            s = MFMA16(ahh[c], bl, s);
            s = MFMA16(ahl[c], bh, s);
        }
        int col = (jt << 6) + (wv << 4) + lm;
        float hc = hhn[col];
        float vm = v2[col];
        float sv[4];
        #pragma unroll
        for (int rg = 0; rg < 4; rg++) {
            float v = s[rg] / fmaxf(hnr[rg] * hc, 1e-12f);
            sv[rg] = (vm == 0.f) ? -1e9f : v;
        }
        float mx[4];
        #pragma unroll
        for (int rg = 0; rg < 4; rg++) {
            float m = sv[rg];
            #pragma unroll
            for (int d = 1; d < 16; d <<= 1) m = fmaxf(m, __shfl_xor(m, d));
            mx[rg] = m;
        }
        if (lm == 0) {
            #pragma unroll
            for (int rg = 0; rg < 4; rg++) redmax[wv][(quad << 2) + rg] = mx[rg];
        }
        __syncthreads();
        float m_new[4], alpha[4];
        #pragma unroll
        for (int rg = 0; rg < 4; rg++) {
            int r = (quad << 2) + rg;
            float mt = fmaxf(fmaxf(redmax[0][r], redmax[1][r]),
                             fmaxf(redmax[2][r], redmax[3][r]));
            m_new[rg] = fmaxf(m_old[rg], mt);
            alpha[rg] = __expf(m_old[rg] - m_new[rg]);
        }
        float psum[4];
        #pragma unroll
        for (int rg = 0; rg < 4; rg++) {
            float p = __expf(sv[rg] - m_new[rg]);
            float ssum = p;
            #pragma unroll
            for (int d = 1; d < 16; d <<= 1) ssum += __shfl_xor(ssum, d);
            psum[rg] = ssum;
            int off = ((quad << 2) + rg) * 72 + (wv << 4) + lm;
            unsigned short h = f2bf(p);
            Ph[off] = h;
            Pl[off] = f2bf(p - bf2f(h));
        }
        if (lm == 0) {
            #pragma unroll
            for (int rg = 0; rg < 4; rg++) redsum[wv][(quad << 2) + rg] = psum[rg];
        }
        __syncthreads();
        #pragma unroll
        for (int rg = 0; rg < 4; rg++) {
            int r = (quad << 2) + rg;
            float ts = redsum[0][r] + redsum[1][r] + redsum[2][r] + redsum[3][r];
            l_old[rg] = l_old[rg] * alpha[rg] + ts;
            m_old[rg] = m_new[rg];
            o0[rg] *= alpha[rg];
            o1[rg] *= alpha[rg];
        }
        int vt0 = wv << 1;
        #pragma unroll
        for (int c2 = 0; c2 < 2; c2++) {
            int poff = lm * 72 + (c2 << 5) + (quad << 3);
            short8 pah = *(const short8*)&Ph[poff];
            short8 pal = *(const short8*)&Pl[poff];
            int cg = (jt << 1) + c2;
            size_t b0 = ((size_t)(vt0 * 128 + cg) * 64 + lane) * 8;
            size_t b1 = ((size_t)((vt0 + 1) * 128 + cg) * 64 + lane) * 8;
            short8 vh0 = *(const short8*)(Vh + b0);
            short8 vl0 = *(const short8*)(Vl + b0);
            short8 vh1 = *(const short8*)(Vh + b1);
            short8 vl1 = *(const short8*)(Vl + b1);
            o0 = MFMA16(pah, vh0, o0);
            o0 = MFMA16(pah, vl0, o0);
            o0 = MFMA16(pal, vh0, o0);
            o1 = MFMA16(pah, vh1, o1);
            o1 = MFMA16(pah, vl1, o1);
            o1 = MFMA16(pal, vh1, o1);
        }
        __syncthreads();
    }
    #pragma unroll
    for (int rg = 0; rg < 4; rg++) {
        int row = bm + (quad << 2) + rg;
        float inv = __fdividef(1.f, l_old[rg]);
        O[(size_t)row * HDIM + (wv << 5) + lm] = o0[rg] * inv;
        O[(size_t)row * HDIM + (wv << 5) + 16 + lm] = o1[rg] * inv;
    }
}

// ---------------------------------------------------------------------------
// GRU weight pack
// ---------------------------------------------------------------------------
__global__ void pack_wb(const float* __restrict__ W, unsigned short* __restrict__ Wp,
                        int K, int nch)
{
    int idx = blockIdx.x * 256 + threadIdx.x;
    if (idx >= 24 * nch * 64) return;
    int lane = idx & 63;
    int c = (idx >> 6) % nch;
    int t = idx / (nch * 64);
    int n = t * 16 + (lane & 15);
    int kb = c * 32 + (lane >> 4) * 8;
    #pragma unroll
    for (int j = 0; j < 8; j++) {
        int k = kb + j;
        float f = (k < K) ? W[(size_t)n * K + k] : 0.f;
        Wp[(size_t)idx * 8 + j] = f2bf(f);
    }
}

// x [N, D*T] -> seq [T, N, D]
__global__ void seq_transpose(const float* __restrict__ x, float* __restrict__ seq)
{
    int idx = blockIdx.x * 256 + threadIdx.x;
    int d = idx % DDIM;
    int r = idx / DDIM;
    int n = r & (NR - 1);
    int t = r >> 12;
    seq[idx] = x[(size_t)n * (DDIM * TSTEPS) + d * TSTEPS + t];
}

// ---------------------------------------------------------------------------
// MFMA 2-layer GRU, 8 waves (unchanged from round 7)
// ---------------------------------------------------------------------------
__global__ __launch_bounds__(512) void gru_mfma(
    const float* __restrict__ seq,
    const unsigned short* __restrict__ wih0p,
    const unsigned short* __restrict__ whh0p,
    const unsigned short* __restrict__ wih1p,
    const unsigned short* __restrict__ whh1p,
    const float* __restrict__ bih0, const float* __restrict__ bhh0,
    const float* __restrict__ bih1, const float* __restrict__ bhh1,
    float* __restrict__ xh)
{
    __shared__ __attribute__((aligned(16))) unsigned short hA[2][2][16 * 136];
    __shared__ __attribute__((aligned(16))) unsigned short xA[2][2][16 * 40];

    const int tid = threadIdx.x;
    const int w2 = tid >> 6;
    const int lane = tid & 63;
    const int quad = lane >> 4;
    const int lm = lane & 15;
    const int n0 = blockIdx.x << 4;
    const int j = (w2 << 4) + lm;

    for (int i = tid; i < 2 * 2 * 16 * 136; i += 512) ((unsigned short*)hA)[i] = 0;
    for (int i = tid; i < 2 * 2 * 16 * 40; i += 512) ((unsigned short*)xA)[i] = 0;

    float br0 = bih0[j] + bhh0[j];
    float bz0 = bih0[128 + j] + bhh0[128 + j];
    float bni0 = bih0[256 + j];
    float bnh0 = bhh0[256 + j];
    float br1 = bih1[j] + bhh1[j];
    float bz1 = bih1[128 + j] + bhh1[128 + j];
    float bni1 = bih1[256 + j];
    float bnh1 = bhh1[256 + j];

    const int aoff = lm * 136 + quad * 8;
    const int xoff = lm * 40 + quad * 8;

    {
        const float* src = seq + (size_t)n0 * DDIM;
        for (int i = tid; i < 16 * DDIM; i += 512) {
            int m = i / DDIM, d = i % DDIM;
            float v = src[i];
            unsigned short hi = f2bf(v);
            xA[0][0][m * 40 + d] = hi;
            xA[0][1][m * 40 + d] = f2bf(v - bf2f(hi));
        }
    }
    __syncthreads();

    for (int t = 0; t < TSTEPS; t++) {
        const int buf = t & 1;
        f32x4 accr = (f32x4){0.f, 0.f, 0.f, 0.f};
        f32x4 accz = (f32x4){0.f, 0.f, 0.f, 0.f};
        f32x4 accni = (f32x4){0.f, 0.f, 0.f, 0.f};
        f32x4 accnh = (f32x4){0.f, 0.f, 0.f, 0.f};

        // ---- layer 0 ----
        {
            short8 axh = *(const short8*)&xA[buf][0][xoff];
            short8 axl = *(const short8*)&xA[buf][1][xoff];
            short8 b;
            b = *(const short8*)&wih0p[(size_t)(w2) * 512 + lane * 8];
            accr = MFMA16(axh, b, accr);
            accr = MFMA16(axl, b, accr);
            b = *(const short8*)&wih0p[(size_t)(8 + w2) * 512 + lane * 8];
            accz = MFMA16(axh, b, accz);
            accz = MFMA16(axl, b, accz);
            b = *(const short8*)&wih0p[(size_t)(16 + w2) * 512 + lane * 8];
            accni = MFMA16(axh, b, accni);
            accni = MFMA16(axl, b, accni);
        }
        #pragma unroll
        for (int c = 0; c < 4; c++) {
            short8 ahh = *(const short8*)&hA[0][0][aoff + c * 32];
            short8 ahl = *(const short8*)&hA[0][1][aoff + c * 32];
            short8 b;
            b = *(const short8*)&whh0p[(size_t)((w2) * 4 + c) * 512 + lane * 8];
            accr = MFMA16(ahh, b, accr);
            accr = MFMA16(ahl, b, accr);
            b = *(const short8*)&whh0p[(size_t)((8 + w2) * 4 + c) * 512 + lane * 8];
            accz = MFMA16(ahh, b, accz);
            accz = MFMA16(ahl, b, accz);
            b = *(const short8*)&whh0p[(size_t)((16 + w2) * 4 + c) * 512 + lane * 8];
            accnh = MFMA16(ahh, b, accnh);
            accnh = MFMA16(ahl, b, accnh);
        }
        float hold[4];
        #pragma unroll
        for (int rg = 0; rg < 4; rg++) {
            int off = (quad * 4 + rg) * 136 + j;
            hold[rg] = bf2f(hA[0][0][off]) + bf2f(hA[0][1][off]);
        }
        __syncthreads();
        #pragma unroll
        for (int rg = 0; rg < 4; rg++) {
            float r = sigm(accr[rg] + br0);
            float z = sigm(accz[rg] + bz0);
            float nc = tanh_f(accni[rg] + bni0 + r * (accnh[rg] + bnh0));
            float hnew = (1.f - z) * nc + z * hold[rg];
            int off = (quad * 4 + rg) * 136 + j;
            unsigned short hi = f2bf(hnew);
            hA[0][0][off] = hi;
            hA[0][1][off] = f2bf(hnew - bf2f(hi));
        }
        __syncthreads();

        // ---- layer 1 ----
        accr = (f32x4){0.f, 0.f, 0.f, 0.f};
        accz = (f32x4){0.f, 0.f, 0.f, 0.f};
        accni = (f32x4){0.f, 0.f, 0.f, 0.f};
        accnh = (f32x4){0.f, 0.f, 0.f, 0.f};
        #pragma unroll
        for (int c = 0; c < 4; c++) {
            short8 a0h = *(const short8*)&hA[0][0][aoff + c * 32];
            short8 a0l = *(const short8*)&hA[0][1][aoff + c * 32];
            short8 a1h = *(const short8*)&hA[1][0][aoff + c * 32];
            short8 a1l = *(const short8*)&hA[1][1][aoff + c * 32];
            short8 b;
            b = *(const short8*)&wih1p[(size_t)((w2) * 4 + c) * 512 + lane * 8];
            accr = MFMA16(a0h, b, accr);
            accr = MFMA16(a0l, b, accr);
            b = *(const short8*)&whh1p[(size_t)((w2) * 4 + c) * 512 + lane * 8];
            accr = MFMA16(a1h, b, accr);
            accr = MFMA16(a1l, b, accr);
            b = *(const short8*)&wih1p[(size_t)((8 + w2) * 4 + c) * 512 + lane * 8];
            accz = MFMA16(a0h, b, accz);
            accz = MFMA16(a0l, b, accz);
            b = *(const short8*)&whh1p[(size_t)((8 + w2) * 4 + c) * 512 + lane * 8];
            accz = MFMA16(a1h, b, accz);
            accz = MFMA16(a1l, b, accz);
            b = *(const short8*)&wih1p[(size_t)((16 + w2) * 4 + c) * 512 + lane * 8];
            accni = MFMA16(a0h, b, accni);
            accni = MFMA16(a0l, b, accni);
            b = *(const short8*)&whh1p[(size_t)((16 + w2) * 4 + c) * 512 + lane * 8];
            accnh = MFMA16(a1h, b, accnh);
            accnh = MFMA16(a1l, b, accnh);
        }
        #pragma unroll
        for (int rg = 0; rg < 4; rg++) {
            int off = (quad * 4 + rg) * 136 + j;
            hold[rg] = bf2f(hA[1][0][off]) + bf2f(hA[1][1][off]);
        }
        if (t + 1 < TSTEPS) {
            const float* src = seq + ((size_t)(t + 1) * NR + n0) * DDIM;
            for (int i = tid; i < 16 * DDIM; i += 512) {
                int m = i / DDIM, d = i % DDIM;
                float v = src[i];
                unsigned short hi = f2bf(v);
                xA[buf ^ 1][0][m * 40 + d] = hi;
                xA[buf ^ 1][1][m * 40 + d] = f2bf(v - bf2f(hi));
            }
        }
        __syncthreads();
        #pragma unroll
        for (int rg = 0; rg < 4; rg++) {
            float r = sigm(accr[rg] + br1);
            float z = sigm(accz[rg] + bz1);
            float nc = tanh_f(accni[rg] + bni1 + r * (accnh[rg] + bnh1));
            float hnew = (1.f - z) * nc + z * hold[rg];
            int off = (quad * 4 + rg) * 136 + j;
            unsigned short hi = f2bf(hnew);
            hA[1][0][off] = hi;
            hA[1][1][off] = f2bf(hnew - bf2f(hi));
            if (t + 1 == TSTEPS)
                xh[(size_t)(n0 + quad * 4 + rg) * HDIM + j] = hnew;
        }
    }
}

// ---------------------------------------------------------------------------
// den: parallel atomic reduction. Grid (CDIM/64, 32); block = 4 n-subgroups
// x 64 consecutive c (coalesced 256B/wave). den must be zeroed first.
// ---------------------------------------------------------------------------
__global__ __launch_bounds__(256) void den_atomic(const float* __restrict__ cm,
        const float* __restrict__ mv, float* __restrict__ den)
{
    int c = blockIdx.x * 64 + (threadIdx.x & 63);
    int rg = threadIdx.x >> 6;                  // 0..3
    int nbase = blockIdx.y * 128;               // 32 n-splits x 128 rows
    float acc = 0.f;
    for (int i = 0; i < 32; i++) {
        int n = nbase + rg + (i << 2);
        acc += cm[(size_t)n * CDIM + c] * mv[n];
    }
    __shared__ float red[4][64];
    red[rg][threadIdx.x & 63] = acc;
    __syncthreads();
    if (rg == 0)
        atomicAdd(&den[c], red[0][threadIdx.x] + red[1][threadIdx.x] +
                           red[2][threadIdx.x] + red[3][threadIdx.x]);
}

// ---------------------------------------------------------------------------
// s2ct via LDS tile transpose: read cm [n][c] coalesced, write s2cT [c][n]
// coalesced. Grid (NR/64, CDIM/64), 256 thr; 64x64 tile, pitch 65.
// ---------------------------------------------------------------------------
__global__ __launch_bounds__(256) void s2ct_trans(const float* __restrict__ cm,
        const float* __restrict__ mv, const float* __restrict__ den,
        float* __restrict__ s2cT)
{
    __shared__ float tile[64][65];
    __shared__ float mvs[64];
    const int tid = threadIdx.x;
    const int n0 = blockIdx.x << 6;
    const int c0 = blockIdx.y << 6;
    const int lc = tid & 63, lr = tid >> 6;     // load: 4 rows/pass x 16 passes
    if (tid < 64) mvs[tid] = mv[n0 + tid];
    #pragma unroll
    for (int i = 0; i < 16; i++) {
        int n = lr + (i << 2);
        tile[n][lc] = cm[(size_t)(n0 + n) * CDIM + c0 + lc];
    }
    __syncthreads();
    #pragma unroll
    for (int i = 0; i < 16; i++) {
        int c = lr + (i << 2);
        float m = tile[lc][c];                  // cm[n0+lc][c0+c]
        float d = den[c0 + c];
        s2cT[(size_t)(c0 + c) * NR + n0 + lc] = (m * mvs[lc]) / (d * m + 1.f);
    }
}

// ---------------------------------------------------------------------------
// Small helpers (unchanged)
// ---------------------------------------------------------------------------
__global__ void row_norm(const float* __restrict__ a, float* __restrict__ out)
{
    int r = blockIdx.x;
    float acc = 0.f;
    for (int h = threadIdx.x; h < HDIM; h += 64) {
        float v = a[(size_t)r * HDIM + h];
        acc += v * v;
    }
    for (int o = 32; o > 0; o >>= 1) acc += __shfl_down(acc, o);
    if (threadIdx.x == 0) out[r] = sqrtf(acc);
}

__global__ void row_nonzero(const float* __restrict__ a, float* __restrict__ out)
{
    int r = blockIdx.x;
    float acc = 0.f;
    for (int h = threadIdx.x; h < HDIM; h += 64) acc += a[(size_t)r * HDIM + h];
    for (int o = 32; o > 0; o >>= 1) acc += __shfl_down(acc, o);
    if (threadIdx.x == 0) out[r] = (acc != 0.f) ? 1.f : 0.f;
}

__global__ __launch_bounds__(256) void cos_softmax_row(float* __restrict__ data, int N,
        const float* __restrict__ rn, const float* __restrict__ cn,
        const float* __restrict__ vmask)
{
    int row = blockIdx.x;
    float* d = data + (size_t)row * N;
    int tid = threadIdx.x;
    __shared__ float red[256];
    float rnv = rn ? rn[row] : 0.f;
    float mx = -INFINITY;
    for (int j = tid; j < N; j += 256) {
        float v = d[j];
        if (cn) v = v / fmaxf(rnv * cn[j], 1e-12f);
        if (vmask && vmask[j] == 0.f) v = -1e9f;
        d[j] = v;
        mx = fmaxf(mx, v);
    }
    red[tid] = mx; __syncthreads();
    for (int sdx = 128; sdx > 0; sdx >>= 1) {
        if (tid < sdx) red[tid] = fmaxf(red[tid], red[tid + sdx]);
        __syncthreads();
    }
    float M = red[0]; __syncthreads();
    float sum = 0.f;
    for (int j = tid; j < N; j += 256) {
        float e = expf(d[j] - M);
        d[j] = e;
        sum += e;
    }
    red[tid] = sum; __syncthreads();
    for (int sdx = 128; sdx > 0; sdx >>= 1) {
        if (tid < sdx) red[tid] += red[tid + sdx];
        __syncthreads();
    }
    float inv = 1.f / red[0];
    for (int j = tid; j < N; j += 256) {
        float v = d[j] * inv;
        if (vmask) v *= vmask[j];
        d[j] = v;
    }
}

__global__ void colsum_scatter(const float* __restrict__ vals, const int* __restrict__ idxs,
                               float* __restrict__ colsum)
{
    int idx = blockIdx.x * 256 + threadIdx.x;
    if (idx < NR * KTOP) atomicAdd(&colsum[idxs[idx]], vals[idx]);
}

__global__ void hh_scatter(const float* __restrict__ vals, const int* __restrict__ idxs,
                           const float* __restrict__ hsh, float* __restrict__ hh)
{
    int p = blockIdx.x;
    int j = idxs[p];
    float v = vals[p];
    int i = p / KTOP;
    atomicAdd(&hh[(size_t)j * HDIM + threadIdx.x], v * hsh[(size_t)i * HDIM + threadIdx.x]);
}

__global__ void hh_diag(const float* __restrict__ colsum, const float* __restrict__ diag,
                        const float* __restrict__ hsh, float* __restrict__ hh)
{
    int idx = blockIdx.x * 256 + threadIdx.x;
    int j = idx >> 7;
    if (colsum[j] != 0.f) hh[idx] += diag[j] * hsh[idx];
}

__global__ void sub2_kernel(const float* __restrict__ a, const float* __restrict__ b,
                            float* __restrict__ o)
{
    int i = blockIdx.x * 256 + threadIdx.x;
    o[i] = a[i] - b[i];
}

__global__ void sub3_kernel(const float* __restrict__ a, const float* __restrict__ b,
                            const float* __restrict__ c, float* __restrict__ o)
{
    int i = blockIdx.x * 256 + threadIdx.x;
    o[i] = a[i] - b[i] - c[i];
}

__global__ void head_kernel(const float* __restrict__ ps, const float* __restrict__ hs,
                            const float* __restrict__ indi, const float* __restrict__ w,
                            const float* __restrict__ b, float* __restrict__ out)
{
    int n = blockIdx.x;
    int t = threadIdx.x;
    float acc = 0.f;
    for (int h = t; h < HDIM; h += 64) {
        size_t k = (size_t)n * HDIM + h;
        acc += (ps[k] + hs[k] + indi[k]) * w[h];
    }
    for (int o = 32; o > 0; o >>= 1) acc += __shfl_down(acc, o);
    if (t == 0) out[n] = acc + b[0];
}

// ---------------------------------------------------------------------------
// host-side helpers
// ---------------------------------------------------------------------------
static inline void mg(hipStream_t s, const float* A, const unsigned short* Bh,
                      const unsigned short* Bl, const float* bias, float* C,
                      int M, int N, int K, int z, int flags)
{
    MG g{A, Bh, Bl, bias, C, N, K, K / z, flags | (z > 1 ? 4 : 0)};
    mfma_gemm<<<dim3(N / 64, M / 64, z), 256, 0, s>>>(g);
}
static inline void pbt(hipStream_t s, const float* src, unsigned short* hi,
                       unsigned short* lo, int N, int K)
{
    int total = (N / 16) * (K / 32) * 64;
    pack_bt<<<(total + 255) / 256, 256, 0, s>>>(src, hi, lo, K, total);
}
static inline void pkn(hipStream_t s, const float* src, unsigned short* hi,
                       unsigned short* lo, int K, int N)
{
    int total = (N / 16) * (K / 32) * 64;
    pack_kn<<<(total + 255) / 256, 256, 0, s>>>(src, hi, lo, K, N, total);
}

extern "C" void kernel_launch(void* const* d_in, const int* in_sizes, int n_in,
                              void* d_out, int out_size, void* d_ws, size_t ws_size,
                              hipStream_t stream)
{
    (void)in_sizes; (void)n_in; (void)out_size; (void)ws_size;
    const float* x    = (const float*)d_in[0];
    const float* cm   = (const float*)d_in[1];
    const float* mv   = (const float*)d_in[2];
    const float* wih0 = (const float*)d_in[3];
    const float* whh0 = (const float*)d_in[4];
    const float* bih0 = (const float*)d_in[5];
    const float* bhh0 = (const float*)d_in[6];
    const float* wih1 = (const float*)d_in[7];
    const float* whh1 = (const float*)d_in[8];
    const float* bih1 = (const float*)d_in[9];
    const float* bhh1 = (const float*)d_in[10];
    const float* w_ps = (const float*)d_in[11];
    const float* b_ps = (const float*)d_in[12];
    const float* w_hs = (const float*)d_in[13];
    const float* b_hs = (const float*)d_in[14];
    const float* w_ps_fore = (const float*)d_in[15];
    const float* b_ps_fore = (const float*)d_in[16];
    const float* w_hs_fore = (const float*)d_in[17];
    const float* b_hs_fore = (const float*)d_in[18];
    const float* w_ps_back = (const float*)d_in[19];
    const float* b_ps_back = (const float*)d_in[20];
    const float* w_hs_back = (const float*)d_in[21];
    const float* b_hs_back = (const float*)d_in[22];
    const float* w_indi = (const float*)d_in[23];
    const float* b_indi = (const float*)d_in[24];
    const float* w_out  = (const float*)d_in[25];
    const float* b_out  = (const float*)d_in[26];
    float* out = (float*)d_out;

    // ---- workspace layout (floats) ----
    float* ws = (float*)d_ws;
    float* BIG = ws;                         // 16,777,216 (overlaid)
    float* h0 = ws + 16777216;               // 524288 (unused)
    float* h1 = h0 + 524288;                 // x_hidden
    float* den = h1 + 524288;                // 512
    float* v1 = den + 512;                   // 512
    float* hidden = v1 + 512;                // 65536
    float* hidden2 = hidden + 65536;         // 65536
    float* xnorm = hidden2 + 65536;          // 4096
    float* h2n = xnorm + 4096;               // 512
    float* p0 = h2n + 512;                   // 524288
    float* p_shared = p0 + 524288;
    float* p_back = p_shared + 524288;
    float* out_ps = p_back + 524288;
    float* h_shared = out_ps + 524288;
    float* hn = h_shared + 524288;           // 4096
    float* diagv = hn + 4096;                // 4096
    float* colsum = diagv + 4096;            // 4096
    float* tvals = colsum + 4096;            // 40960
    int*   tidx = (int*)(tvals + 40960);     // 40960 ints
    float* hidden_h = (float*)(tidx + 40960);
    float* v2 = hidden_h + 524288;           // 4096
    float* hhn = v2 + 4096;                  // 4096
    float* hsi0 = hhn + 4096;                // 524288
    float* h_si = hsi0 + 524288;
    float* h_back = h_si + 524288;
    float* out_hs = h_back + 524288;
    float* indi = out_hs + 524288;
    float* out_indi = indi + 524288;
    float* extra = out_indi + 524288;

    // GRU-phase overlays inside BIG:
    float* seqt = BIG;
    unsigned short* wih0p = (unsigned short*)(BIG + 5242880);
    unsigned short* whh0p = wih0p + 12288;
    unsigned short* wih1p = whh0p + 49152;
    unsigned short* whh1p = wih1p + 49152;
    // concept-phase overlays inside BIG:
    float* s2cT = BIG;
    float* L    = BIG + 2097152;
    float* c2s  = BIG + 4194304;
    unsigned short* PB = (unsigned short*)(BIG + 6291456);
    unsigned short* pbt_xh_hi = PB;
    unsigned short* pbt_xh_lo = pbt_xh_hi + 524288;
    unsigned short* pkn_xh_hi = pbt_xh_lo + 524288;
    unsigned short* pkn_xh_lo = pkn_xh_hi + 524288;
    unsigned short* pbt_h2_hi = pkn_xh_lo + 524288;
    unsigned short* pbt_h2_lo = pbt_h2_hi + 65536;
    unsigned short* pkn_h2_hi = pbt_h2_lo + 65536;
    unsigned short* pkn_h2_lo = pkn_h2_hi + 65536;
    unsigned short* wps_hi  = pkn_h2_lo + 65536;
    unsigned short* wps_lo  = wps_hi + 16384;
    unsigned short* wpsb_hi = wps_lo + 16384;
    unsigned short* wpsb_lo = wpsb_hi + 16384;
    unsigned short* wpsf_hi = wpsb_lo + 16384;
    unsigned short* wpsf_lo = wpsf_hi + 16384;
    unsigned short* pbt_hsh_hi = (unsigned short*)p0;
    unsigned short* pbt_hsh_lo = pbt_hsh_hi + 524288;
    unsigned short* pbt_hh_hi = (unsigned short*)indi;
    unsigned short* pbt_hh_lo = pbt_hh_hi + 524288;
    unsigned short* pkn_hh_hi = (unsigned short*)out_indi;
    unsigned short* pkn_hh_lo = pkn_hh_hi + 524288;
    unsigned short* EX = (unsigned short*)extra;
    unsigned short* whs_hi  = EX;            unsigned short* whs_lo  = EX + 16384;
    unsigned short* whsb_hi = EX + 32768;    unsigned short* whsb_lo = EX + 49152;
    unsigned short* whsf_hi = EX + 65536;    unsigned short* whsf_lo = EX + 81920;
    unsigned short* wind_hi = EX + 98304;    unsigned short* wind_lo = EX + 114688;

    // ================= Phase A: MFMA 2-layer GRU =================
    seq_transpose<<<(TSTEPS * NR * DDIM) / 256, 256, 0, stream>>>(x, seqt);
    pack_wb<<<6, 256, 0, stream>>>(wih0, wih0p, DDIM, 1);
    pack_wb<<<24, 256, 0, stream>>>(whh0, whh0p, HDIM, 4);
    pack_wb<<<24, 256, 0, stream>>>(wih1, wih1p, HDIM, 4);
    pack_wb<<<24, 256, 0, stream>>>(whh1, whh1p, HDIM, 4);
    gru_mfma<<<NR / 16, 512, 0, stream>>>(seqt, wih0p, whh0p, wih1p, whh1p,
                                          bih0, bhh0, bih1, bhh1, h1);
    float* x_hidden = h1;

    // ================= Phase B: predefined-concept branch =================
    hipMemsetAsync(den, 0, CDIM * sizeof(float), stream);
    den_atomic<<<dim3(CDIM / 64, 32), 256, 0, stream>>>(cm, mv, den);
    s2ct_trans<<<dim3(NR / 64, CDIM / 64), 256, 0, stream>>>(cm, mv, den, s2cT);
    pkn(stream, x_hidden, pkn_xh_hi, pkn_xh_lo, NR, HDIM);
    pbt(stream, x_hidden, pbt_xh_hi, pbt_xh_lo, NR, HDIM);
    hipMemsetAsync(hidden, 0, 65536 * sizeof(float), stream);
    mg(stream, s2cT, pkn_xh_hi, pkn_xh_lo, nullptr, hidden, CDIM, HDIM, NR, 8, 0);
    row_nonzero<<<CDIM, 64, 0, stream>>>(hidden, v1);
    mg(stream, hidden, pbt_xh_hi, pbt_xh_lo, nullptr, L, CDIM, NR, HDIM, 1, 0);
    cos_softmax_row<<<CDIM, 256, 0, stream>>>(L, NR, nullptr, nullptr, nullptr);
    hipMemsetAsync(hidden2, 0, 65536 * sizeof(float), stream);
    mg(stream, L, pkn_xh_hi, pkn_xh_lo, nullptr, hidden2, CDIM, HDIM, NR, 8, 0);
    row_norm<<<NR, 64, 0, stream>>>(x_hidden, xnorm);
    row_norm<<<CDIM, 64, 0, stream>>>(hidden2, h2n);
    pbt(stream, hidden2, pbt_h2_hi, pbt_h2_lo, CDIM, HDIM);
    pkn(stream, hidden2, pkn_h2_hi, pkn_h2_lo, CDIM, HDIM);
    mg(stream, x_hidden, pbt_h2_hi, pbt_h2_lo, nullptr, c2s, NR, CDIM, HDIM, 1, 0);
    cos_softmax_row<<<NR, 256, 0, stream>>>(c2s, CDIM, xnorm, h2n, v1);
    hipMemsetAsync(p0, 0, 524288 * sizeof(float), stream);
    mg(stream, c2s, pkn_h2_hi, pkn_h2_lo, nullptr, p0, NR, HDIM, CDIM, 2, 0);
    pbt(stream, w_ps, wps_hi, wps_lo, HDIM, HDIM);
    pbt(stream, w_ps_back, wpsb_hi, wpsb_lo, HDIM, HDIM);
    pbt(stream, w_ps_fore, wpsf_hi, wpsf_lo, HDIM, HDIM);
    mg(stream, p0, wps_hi, wps_lo, b_ps, p_shared, NR, HDIM, HDIM, 1, 1);
    mg(stream, p_shared, wpsb_hi, wpsb_lo, b_ps_back, p_back, NR, HDIM, HDIM, 1, 1);
    mg(stream, p_shared, wpsf_hi, wpsf_lo, b_ps_fore, out_ps, NR, HDIM, HDIM, 1, 1 | 2);

    // ================= Phase C: hidden-concept branch =================
    sub2_kernel<<<2048, 256, 0, stream>>>(x_hidden, p_back, h_shared);
    row_norm<<<NR, 64, 0, stream>>>(h_shared, hn);
    pbt(stream, h_shared, pbt_hsh_hi, pbt_hsh_lo, NR, HDIM);
    mg(stream, h_shared, pbt_hsh_hi, pbt_hsh_lo, nullptr, BIG, NR, NR, HDIM, 1, 0);
    scan_topk<<<NR, 256, 0, stream>>>(BIG, hn, diagv, tvals, tidx);
    hipMemsetAsync(colsum, 0, NR * sizeof(float), stream);
    hipMemsetAsync(hidden_h, 0, 524288 * sizeof(float), stream);
    colsum_scatter<<<(NR * KTOP + 255) / 256, 256, 0, stream>>>(tvals, tidx, colsum);
    hh_scatter<<<NR * KTOP, HDIM, 0, stream>>>(tvals, tidx, h_shared, hidden_h);
    hh_diag<<<2048, 256, 0, stream>>>(colsum, diagv, h_shared, hidden_h);
    row_nonzero<<<NR, 64, 0, stream>>>(hidden_h, v2);
    row_norm<<<NR, 64, 0, stream>>>(hidden_h, hhn);
    pbt(stream, hidden_h, pbt_hh_hi, pbt_hh_lo, NR, HDIM);
    pkn(stream, hidden_h, pkn_hh_hi, pkn_hh_lo, NR, HDIM);
    hc2s_flash<<<NR / 16, 256, 0, stream>>>(h_shared, hn, hhn, v2,
                                            pbt_hh_hi, pbt_hh_lo,
                                            pkn_hh_hi, pkn_hh_lo, hsi0);
    pbt(stream, w_hs, whs_hi, whs_lo, HDIM, HDIM);
    pbt(stream, w_hs_back, whsb_hi, whsb_lo, HDIM, HDIM);
    pbt(stream, w_hs_fore, whsf_hi, whsf_lo, HDIM, HDIM);
    mg(stream, hsi0, whs_hi, whs_lo, b_hs, h_si, NR, HDIM, HDIM, 1, 1);
    mg(stream, h_si, whsb_hi, whsb_lo, b_hs_back, h_back, NR, HDIM, HDIM, 1, 1);
    mg(stream, h_si, whsf_hi, whsf_lo, b_hs_fore, out_hs, NR, HDIM, HDIM, 1, 1 | 2);

    // ================= Phase D: individual branch + head =================
    sub3_kernel<<<2048, 256, 0, stream>>>(x_hidden, p_back, h_back, indi);
    pbt(stream, w_indi, wind_hi, wind_lo, HDIM, HDIM);
    mg(stream, indi, wind_hi, wind_lo, b_indi, out_indi, NR, HDIM, HDIM, 1, 1 | 2);
    head_kernel<<<NR, 64, 0, stream>>>(out_ps, out_hs, out_indi, w_out, b_out, out);
}

// Round 9
// 955.257 us; speedup vs baseline: 7.8101x; 1.0129x over previous
//
#include <hip/hip_runtime.h>
#include <cstddef>

// Problem dims
#define NR 4096      // batch
#define CDIM 512     // concepts
#define HDIM 128     // hidden
#define TSTEPS 64
#define DDIM 20
#define KTOP 10

typedef __attribute__((ext_vector_type(8))) short short8;
typedef __attribute__((ext_vector_type(4))) float f32x4;

__device__ __forceinline__ unsigned short f2bf(float f) {
    union { float f; unsigned u; } x; x.f = f;
    unsigned r = (x.u + 0x7fffu + ((x.u >> 16) & 1u)) >> 16;
    return (unsigned short)r;
}
__device__ __forceinline__ float bf2f(unsigned short h) {
    union { unsigned u; float f; } x; x.u = ((unsigned)h) << 16;
    return x.f;
}
__device__ __forceinline__ float sigm(float v) {
    float c = fminf(fmaxf(v, -30.f), 30.f);
    return __fdividef(1.f, 1.f + __expf(-c));
}
__device__ __forceinline__ float tanh_f(float v) {
    float c = fminf(fmaxf(v, -10.f), 10.f);
    float e = __expf(2.f * c);
    return __fdividef(e - 1.f, e + 1.f);
}

#define MFMA16(a, b, c) __builtin_amdgcn_mfma_f32_16x16x32_bf16(a, b, c, 0, 0, 0)

// ---------------------------------------------------------------------------
// Generic MFMA GEMM (unchanged)
// ---------------------------------------------------------------------------
struct MG {
    const float* A; const unsigned short* Bh; const unsigned short* Bl;
    const float* bias; float* C; int N, K, kchunk, flags;
};

__global__ __launch_bounds__(256) void mfma_gemm(MG g)
{
    const int tid = threadIdx.x;
    const int w = tid >> 6, lane = tid & 63, quad = lane >> 4, lm = lane & 15;
    const int bm = (blockIdx.y << 6) + (w << 4);
    const int bn = blockIdx.x << 6;
    const int NC = g.K >> 5;
    const int c0 = (blockIdx.z * g.kchunk) >> 5;
    const int c1 = c0 + (g.kchunk >> 5);
    const float* arow = g.A + (size_t)(bm + lm) * g.K;
    f32x4 acc[4];
    #pragma unroll
    for (int t = 0; t < 4; t++) acc[t] = (f32x4){0.f, 0.f, 0.f, 0.f};

    for (int c = c0; c < c1; c++) {
        const float* ap = arow + (c << 5) + (quad << 3);
        float4 a0 = *(const float4*)ap;
        float4 a1 = *(const float4*)(ap + 4);
        short8 ah, al;
        #pragma unroll
        for (int j = 0; j < 4; j++) {
            float f = (&a0.x)[j];
            unsigned short h = f2bf(f);
            ah[j] = h; al[j] = f2bf(f - bf2f(h));
            f = (&a1.x)[j];
            h = f2bf(f);
            ah[4 + j] = h; al[4 + j] = f2bf(f - bf2f(h));
        }
        #pragma unroll
        for (int t = 0; t < 4; t++) {
            size_t bidx = ((size_t)(((bn >> 4) + t) * NC + c) * 64 + lane) * 8;
            short8 bh = *(const short8*)(g.Bh + bidx);
            short8 bl = *(const short8*)(g.Bl + bidx);
            acc[t] = MFMA16(ah, bh, acc[t]);
            acc[t] = MFMA16(ah, bl, acc[t]);
            acc[t] = MFMA16(al, bh, acc[t]);
        }
    }
    #pragma unroll
    for (int t = 0; t < 4; t++) {
        #pragma unroll
        for (int rg = 0; rg < 4; rg++) {
            int row = bm + (quad << 2) + rg;
            int col = bn + (t << 4) + lm;
            float v = acc[t][rg];
            if (g.flags & 1) v += g.bias[col];
            if (g.flags & 2) v = v > 0.f ? v : 0.01f * v;
            if (g.flags & 4) atomicAdd(&g.C[(size_t)row * g.N + col], v);
            else g.C[(size_t)row * g.N + col] = v;
        }
    }
}

// B-pack from [N,K] rows; layout [nt][c][lane][8], hi/lo planes.
__global__ void pack_bt(const float* __restrict__ src, unsigned short* __restrict__ hi,
                        unsigned short* __restrict__ lo, int K, int total)
{
    int idx = blockIdx.x * 256 + threadIdx.x;
    if (idx >= total) return;
    int NC = K >> 5;
    int lane = idx & 63;
    int c = (idx >> 6) % NC;
    int t = idx / (NC * 64);
    int n = (t << 4) + (lane & 15);
    int kb = (c << 5) + ((lane >> 4) << 3);
    #pragma unroll
    for (int j = 0; j < 8; j++) {
        float f = src[(size_t)n * K + kb + j];
        unsigned short h = f2bf(f);
        hi[(size_t)idx * 8 + j] = h;
        lo[(size_t)idx * 8 + j] = f2bf(f - bf2f(h));
    }
}

// Combined pack (K = HDIM = 128 only): writes BT (B[n][k]) and KN (B[k][n])
// layouts in one pass over src [N, 128].
__global__ void pack_both(const float* __restrict__ src,
                          unsigned short* __restrict__ bth, unsigned short* __restrict__ btl,
                          unsigned short* __restrict__ knh, unsigned short* __restrict__ knl,
                          int N, int total_kn)
{
    int idx = blockIdx.x * 256 + threadIdx.x;
    int lane = idx & 63;
    // --- BT: total = (N/16)*4*64 ---
    int totBT = (N >> 4) * 256;
    if (idx < totBT) {
        int c = (idx >> 6) & 3;
        int t = idx >> 8;
        int n = (t << 4) + (lane & 15);
        int kb = (c << 5) + ((lane >> 4) << 3);
        #pragma unroll
        for (int j = 0; j < 8; j++) {
            float f = src[(size_t)n * HDIM + kb + j];
            unsigned short h = f2bf(f);
            bth[(size_t)idx * 8 + j] = h;
            btl[(size_t)idx * 8 + j] = f2bf(f - bf2f(h));
        }
    }
    // --- KN: total = 8 * (N/32) * 64 (k-dim is the 128 cols? no: K=N rows) ---
    if (idx < total_kn) {
        int NC = N >> 5;                  // src rows are the K dimension
        int c = (idx >> 6) % NC;
        int t = idx / (NC * 64);
        int n = (t << 4) + (lane & 15);   // output col = hidden unit
        int kb = (c << 5) + ((lane >> 4) << 3);
        #pragma unroll
        for (int j = 0; j < 8; j++) {
            float f = src[(size_t)(kb + j) * HDIM + n];
            unsigned short h = f2bf(f);
            knh[(size_t)idx * 8 + j] = h;
            knl[(size_t)idx * 8 + j] = f2bf(f - bf2f(h));
        }
    }
}

// ---------------------------------------------------------------------------
// scan_topk (unchanged)
// ---------------------------------------------------------------------------
__global__ __launch_bounds__(256) void scan_topk(const float* __restrict__ S,
        const float* __restrict__ hn, float* __restrict__ diagv,
        float* __restrict__ tvals, int* __restrict__ tidx)
{
    int row = blockIdx.x;
    const float* d = S + (size_t)row * NR;
    int tid = threadIdx.x;
    float hi_ = hn[row];
    float lv[16]; int li[16];
    #pragma unroll
    for (int i = 0; i < 16; i++) {
        int j = tid + i * 256;
        float v = d[j] / fmaxf(hi_ * hn[j], 1e-12f);
        if (j == row) { diagv[row] = v; v = 0.f; }
        lv[i] = v;
        li[i] = j;
    }
    __shared__ float sv[256];
    __shared__ int si[256];
    for (int k = 0; k < KTOP; k++) {
        float bv = -INFINITY; int bi = 0x7fffffff;
        #pragma unroll
        for (int i = 0; i < 16; i++) {
            if (lv[i] > bv || (lv[i] == bv && li[i] < bi)) { bv = lv[i]; bi = li[i]; }
        }
        sv[tid] = bv; si[tid] = bi;
        __syncthreads();
        for (int sdx = 128; sdx > 0; sdx >>= 1) {
            if (tid < sdx) {
                if (sv[tid + sdx] > sv[tid] || (sv[tid + sdx] == sv[tid] && si[tid + sdx] < si[tid])) {
                    sv[tid] = sv[tid + sdx]; si[tid] = si[tid + sdx];
                }
            }
            __syncthreads();
        }
        if (tid == 0) { tvals[row * KTOP + k] = sv[0]; tidx[row * KTOP + k] = si[0]; }
        int wn = si[0];
        if ((wn & 255) == tid) lv[wn >> 8] = -INFINITY;
        __syncthreads();
    }
}

// ---------------------------------------------------------------------------
// hc2s_flash (unchanged)
// ---------------------------------------------------------------------------
__global__ __launch_bounds__(256) void hc2s_flash(
    const float* __restrict__ hsh, const float* __restrict__ hn,
    const float* __restrict__ hhn, const float* __restrict__ v2,
    const unsigned short* __restrict__ Bh, const unsigned short* __restrict__ Bl,
    const unsigned short* __restrict__ Vh, const unsigned short* __restrict__ Vl,
    float* __restrict__ O)
{
    __shared__ __attribute__((aligned(16))) unsigned short Ph[16 * 72];
    __shared__ __attribute__((aligned(16))) unsigned short Pl[16 * 72];
    __shared__ float redmax[4][16];
    __shared__ float redsum[4][16];

    const int tid = threadIdx.x;
    const int wv = tid >> 6, lane = tid & 63, quad = lane >> 4, lm = lane & 15;
    const int bm = blockIdx.x << 4;

    short8 ahh[4], ahl[4];
    #pragma unroll
    for (int c = 0; c < 4; c++) {
        const float* ap = hsh + (size_t)(bm + lm) * HDIM + (c << 5) + (quad << 3);
        float4 a0 = *(const float4*)ap;
        float4 a1 = *(const float4*)(ap + 4);
        #pragma unroll
        for (int j = 0; j < 4; j++) {
            float f = (&a0.x)[j];
            unsigned short h = f2bf(f);
            ahh[c][j] = h; ahl[c][j] = f2bf(f - bf2f(h));
            f = (&a1.x)[j];
            h = f2bf(f);
            ahh[c][4 + j] = h; ahl[c][4 + j] = f2bf(f - bf2f(h));
        }
    }
    float hnr[4];
    #pragma unroll
    for (int rg = 0; rg < 4; rg++) hnr[rg] = hn[bm + (quad << 2) + rg];

    float m_old[4], l_old[4];
    #pragma unroll
    for (int rg = 0; rg < 4; rg++) { m_old[rg] = -INFINITY; l_old[rg] = 0.f; }
    f32x4 o0 = (f32x4){0.f, 0.f, 0.f, 0.f};
    f32x4 o1 = (f32x4){0.f, 0.f, 0.f, 0.f};

    for (int jt = 0; jt < NR / 64; jt++) {
        f32x4 s = (f32x4){0.f, 0.f, 0.f, 0.f};
        int nt = (jt << 2) + wv;
        #pragma unroll
        for (int c = 0; c < 4; c++) {
            size_t bidx = ((size_t)(nt * 4 + c) * 64 + lane) * 8;
            short8 bh = *(const short8*)(Bh + bidx);
            short8 bl = *(const short8*)(Bl + bidx);
            s = MFMA16(ahh[c], bh, s);
            s = MFMA16(ahh[c], bl, s);
            s = MFMA16(ahl[c], bh, s);
        }
        int col = (jt << 6) + (wv << 4) + lm;
        float hc = hhn[col];
        float vm = v2[col];
        float sv[4];
        #pragma unroll
        for (int rg = 0; rg < 4; rg++) {
            float v = s[rg] / fmaxf(hnr[rg] * hc, 1e-12f);
            sv[rg] = (vm == 0.f) ? -1e9f : v;
        }
        float mx[4];
        #pragma unroll
        for (int rg = 0; rg < 4; rg++) {
            float m = sv[rg];
            #pragma unroll
            for (int d = 1; d < 16; d <<= 1) m = fmaxf(m, __shfl_xor(m, d));
            mx[rg] = m;
        }
        if (lm == 0) {
            #pragma unroll
            for (int rg = 0; rg < 4; rg++) redmax[wv][(quad << 2) + rg] = mx[rg];
        }
        __syncthreads();
        float m_new[4], alpha[4];
        #pragma unroll
        for (int rg = 0; rg < 4; rg++) {
            int r = (quad << 2) + rg;
            float mt = fmaxf(fmaxf(redmax[0][r], redmax[1][r]),
                             fmaxf(redmax[2][r], redmax[3][r]));
            m_new[rg] = fmaxf(m_old[rg], mt);
            alpha[rg] = __expf(m_old[rg] - m_new[rg]);
        }
        float psum[4];
        #pragma unroll
        for (int rg = 0; rg < 4; rg++) {
            float p = __expf(sv[rg] - m_new[rg]);
            float ssum = p;
            #pragma unroll
            for (int d = 1; d < 16; d <<= 1) ssum += __shfl_xor(ssum, d);
            psum[rg] = ssum;
            int off = ((quad << 2) + rg) * 72 + (wv << 4) + lm;
            unsigned short h = f2bf(p);
            Ph[off] = h;
            Pl[off] = f2bf(p - bf2f(h));
        }
        if (lm == 0) {
            #pragma unroll
            for (int rg = 0; rg < 4; rg++) redsum[wv][(quad << 2) + rg] = psum[rg];
        }
        __syncthreads();
        #pragma unroll
        for (int rg = 0; rg < 4; rg++) {
            int r = (quad << 2) + rg;
            float ts = redsum[0][r] + redsum[1][r] + redsum[2][r] + redsum[3][r];
            l_old[rg] = l_old[rg] * alpha[rg] + ts;
            m_old[rg] = m_new[rg];
            o0[rg] *= alpha[rg];
            o1[rg] *= alpha[rg];
        }
        int vt0 = wv << 1;
        #pragma unroll
        for (int c2 = 0; c2 < 2; c2++) {
            int poff = lm * 72 + (c2 << 5) + (quad << 3);
            short8 pah = *(const short8*)&Ph[poff];
            short8 pal = *(const short8*)&Pl[poff];
            int cg = (jt << 1) + c2;
            size_t b0 = ((size_t)(vt0 * 128 + cg) * 64 + lane) * 8;
            size_t b1 = ((size_t)((vt0 + 1) * 128 + cg) * 64 + lane) * 8;
            short8 vh0 = *(const short8*)(Vh + b0);
            short8 vl0 = *(const short8*)(Vl + b0);
            short8 vh1 = *(const short8*)(Vh + b1);
            short8 vl1 = *(const short8*)(Vl + b1);
            o0 = MFMA16(pah, vh0, o0);
            o0 = MFMA16(pah, vl0, o0);
            o0 = MFMA16(pal, vh0, o0);
            o1 = MFMA16(pah, vh1, o1);
            o1 = MFMA16(pah, vl1, o1);
            o1 = MFMA16(pal, vh1, o1);
        }
        __syncthreads();
    }
    #pragma unroll
    for (int rg = 0; rg < 4; rg++) {
        int row = bm + (quad << 2) + rg;
        float inv = __fdividef(1.f, l_old[rg]);
        O[(size_t)row * HDIM + (wv << 5) + lm] = o0[rg] * inv;
        O[(size_t)row * HDIM + (wv << 5) + 16 + lm] = o1[rg] * inv;
    }
}

// ---------------------------------------------------------------------------
// GRU weight pack
// ---------------------------------------------------------------------------
__global__ void pack_wb(const float* __restrict__ W, unsigned short* __restrict__ Wp,
                        int K, int nch)
{
    int idx = blockIdx.x * 256 + threadIdx.x;
    if (idx >= 24 * nch * 64) return;
    int lane = idx & 63;
    int c = (idx >> 6) % nch;
    int t = idx / (nch * 64);
    int n = t * 16 + (lane & 15);
    int kb = c * 32 + (lane >> 4) * 8;
    #pragma unroll
    for (int j = 0; j < 8; j++) {
        int k = kb + j;
        float f = (k < K) ? W[(size_t)n * K + k] : 0.f;
        Wp[(size_t)idx * 8 + j] = f2bf(f);
    }
}

// x [N, D*T] -> seq [T, N, D]
__global__ void seq_transpose(const float* __restrict__ x, float* __restrict__ seq)
{
    int idx = blockIdx.x * 256 + threadIdx.x;
    int d = idx % DDIM;
    int r = idx / DDIM;
    int n = r & (NR - 1);
    int t = r >> 12;
    seq[idx] = x[(size_t)n * (DDIM * TSTEPS) + d * TSTEPS + t];
}

// ---------------------------------------------------------------------------
// MFMA 2-layer GRU, 8 waves, REGISTER-RESIDENT WEIGHTS.
// Each wave loads its 39 weight fragments (156 VGPRs) once before the t-loop;
// the loop body has zero global loads and zero address recompute.
// ---------------------------------------------------------------------------
__global__ __launch_bounds__(512) void gru_mfma(
    const float* __restrict__ seq,
    const unsigned short* __restrict__ wih0p,
    const unsigned short* __restrict__ whh0p,
    const unsigned short* __restrict__ wih1p,
    const unsigned short* __restrict__ whh1p,
    const float* __restrict__ bih0, const float* __restrict__ bhh0,
    const float* __restrict__ bih1, const float* __restrict__ bhh1,
    float* __restrict__ xh)
{
    __shared__ __attribute__((aligned(16))) unsigned short hA[2][2][16 * 136];
    __shared__ __attribute__((aligned(16))) unsigned short xA[2][2][16 * 40];

    const int tid = threadIdx.x;
    const int w2 = tid >> 6;
    const int lane = tid & 63;
    const int quad = lane >> 4;
    const int lm = lane & 15;
    const int n0 = blockIdx.x << 4;
    const int j = (w2 << 4) + lm;

    for (int i = tid; i < 2 * 2 * 16 * 136; i += 512) ((unsigned short*)hA)[i] = 0;
    for (int i = tid; i < 2 * 2 * 16 * 40; i += 512) ((unsigned short*)xA)[i] = 0;

    float br0 = bih0[j] + bhh0[j];
    float bz0 = bih0[128 + j] + bhh0[128 + j];
    float bni0 = bih0[256 + j];
    float bnh0 = bhh0[256 + j];
    float br1 = bih1[j] + bhh1[j];
    float bz1 = bih1[128 + j] + bhh1[128 + j];
    float bni1 = bih1[256 + j];
    float bnh1 = bhh1[256 + j];

    // ---- load all weight fragments into registers (t-invariant) ----
    short8 W0x[3];          // wih0 r/z/n (single k-chunk)
    short8 W0h[3][4];       // whh0 [gate][chunk]
    short8 W1x[3][4];       // wih1
    short8 W1h[3][4];       // whh1
    {
        const int lb = lane * 8;
        W0x[0] = *(const short8*)&wih0p[(size_t)(w2) * 512 + lb];
        W0x[1] = *(const short8*)&wih0p[(size_t)(8 + w2) * 512 + lb];
        W0x[2] = *(const short8*)&wih0p[(size_t)(16 + w2) * 512 + lb];
        #pragma unroll
        for (int c = 0; c < 4; c++) {
            W0h[0][c] = *(const short8*)&whh0p[(size_t)((w2) * 4 + c) * 512 + lb];
            W0h[1][c] = *(const short8*)&whh0p[(size_t)((8 + w2) * 4 + c) * 512 + lb];
            W0h[2][c] = *(const short8*)&whh0p[(size_t)((16 + w2) * 4 + c) * 512 + lb];
            W1x[0][c] = *(const short8*)&wih1p[(size_t)((w2) * 4 + c) * 512 + lb];
            W1x[1][c] = *(const short8*)&wih1p[(size_t)((8 + w2) * 4 + c) * 512 + lb];
            W1x[2][c] = *(const short8*)&wih1p[(size_t)((16 + w2) * 4 + c) * 512 + lb];
            W1h[0][c] = *(const short8*)&whh1p[(size_t)((w2) * 4 + c) * 512 + lb];
            W1h[1][c] = *(const short8*)&whh1p[(size_t)((8 + w2) * 4 + c) * 512 + lb];
            W1h[2][c] = *(const short8*)&whh1p[(size_t)((16 + w2) * 4 + c) * 512 + lb];
        }
    }

    const int aoff = lm * 136 + quad * 8;
    const int xoff = lm * 40 + quad * 8;

    {
        const float* src = seq + (size_t)n0 * DDIM;
        for (int i = tid; i < 16 * DDIM; i += 512) {
            int m = i / DDIM, d = i % DDIM;
            float v = src[i];
            unsigned short hi = f2bf(v);
            xA[0][0][m * 40 + d] = hi;
            xA[0][1][m * 40 + d] = f2bf(v - bf2f(hi));
        }
    }
    __syncthreads();

    for (int t = 0; t < TSTEPS; t++) {
        const int buf = t & 1;
        f32x4 accr = (f32x4){0.f, 0.f, 0.f, 0.f};
        f32x4 accz = (f32x4){0.f, 0.f, 0.f, 0.f};
        f32x4 accni = (f32x4){0.f, 0.f, 0.f, 0.f};
        f32x4 accnh = (f32x4){0.f, 0.f, 0.f, 0.f};

        // ---- layer 0 ----
        {
            short8 axh = *(const short8*)&xA[buf][0][xoff];
            short8 axl = *(const short8*)&xA[buf][1][xoff];
            accr = MFMA16(axh, W0x[0], accr);
            accr = MFMA16(axl, W0x[0], accr);
            accz = MFMA16(axh, W0x[1], accz);
            accz = MFMA16(axl, W0x[1], accz);
            accni = MFMA16(axh, W0x[2], accni);
            accni = MFMA16(axl, W0x[2], accni);
        }
        #pragma unroll
        for (int c = 0; c < 4; c++) {
            short8 ahh = *(const short8*)&hA[0][0][aoff + c * 32];
            short8 ahl = *(const short8*)&hA[0][1][aoff + c * 32];
            accr = MFMA16(ahh, W0h[0][c], accr);
            accr = MFMA16(ahl, W0h[0][c], accr);
            accz = MFMA16(ahh, W0h[1][c], accz);
            accz = MFMA16(ahl, W0h[1][c], accz);
            accnh = MFMA16(ahh, W0h[2][c], accnh);
            accnh = MFMA16(ahl, W0h[2][c], accnh);
        }
        float hold[4];
        #pragma unroll
        for (int rg = 0; rg < 4; rg++) {
            int off = (quad * 4 + rg) * 136 + j;
            hold[rg] = bf2f(hA[0][0][off]) + bf2f(hA[0][1][off]);
        }
        __syncthreads();     // B1: all reads of h0 done
        #pragma unroll
        for (int rg = 0; rg < 4; rg++) {
            float r = sigm(accr[rg] + br0);
            float z = sigm(accz[rg] + bz0);
            float nc = tanh_f(accni[rg] + bni0 + r * (accnh[rg] + bnh0));
            float hnew = (1.f - z) * nc + z * hold[rg];
            int off = (quad * 4 + rg) * 136 + j;
            unsigned short hi = f2bf(hnew);
            hA[0][0][off] = hi;
            hA[0][1][off] = f2bf(hnew - bf2f(hi));
        }
        __syncthreads();     // B2: new h0 visible

        // ---- layer 1 ----
        accr = (f32x4){0.f, 0.f, 0.f, 0.f};
        accz = (f32x4){0.f, 0.f, 0.f, 0.f};
        accni = (f32x4){0.f, 0.f, 0.f, 0.f};
        accnh = (f32x4){0.f, 0.f, 0.f, 0.f};
        #pragma unroll
        for (int c = 0; c < 4; c++) {
            short8 a0h = *(const short8*)&hA[0][0][aoff + c * 32];
            short8 a0l = *(const short8*)&hA[0][1][aoff + c * 32];
            short8 a1h = *(const short8*)&hA[1][0][aoff + c * 32];
            short8 a1l = *(const short8*)&hA[1][1][aoff + c * 32];
            accr = MFMA16(a0h, W1x[0][c], accr);
            accr = MFMA16(a0l, W1x[0][c], accr);
            accr = MFMA16(a1h, W1h[0][c], accr);
            accr = MFMA16(a1l, W1h[0][c], accr);
            accz = MFMA16(a0h, W1x[1][c], accz);
            accz = MFMA16(a0l, W1x[1][c], accz);
            accz = MFMA16(a1h, W1h[1][c], accz);
            accz = MFMA16(a1l, W1h[1][c], accz);
            accni = MFMA16(a0h, W1x[2][c], accni);
            accni = MFMA16(a0l, W1x[2][c], accni);
            accnh = MFMA16(a1h, W1h[2][c], accnh);
            accnh = MFMA16(a1l, W1h[2][c], accnh);
        }
        #pragma unroll
        for (int rg = 0; rg < 4; rg++) {
            int off = (quad * 4 + rg) * 136 + j;
            hold[rg] = bf2f(hA[1][0][off]) + bf2f(hA[1][1][off]);
        }
        if (t + 1 < TSTEPS) {
            const float* src = seq + ((size_t)(t + 1) * NR + n0) * DDIM;
            for (int i = tid; i < 16 * DDIM; i += 512) {
                int m = i / DDIM, d = i % DDIM;
                float v = src[i];
                unsigned short hi = f2bf(v);
                xA[buf ^ 1][0][m * 40 + d] = hi;
                xA[buf ^ 1][1][m * 40 + d] = f2bf(v - bf2f(hi));
            }
        }
        __syncthreads();     // B3: h0/h1 reads + x-stage done
        #pragma unroll
        for (int rg = 0; rg < 4; rg++) {
            float r = sigm(accr[rg] + br1);
            float z = sigm(accz[rg] + bz1);
            float nc = tanh_f(accni[rg] + bni1 + r * (accnh[rg] + bnh1));
            float hnew = (1.f - z) * nc + z * hold[rg];
            int off = (quad * 4 + rg) * 136 + j;
            unsigned short hi = f2bf(hnew);
            hA[1][0][off] = hi;
            hA[1][1][off] = f2bf(hnew - bf2f(hi));
            if (t + 1 == TSTEPS)
                xh[(size_t)(n0 + quad * 4 + rg) * HDIM + j] = hnew;
        }
    }
}

// ---------------------------------------------------------------------------
// den / s2ct (unchanged from round 8)
// ---------------------------------------------------------------------------
__global__ __launch_bounds__(256) void den_atomic(const float* __restrict__ cm,
        const float* __restrict__ mv, float* __restrict__ den)
{
    int c = blockIdx.x * 64 + (threadIdx.x & 63);
    int rg = threadIdx.x >> 6;
    int nbase = blockIdx.y * 128;
    float acc = 0.f;
    for (int i = 0; i < 32; i++) {
        int n = nbase + rg + (i << 2);
        acc += cm[(size_t)n * CDIM + c] * mv[n];
    }
    __shared__ float red[4][64];
    red[rg][threadIdx.x & 63] = acc;
    __syncthreads();
    if (rg == 0)
        atomicAdd(&den[c], red[0][threadIdx.x] + red[1][threadIdx.x] +
                           red[2][threadIdx.x] + red[3][threadIdx.x]);
}

__global__ __launch_bounds__(256) void s2ct_trans(const float* __restrict__ cm,
        const float* __restrict__ mv, const float* __restrict__ den,
        float* __restrict__ s2cT)
{
    __shared__ float tile[64][65];
    __shared__ float mvs[64];
    const int tid = threadIdx.x;
    const int n0 = blockIdx.x << 6;
    const int c0 = blockIdx.y << 6;
    const int lc = tid & 63, lr = tid >> 6;
    if (tid < 64) mvs[tid] = mv[n0 + tid];
    #pragma unroll
    for (int i = 0; i < 16; i++) {
        int n = lr + (i << 2);
        tile[n][lc] = cm[(size_t)(n0 + n) * CDIM + c0 + lc];
    }
    __syncthreads();
    #pragma unroll
    for (int i = 0; i < 16; i++) {
        int c = lr + (i << 2);
        float m = tile[lc][c];
        float d = den[c0 + c];
        s2cT[(size_t)(c0 + c) * NR + n0 + lc] = (m * mvs[lc]) / (d * m + 1.f);
    }
}

// ---------------------------------------------------------------------------
// Small helpers
// ---------------------------------------------------------------------------
__global__ void row_norm(const float* __restrict__ a, float* __restrict__ out)
{
    int r = blockIdx.x;
    float acc = 0.f;
    for (int h = threadIdx.x; h < HDIM; h += 64) {
        float v = a[(size_t)r * HDIM + h];
        acc += v * v;
    }
    for (int o = 32; o > 0; o >>= 1) acc += __shfl_down(acc, o);
    if (threadIdx.x == 0) out[r] = sqrtf(acc);
}

__global__ void row_nonzero(const float* __restrict__ a, float* __restrict__ out)
{
    int r = blockIdx.x;
    float acc = 0.f;
    for (int h = threadIdx.x; h < HDIM; h += 64) acc += a[(size_t)r * HDIM + h];
    for (int o = 32; o > 0; o >>= 1) acc += __shfl_down(acc, o);
    if (threadIdx.x == 0) out[r] = (acc != 0.f) ? 1.f : 0.f;
}

// fused: norm + nonzero in one pass
__global__ void row_norm_nz(const float* __restrict__ a, float* __restrict__ nrm,
                            float* __restrict__ nz)
{
    int r = blockIdx.x;
    float acc = 0.f, s = 0.f;
    for (int h = threadIdx.x; h < HDIM; h += 64) {
        float v = a[(size_t)r * HDIM + h];
        acc += v * v;
        s += v;
    }
    for (int o = 32; o > 0; o >>= 1) { acc += __shfl_down(acc, o); s += __shfl_down(s, o); }
    if (threadIdx.x == 0) { nrm[r] = sqrtf(acc); nz[r] = (s != 0.f) ? 1.f : 0.f; }
}

__global__ __launch_bounds__(256) void cos_softmax_row(float* __restrict__ data, int N,
        const float* __restrict__ rn, const float* __restrict__ cn,
        const float* __restrict__ vmask)
{
    int row = blockIdx.x;
    float* d = data + (size_t)row * N;
    int tid = threadIdx.x;
    __shared__ float red[256];
    float rnv = rn ? rn[row] : 0.f;
    float mx = -INFINITY;
    for (int j = tid; j < N; j += 256) {
        float v = d[j];
        if (cn) v = v / fmaxf(rnv * cn[j], 1e-12f);
        if (vmask && vmask[j] == 0.f) v = -1e9f;
        d[j] = v;
        mx = fmaxf(mx, v);
    }
    red[tid] = mx; __syncthreads();
    for (int sdx = 128; sdx > 0; sdx >>= 1) {
        if (tid < sdx) red[tid] = fmaxf(red[tid], red[tid + sdx]);
        __syncthreads();
    }
    float M = red[0]; __syncthreads();
    float sum = 0.f;
    for (int j = tid; j < N; j += 256) {
        float e = expf(d[j] - M);
        d[j] = e;
        sum += e;
    }
    red[tid] = sum; __syncthreads();
    for (int sdx = 128; sdx > 0; sdx >>= 1) {
        if (tid < sdx) red[tid] += red[tid + sdx];
        __syncthreads();
    }
    float inv = 1.f / red[0];
    for (int j = tid; j < N; j += 256) {
        float v = d[j] * inv;
        if (vmask) v *= vmask[j];
        d[j] = v;
    }
}

__global__ void colsum_scatter(const float* __restrict__ vals, const int* __restrict__ idxs,
                               float* __restrict__ colsum)
{
    int idx = blockIdx.x * 256 + threadIdx.x;
    if (idx < NR * KTOP) atomicAdd(&colsum[idxs[idx]], vals[idx]);
}

__global__ void hh_scatter(const float* __restrict__ vals, const int* __restrict__ idxs,
                           const float* __restrict__ hsh, float* __restrict__ hh)
{
    int p = blockIdx.x;
    int j = idxs[p];
    float v = vals[p];
    int i = p / KTOP;
    atomicAdd(&hh[(size_t)j * HDIM + threadIdx.x], v * hsh[(size_t)i * HDIM + threadIdx.x]);
}

__global__ void hh_diag(const float* __restrict__ colsum, const float* __restrict__ diag,
                        const float* __restrict__ hsh, float* __restrict__ hh)
{
    int idx = blockIdx.x * 256 + threadIdx.x;
    int j = idx >> 7;
    if (colsum[j] != 0.f) hh[idx] += diag[j] * hsh[idx];
}

__global__ void sub2_kernel(const float* __restrict__ a, const float* __restrict__ b,
                            float* __restrict__ o)
{
    int i = blockIdx.x * 256 + threadIdx.x;
    o[i] = a[i] - b[i];
}

__global__ void sub3_kernel(const float* __restrict__ a, const float* __restrict__ b,
                            const float* __restrict__ c, float* __restrict__ o)
{
    int i = blockIdx.x * 256 + threadIdx.x;
    o[i] = a[i] - b[i] - c[i];
}

__global__ void head_kernel(const float* __restrict__ ps, const float* __restrict__ hs,
                            const float* __restrict__ indi, const float* __restrict__ w,
                            const float* __restrict__ b, float* __restrict__ out)
{
    int n = blockIdx.x;
    int t = threadIdx.x;
    float acc = 0.f;
    for (int h = t; h < HDIM; h += 64) {
        size_t k = (size_t)n * HDIM + h;
        acc += (ps[k] + hs[k] + indi[k]) * w[h];
    }
    for (int o = 32; o > 0; o >>= 1) acc += __shfl_down(acc, o);
    if (t == 0) out[n] = acc + b[0];
}

// ---------------------------------------------------------------------------
// host-side helpers
// ---------------------------------------------------------------------------
static inline void mg(hipStream_t s, const float* A, const unsigned short* Bh,
                      const unsigned short* Bl, const float* bias, float* C,
                      int M, int N, int K, int z, int flags)
{
    MG g{A, Bh, Bl, bias, C, N, K, K / z, flags | (z > 1 ? 4 : 0)};
    mfma_gemm<<<dim3(N / 64, M / 64, z), 256, 0, s>>>(g);
}
static inline void pbt(hipStream_t s, const float* src, unsigned short* hi,
                       unsigned short* lo, int N, int K)
{
    int total = (N / 16) * (K / 32) * 64;
    pack_bt<<<(total + 255) / 256, 256, 0, s>>>(src, hi, lo, K, total);
}
// combined BT+KN pack for [N,128] sources
static inline void pboth(hipStream_t s, const float* src,
                         unsigned short* bth, unsigned short* btl,
                         unsigned short* knh, unsigned short* knl, int N)
{
    int totBT = (N / 16) * 4 * 64;
    int totKN = 8 * (N / 32) * 64;
    int tot = totBT > totKN ? totBT : totKN;
    pack_both<<<(tot + 255) / 256, 256, 0, s>>>(src, bth, btl, knh, knl, N, totKN);
}

extern "C" void kernel_launch(void* const* d_in, const int* in_sizes, int n_in,
                              void* d_out, int out_size, void* d_ws, size_t ws_size,
                              hipStream_t stream)
{
    (void)in_sizes; (void)n_in; (void)out_size; (void)ws_size;
    const float* x    = (const float*)d_in[0];
    const float* cm   = (const float*)d_in[1];
    const float* mv   = (const float*)d_in[2];
    const float* wih0 = (const float*)d_in[3];
    const float* whh0 = (const float*)d_in[4];
    const float* bih0 = (const float*)d_in[5];
    const float* bhh0 = (const float*)d_in[6];
    const float* wih1 = (const float*)d_in[7];
    const float* whh1 = (const float*)d_in[8];
    const float* bih1 = (const float*)d_in[9];
    const float* bhh1 = (const float*)d_in[10];
    const float* w_ps = (const float*)d_in[11];
    const float* b_ps = (const float*)d_in[12];
    const float* w_hs = (const float*)d_in[13];
    const float* b_hs = (const float*)d_in[14];
    const float* w_ps_fore = (const float*)d_in[15];
    const float* b_ps_fore = (const float*)d_in[16];
    const float* w_hs_fore = (const float*)d_in[17];
    const float* b_hs_fore = (const float*)d_in[18];
    const float* w_ps_back = (const float*)d_in[19];
    const float* b_ps_back = (const float*)d_in[20];
    const float* w_hs_back = (const float*)d_in[21];
    const float* b_hs_back = (const float*)d_in[22];
    const float* w_indi = (const float*)d_in[23];
    const float* b_indi = (const float*)d_in[24];
    const float* w_out  = (const float*)d_in[25];
    const float* b_out  = (const float*)d_in[26];
    float* out = (float*)d_out;

    // ---- workspace layout (floats) ----
    float* ws = (float*)d_ws;
    float* BIG = ws;                         // 16,777,216 (overlaid)
    float* h0 = ws + 16777216;               // 524288 (unused)
    float* h1 = h0 + 524288;                 // x_hidden
    float* den = h1 + 524288;                // 512
    float* v1 = den + 512;                   // 512
    float* hidden = v1 + 512;                // 65536
    float* hidden2 = hidden + 65536;         // 65536
    float* xnorm = hidden2 + 65536;          // 4096
    float* h2n = xnorm + 4096;               // 512
    float* p0 = h2n + 512;                   // 524288
    float* p_shared = p0 + 524288;
    float* p_back = p_shared + 524288;
    float* out_ps = p_back + 524288;
    float* h_shared = out_ps + 524288;
    float* hn = h_shared + 524288;           // 4096
    float* diagv = hn + 4096;                // 4096
    float* colsum = diagv + 4096;            // 4096
    float* tvals = colsum + 4096;            // 40960
    int*   tidx = (int*)(tvals + 40960);     // 40960 ints
    float* hidden_h = (float*)(tidx + 40960);
    float* v2 = hidden_h + 524288;           // 4096
    float* hhn = v2 + 4096;                  // 4096
    float* hsi0 = hhn + 4096;                // 524288
    float* h_si = hsi0 + 524288;
    float* h_back = h_si + 524288;
    float* out_hs = h_back + 524288;
    float* indi = out_hs + 524288;
    float* out_indi = indi + 524288;
    float* extra = out_indi + 524288;

    // GRU-phase overlays inside BIG:
    float* seqt = BIG;
    unsigned short* wih0p = (unsigned short*)(BIG + 5242880);
    unsigned short* whh0p = wih0p + 12288;
    unsigned short* wih1p = whh0p + 49152;
    unsigned short* whh1p = wih1p + 49152;
    // concept-phase overlays inside BIG:
    float* s2cT = BIG;
    float* L    = BIG + 2097152;
    float* c2s  = BIG + 4194304;
    unsigned short* PB = (unsigned short*)(BIG + 6291456);
    unsigned short* pbt_xh_hi = PB;
    unsigned short* pbt_xh_lo = pbt_xh_hi + 524288;
    unsigned short* pkn_xh_hi = pbt_xh_lo + 524288;
    unsigned short* pkn_xh_lo = pkn_xh_hi + 524288;
    unsigned short* pbt_h2_hi = pkn_xh_lo + 524288;
    unsigned short* pbt_h2_lo = pbt_h2_hi + 65536;
    unsigned short* pkn_h2_hi = pbt_h2_lo + 65536;
    unsigned short* pkn_h2_lo = pkn_h2_hi + 65536;
    unsigned short* wps_hi  = pkn_h2_lo + 65536;
    unsigned short* wps_lo  = wps_hi + 16384;
    unsigned short* wpsb_hi = wps_lo + 16384;
    unsigned short* wpsb_lo = wpsb_hi + 16384;
    unsigned short* wpsf_hi = wpsb_lo + 16384;
    unsigned short* wpsf_lo = wpsf_hi + 16384;
    unsigned short* pbt_hsh_hi = (unsigned short*)p0;
    unsigned short* pbt_hsh_lo = pbt_hsh_hi + 524288;
    unsigned short* pbt_hh_hi = (unsigned short*)indi;
    unsigned short* pbt_hh_lo = pbt_hh_hi + 524288;
    unsigned short* pkn_hh_hi = (unsigned short*)out_indi;
    unsigned short* pkn_hh_lo = pkn_hh_hi + 524288;
    unsigned short* EX = (unsigned short*)extra;
    unsigned short* whs_hi  = EX;            unsigned short* whs_lo  = EX + 16384;
    unsigned short* whsb_hi = EX + 32768;    unsigned short* whsb_lo = EX + 49152;
    unsigned short* whsf_hi = EX + 65536;    unsigned short* whsf_lo = EX + 81920;
    unsigned short* wind_hi = EX + 98304;    unsigned short* wind_lo = EX + 114688;

    // ================= Phase A: MFMA 2-layer GRU =================
    seq_transpose<<<(TSTEPS * NR * DDIM) / 256, 256, 0, stream>>>(x, seqt);
    pack_wb<<<6, 256, 0, stream>>>(wih0, wih0p, DDIM, 1);
    pack_wb<<<24, 256, 0, stream>>>(whh0, whh0p, HDIM, 4);
    pack_wb<<<24, 256, 0, stream>>>(wih1, wih1p, HDIM, 4);
    pack_wb<<<24, 256, 0, stream>>>(whh1, whh1p, HDIM, 4);
    gru_mfma<<<NR / 16, 512, 0, stream>>>(seqt, wih0p, whh0p, wih1p, whh1p,
                                          bih0, bhh0, bih1, bhh1, h1);
    float* x_hidden = h1;

    // ================= Phase B: predefined-concept branch =================
    hipMemsetAsync(den, 0, CDIM * sizeof(float), stream);
    den_atomic<<<dim3(CDIM / 64, 32), 256, 0, stream>>>(cm, mv, den);
    s2ct_trans<<<dim3(NR / 64, CDIM / 64), 256, 0, stream>>>(cm, mv, den, s2cT);
    pboth(stream, x_hidden, pbt_xh_hi, pbt_xh_lo, pkn_xh_hi, pkn_xh_lo, NR);
    hipMemsetAsync(hidden, 0, 65536 * sizeof(float), stream);
    mg(stream, s2cT, pkn_xh_hi, pkn_xh_lo, nullptr, hidden, CDIM, HDIM, NR, 8, 0);
    row_nonzero<<<CDIM, 64, 0, stream>>>(hidden, v1);
    mg(stream, hidden, pbt_xh_hi, pbt_xh_lo, nullptr, L, CDIM, NR, HDIM, 1, 0);
    cos_softmax_row<<<CDIM, 256, 0, stream>>>(L, NR, nullptr, nullptr, nullptr);
    hipMemsetAsync(hidden2, 0, 65536 * sizeof(float), stream);
    mg(stream, L, pkn_xh_hi, pkn_xh_lo, nullptr, hidden2, CDIM, HDIM, NR, 8, 0);
    row_norm<<<NR, 64, 0, stream>>>(x_hidden, xnorm);
    row_norm<<<CDIM, 64, 0, stream>>>(hidden2, h2n);
    pboth(stream, hidden2, pbt_h2_hi, pbt_h2_lo, pkn_h2_hi, pkn_h2_lo, CDIM);
    mg(stream, x_hidden, pbt_h2_hi, pbt_h2_lo, nullptr, c2s, NR, CDIM, HDIM, 1, 0);
    cos_softmax_row<<<NR, 256, 0, stream>>>(c2s, CDIM, xnorm, h2n, v1);
    hipMemsetAsync(p0, 0, 524288 * sizeof(float), stream);
    mg(stream, c2s, pkn_h2_hi, pkn_h2_lo, nullptr, p0, NR, HDIM, CDIM, 2, 0);
    pbt(stream, w_ps, wps_hi, wps_lo, HDIM, HDIM);
    pbt(stream, w_ps_back, wpsb_hi, wpsb_lo, HDIM, HDIM);
    pbt(stream, w_ps_fore, wpsf_hi, wpsf_lo, HDIM, HDIM);
    mg(stream, p0, wps_hi, wps_lo, b_ps, p_shared, NR, HDIM, HDIM, 1, 1);
    mg(stream, p_shared, wpsb_hi, wpsb_lo, b_ps_back, p_back, NR, HDIM, HDIM, 1, 1);
    mg(stream, p_shared, wpsf_hi, wpsf_lo, b_ps_fore, out_ps, NR, HDIM, HDIM, 1, 1 | 2);

    // ================= Phase C: hidden-concept branch =================
    sub2_kernel<<<2048, 256, 0, stream>>>(x_hidden, p_back, h_shared);
    row_norm<<<NR, 64, 0, stream>>>(h_shared, hn);
    pbt(stream, h_shared, pbt_hsh_hi, pbt_hsh_lo, NR, HDIM);
    mg(stream, h_shared, pbt_hsh_hi, pbt_hsh_lo, nullptr, BIG, NR, NR, HDIM, 1, 0);
    scan_topk<<<NR, 256, 0, stream>>>(BIG, hn, diagv, tvals, tidx);
    hipMemsetAsync(colsum, 0, NR * sizeof(float), stream);
    hipMemsetAsync(hidden_h, 0, 524288 * sizeof(float), stream);
    colsum_scatter<<<(NR * KTOP + 255) / 256, 256, 0, stream>>>(tvals, tidx, colsum);
    hh_scatter<<<NR * KTOP, HDIM, 0, stream>>>(tvals, tidx, h_shared, hidden_h);
    hh_diag<<<2048, 256, 0, stream>>>(colsum, diagv, h_shared, hidden_h);
    row_norm_nz<<<NR, 64, 0, stream>>>(hidden_h, hhn, v2);
    pboth(stream, hidden_h, pbt_hh_hi, pbt_hh_lo, pkn_hh_hi, pkn_hh_lo, NR);
    hc2s_flash<<<NR / 16, 256, 0, stream>>>(h_shared, hn, hhn, v2,
                                            pbt_hh_hi, pbt_hh_lo,
                                            pkn_hh_hi, pkn_hh_lo, hsi0);
    pbt(stream, w_hs, whs_hi, whs_lo, HDIM, HDIM);
    pbt(stream, w_hs_back, whsb_hi, whsb_lo, HDIM, HDIM);
    pbt(stream, w_hs_fore, whsf_hi, whsf_lo, HDIM, HDIM);
    mg(stream, hsi0, whs_hi, whs_lo, b_hs, h_si, NR, HDIM, HDIM, 1, 1);
    mg(stream, h_si, whsb_hi, whsb_lo, b_hs_back, h_back, NR, HDIM, HDIM, 1, 1);
    mg(stream, h_si, whsf_hi, whsf_lo, b_hs_fore, out_hs, NR, HDIM, HDIM, 1, 1 | 2);

    // ================= Phase D: individual branch + head =================
    sub3_kernel<<<2048, 256, 0, stream>>>(x_hidden, p_back, h_back, indi);
    pbt(stream, w_indi, wind_hi, wind_lo, HDIM, HDIM);
    mg(stream, indi, wind_hi, wind_lo, b_indi, out_indi, NR, HDIM, HDIM, 1, 1 | 2);
    head_kernel<<<NR, 64, 0, stream>>>(out_ps, out_hs, out_indi, w_out, b_out, out);
}

// Round 10
// 939.771 us; speedup vs baseline: 7.9388x; 1.0165x over previous
//
#include <hip/hip_runtime.h>
#include <cstddef>

// Problem dims
#define NR 4096      // batch
#define CDIM 512     // concepts
#define HDIM 128     // hidden
#define TSTEPS 64
#define DDIM 20
#define KTOP 10

typedef __attribute__((ext_vector_type(8))) short short8;
typedef __attribute__((ext_vector_type(4))) float f32x4;

__device__ __forceinline__ unsigned short f2bf(float f) {
    union { float f; unsigned u; } x; x.f = f;
    unsigned r = (x.u + 0x7fffu + ((x.u >> 16) & 1u)) >> 16;
    return (unsigned short)r;
}
__device__ __forceinline__ float bf2f(unsigned short h) {
    union { unsigned u; float f; } x; x.u = ((unsigned)h) << 16;
    return x.f;
}
__device__ __forceinline__ float sigm(float v) {
    float c = fminf(fmaxf(v, -30.f), 30.f);
    return __fdividef(1.f, 1.f + __expf(-c));
}
__device__ __forceinline__ float tanh_f(float v) {
    float c = fminf(fmaxf(v, -10.f), 10.f);
    float e = __expf(2.f * c);
    return __fdividef(e - 1.f, e + 1.f);
}

#define MFMA16(a, b, c) __builtin_amdgcn_mfma_f32_16x16x32_bf16(a, b, c, 0, 0, 0)

// ---------------------------------------------------------------------------
// Generic MFMA GEMM. flags: 1 bias, 2 lrelu, 4 atomicAdd (split-K),
// 8 fused subtract: sub[r,c] = aux[r,c] - C[r,c]  (replaces sub2/sub3 passes)
// ---------------------------------------------------------------------------
struct MG {
    const float* A; const unsigned short* Bh; const unsigned short* Bl;
    const float* bias; float* C; const float* aux; float* sub;
    int N, K, kchunk, flags;
};

__global__ __launch_bounds__(256) void mfma_gemm(MG g)
{
    const int tid = threadIdx.x;
    const int w = tid >> 6, lane = tid & 63, quad = lane >> 4, lm = lane & 15;
    const int bm = (blockIdx.y << 6) + (w << 4);
    const int bn = blockIdx.x << 6;
    const int NC = g.K >> 5;
    const int c0 = (blockIdx.z * g.kchunk) >> 5;
    const int c1 = c0 + (g.kchunk >> 5);
    const float* arow = g.A + (size_t)(bm + lm) * g.K;
    f32x4 acc[4];
    #pragma unroll
    for (int t = 0; t < 4; t++) acc[t] = (f32x4){0.f, 0.f, 0.f, 0.f};

    for (int c = c0; c < c1; c++) {
        const float* ap = arow + (c << 5) + (quad << 3);
        float4 a0 = *(const float4*)ap;
        float4 a1 = *(const float4*)(ap + 4);
        short8 ah, al;
        #pragma unroll
        for (int j = 0; j < 4; j++) {
            float f = (&a0.x)[j];
            unsigned short h = f2bf(f);
            ah[j] = h; al[j] = f2bf(f - bf2f(h));
            f = (&a1.x)[j];
            h = f2bf(f);
            ah[4 + j] = h; al[4 + j] = f2bf(f - bf2f(h));
        }
        #pragma unroll
        for (int t = 0; t < 4; t++) {
            size_t bidx = ((size_t)(((bn >> 4) + t) * NC + c) * 64 + lane) * 8;
            short8 bh = *(const short8*)(g.Bh + bidx);
            short8 bl = *(const short8*)(g.Bl + bidx);
            acc[t] = MFMA16(ah, bh, acc[t]);
            acc[t] = MFMA16(ah, bl, acc[t]);
            acc[t] = MFMA16(al, bh, acc[t]);
        }
    }
    #pragma unroll
    for (int t = 0; t < 4; t++) {
        #pragma unroll
        for (int rg = 0; rg < 4; rg++) {
            int row = bm + (quad << 2) + rg;
            int col = bn + (t << 4) + lm;
            float v = acc[t][rg];
            if (g.flags & 1) v += g.bias[col];
            if (g.flags & 2) v = v > 0.f ? v : 0.01f * v;
            if (g.flags & 4) atomicAdd(&g.C[(size_t)row * g.N + col], v);
            else g.C[(size_t)row * g.N + col] = v;
            if (g.flags & 8)
                g.sub[(size_t)row * g.N + col] = g.aux[(size_t)row * g.N + col] - v;
        }
    }
}

// B-pack from [N,K] rows; layout [nt][c][lane][8], hi/lo planes.
__global__ void pack_bt(const float* __restrict__ src, unsigned short* __restrict__ hi,
                        unsigned short* __restrict__ lo, int K, int total)
{
    int idx = blockIdx.x * 256 + threadIdx.x;
    if (idx >= total) return;
    int NC = K >> 5;
    int lane = idx & 63;
    int c = (idx >> 6) % NC;
    int t = idx / (NC * 64);
    int n = (t << 4) + (lane & 15);
    int kb = (c << 5) + ((lane >> 4) << 3);
    #pragma unroll
    for (int j = 0; j < 8; j++) {
        float f = src[(size_t)n * K + kb + j];
        unsigned short h = f2bf(f);
        hi[(size_t)idx * 8 + j] = h;
        lo[(size_t)idx * 8 + j] = f2bf(f - bf2f(h));
    }
}

// Combined pack (K = HDIM = 128 only): BT (B[n][k]) + KN (B[k][n]) in one pass.
__global__ void pack_both(const float* __restrict__ src,
                          unsigned short* __restrict__ bth, unsigned short* __restrict__ btl,
                          unsigned short* __restrict__ knh, unsigned short* __restrict__ knl,
                          int N, int total_kn)
{
    int idx = blockIdx.x * 256 + threadIdx.x;
    int lane = idx & 63;
    int totBT = (N >> 4) * 256;
    if (idx < totBT) {
        int c = (idx >> 6) & 3;
        int t = idx >> 8;
        int n = (t << 4) + (lane & 15);
        int kb = (c << 5) + ((lane >> 4) << 3);
        #pragma unroll
        for (int j = 0; j < 8; j++) {
            float f = src[(size_t)n * HDIM + kb + j];
            unsigned short h = f2bf(f);
            bth[(size_t)idx * 8 + j] = h;
            btl[(size_t)idx * 8 + j] = f2bf(f - bf2f(h));
        }
    }
    if (idx < total_kn) {
        int NC = N >> 5;
        int c = (idx >> 6) % NC;
        int t = idx / (NC * 64);
        int n = (t << 4) + (lane & 15);
        int kb = (c << 5) + ((lane >> 4) << 3);
        #pragma unroll
        for (int j = 0; j < 8; j++) {
            float f = src[(size_t)(kb + j) * HDIM + n];
            unsigned short h = f2bf(f);
            knh[(size_t)idx * 8 + j] = h;
            knl[(size_t)idx * 8 + j] = f2bf(f - bf2f(h));
        }
    }
}

// Pack all seven [128,128] weight matrices in one launch.
struct W7 {
    const float* src[7];
    unsigned short* hi[7];
    unsigned short* lo[7];
};
__global__ void pack_w7(W7 p)
{
    int idx = blockIdx.x * 256 + threadIdx.x;   // 7 * 2048
    if (idx >= 7 * 2048) return;
    int m = idx >> 11;
    int r = idx & 2047;
    int lane = r & 63;
    int c = (r >> 6) & 3;
    int t = r >> 8;
    int n = (t << 4) + (lane & 15);
    int kb = (c << 5) + ((lane >> 4) << 3);
    const float* src = p.src[m];
    unsigned short* hi = p.hi[m];
    unsigned short* lo = p.lo[m];
    #pragma unroll
    for (int j = 0; j < 8; j++) {
        float f = src[(size_t)n * HDIM + kb + j];
        unsigned short h = f2bf(f);
        hi[(size_t)r * 8 + j] = h;
        lo[(size_t)r * 8 + j] = f2bf(f - bf2f(h));
    }
}

// ---------------------------------------------------------------------------
// scan_topk (unchanged)
// ---------------------------------------------------------------------------
__global__ __launch_bounds__(256) void scan_topk(const float* __restrict__ S,
        const float* __restrict__ hn, float* __restrict__ diagv,
        float* __restrict__ tvals, int* __restrict__ tidx)
{
    int row = blockIdx.x;
    const float* d = S + (size_t)row * NR;
    int tid = threadIdx.x;
    float hi_ = hn[row];
    float lv[16]; int li[16];
    #pragma unroll
    for (int i = 0; i < 16; i++) {
        int j = tid + i * 256;
        float v = d[j] / fmaxf(hi_ * hn[j], 1e-12f);
        if (j == row) { diagv[row] = v; v = 0.f; }
        lv[i] = v;
        li[i] = j;
    }
    __shared__ float sv[256];
    __shared__ int si[256];
    for (int k = 0; k < KTOP; k++) {
        float bv = -INFINITY; int bi = 0x7fffffff;
        #pragma unroll
        for (int i = 0; i < 16; i++) {
            if (lv[i] > bv || (lv[i] == bv && li[i] < bi)) { bv = lv[i]; bi = li[i]; }
        }
        sv[tid] = bv; si[tid] = bi;
        __syncthreads();
        for (int sdx = 128; sdx > 0; sdx >>= 1) {
            if (tid < sdx) {
                if (sv[tid + sdx] > sv[tid] || (sv[tid + sdx] == sv[tid] && si[tid + sdx] < si[tid])) {
                    sv[tid] = sv[tid + sdx]; si[tid] = si[tid + sdx];
                }
            }
            __syncthreads();
        }
        if (tid == 0) { tvals[row * KTOP + k] = sv[0]; tidx[row * KTOP + k] = si[0]; }
        int wn = si[0];
        if ((wn & 255) == tid) lv[wn >> 8] = -INFINITY;
        __syncthreads();
    }
}

// ---------------------------------------------------------------------------
// hc2s_flash (unchanged)
// ---------------------------------------------------------------------------
__global__ __launch_bounds__(256) void hc2s_flash(
    const float* __restrict__ hsh, const float* __restrict__ hn,
    const float* __restrict__ hhn, const float* __restrict__ v2,
    const unsigned short* __restrict__ Bh, const unsigned short* __restrict__ Bl,
    const unsigned short* __restrict__ Vh, const unsigned short* __restrict__ Vl,
    float* __restrict__ O)
{
    __shared__ __attribute__((aligned(16))) unsigned short Ph[16 * 72];
    __shared__ __attribute__((aligned(16))) unsigned short Pl[16 * 72];
    __shared__ float redmax[4][16];
    __shared__ float redsum[4][16];

    const int tid = threadIdx.x;
    const int wv = tid >> 6, lane = tid & 63, quad = lane >> 4, lm = lane & 15;
    const int bm = blockIdx.x << 4;

    short8 ahh[4], ahl[4];
    #pragma unroll
    for (int c = 0; c < 4; c++) {
        const float* ap = hsh + (size_t)(bm + lm) * HDIM + (c << 5) + (quad << 3);
        float4 a0 = *(const float4*)ap;
        float4 a1 = *(const float4*)(ap + 4);
        #pragma unroll
        for (int j = 0; j < 4; j++) {
            float f = (&a0.x)[j];
            unsigned short h = f2bf(f);
            ahh[c][j] = h; ahl[c][j] = f2bf(f - bf2f(h));
            f = (&a1.x)[j];
            h = f2bf(f);
            ahh[c][4 + j] = h; ahl[c][4 + j] = f2bf(f - bf2f(h));
        }
    }
    float hnr[4];
    #pragma unroll
    for (int rg = 0; rg < 4; rg++) hnr[rg] = hn[bm + (quad << 2) + rg];

    float m_old[4], l_old[4];
    #pragma unroll
    for (int rg = 0; rg < 4; rg++) { m_old[rg] = -INFINITY; l_old[rg] = 0.f; }
    f32x4 o0 = (f32x4){0.f, 0.f, 0.f, 0.f};
    f32x4 o1 = (f32x4){0.f, 0.f, 0.f, 0.f};

    for (int jt = 0; jt < NR / 64; jt++) {
        f32x4 s = (f32x4){0.f, 0.f, 0.f, 0.f};
        int nt = (jt << 2) + wv;
        #pragma unroll
        for (int c = 0; c < 4; c++) {
            size_t bidx = ((size_t)(nt * 4 + c) * 64 + lane) * 8;
            short8 bh = *(const short8*)(Bh + bidx);
            short8 bl = *(const short8*)(Bl + bidx);
            s = MFMA16(ahh[c], bh, s);
            s = MFMA16(ahh[c], bl, s);
            s = MFMA16(ahl[c], bh, s);
        }
        int col = (jt << 6) + (wv << 4) + lm;
        float hc = hhn[col];
        float vm = v2[col];
        float sv[4];
        #pragma unroll
        for (int rg = 0; rg < 4; rg++) {
            float v = s[rg] / fmaxf(hnr[rg] * hc, 1e-12f);
            sv[rg] = (vm == 0.f) ? -1e9f : v;
        }
        float mx[4];
        #pragma unroll
        for (int rg = 0; rg < 4; rg++) {
            float m = sv[rg];
            #pragma unroll
            for (int d = 1; d < 16; d <<= 1) m = fmaxf(m, __shfl_xor(m, d));
            mx[rg] = m;
        }
        if (lm == 0) {
            #pragma unroll
            for (int rg = 0; rg < 4; rg++) redmax[wv][(quad << 2) + rg] = mx[rg];
        }
        __syncthreads();
        float m_new[4], alpha[4];
        #pragma unroll
        for (int rg = 0; rg < 4; rg++) {
            int r = (quad << 2) + rg;
            float mt = fmaxf(fmaxf(redmax[0][r], redmax[1][r]),
                             fmaxf(redmax[2][r], redmax[3][r]));
            m_new[rg] = fmaxf(m_old[rg], mt);
            alpha[rg] = __expf(m_old[rg] - m_new[rg]);
        }
        float psum[4];
        #pragma unroll
        for (int rg = 0; rg < 4; rg++) {
            float p = __expf(sv[rg] - m_new[rg]);
            float ssum = p;
            #pragma unroll
            for (int d = 1; d < 16; d <<= 1) ssum += __shfl_xor(ssum, d);
            psum[rg] = ssum;
            int off = ((quad << 2) + rg) * 72 + (wv << 4) + lm;
            unsigned short h = f2bf(p);
            Ph[off] = h;
            Pl[off] = f2bf(p - bf2f(h));
        }
        if (lm == 0) {
            #pragma unroll
            for (int rg = 0; rg < 4; rg++) redsum[wv][(quad << 2) + rg] = psum[rg];
        }
        __syncthreads();
        #pragma unroll
        for (int rg = 0; rg < 4; rg++) {
            int r = (quad << 2) + rg;
            float ts = redsum[0][r] + redsum[1][r] + redsum[2][r] + redsum[3][r];
            l_old[rg] = l_old[rg] * alpha[rg] + ts;
            m_old[rg] = m_new[rg];
            o0[rg] *= alpha[rg];
            o1[rg] *= alpha[rg];
        }
        int vt0 = wv << 1;
        #pragma unroll
        for (int c2 = 0; c2 < 2; c2++) {
            int poff = lm * 72 + (c2 << 5) + (quad << 3);
            short8 pah = *(const short8*)&Ph[poff];
            short8 pal = *(const short8*)&Pl[poff];
            int cg = (jt << 1) + c2;
            size_t b0 = ((size_t)(vt0 * 128 + cg) * 64 + lane) * 8;
            size_t b1 = ((size_t)((vt0 + 1) * 128 + cg) * 64 + lane) * 8;
            short8 vh0 = *(const short8*)(Vh + b0);
            short8 vl0 = *(const short8*)(Vl + b0);
            short8 vh1 = *(const short8*)(Vh + b1);
            short8 vl1 = *(const short8*)(Vl + b1);
            o0 = MFMA16(pah, vh0, o0);
            o0 = MFMA16(pah, vl0, o0);
            o0 = MFMA16(pal, vh0, o0);
            o1 = MFMA16(pah, vh1, o1);
            o1 = MFMA16(pah, vl1, o1);
            o1 = MFMA16(pal, vh1, o1);
        }
        __syncthreads();
    }
    #pragma unroll
    for (int rg = 0; rg < 4; rg++) {
        int row = bm + (quad << 2) + rg;
        float inv = __fdividef(1.f, l_old[rg]);
        O[(size_t)row * HDIM + (wv << 5) + lm] = o0[rg] * inv;
        O[(size_t)row * HDIM + (wv << 5) + 16 + lm] = o1[rg] * inv;
    }
}

// ---------------------------------------------------------------------------
// GRU weight pack
// ---------------------------------------------------------------------------
__global__ void pack_wb(const float* __restrict__ W, unsigned short* __restrict__ Wp,
                        int K, int nch)
{
    int idx = blockIdx.x * 256 + threadIdx.x;
    if (idx >= 24 * nch * 64) return;
    int lane = idx & 63;
    int c = (idx >> 6) % nch;
    int t = idx / (nch * 64);
    int n = t * 16 + (lane & 15);
    int kb = c * 32 + (lane >> 4) * 8;
    #pragma unroll
    for (int j = 0; j < 8; j++) {
        int k = kb + j;
        float f = (k < K) ? W[(size_t)n * K + k] : 0.f;
        Wp[(size_t)idx * 8 + j] = f2bf(f);
    }
}

// x [N, D*T] -> seq [T, N, D]
__global__ void seq_transpose(const float* __restrict__ x, float* __restrict__ seq)
{
    int idx = blockIdx.x * 256 + threadIdx.x;
    int d = idx % DDIM;
    int r = idx / DDIM;
    int n = r & (NR - 1);
    int t = r >> 12;
    seq[idx] = x[(size_t)n * (DDIM * TSTEPS) + d * TSTEPS + t];
}

// ---------------------------------------------------------------------------
// MFMA 2-layer GRU, 8 waves, register weights, TIME-DOUBLE-BUFFERED h state:
// hA[buf][layer][plane]. Reads come from buf rb=b^1, writes go to buf b ->
// only ONE barrier per step (between h0-write/x-stage and L1-reads). All other
// cross-wave read/write pairs land on opposite buffers or are ordered by the
// next step's barrier (waves can lead by at most one barrier).
// ---------------------------------------------------------------------------
__global__ __launch_bounds__(512) void gru_mfma(
    const float* __restrict__ seq,
    const unsigned short* __restrict__ wih0p,
    const unsigned short* __restrict__ whh0p,
    const unsigned short* __restrict__ wih1p,
    const unsigned short* __restrict__ whh1p,
    const float* __restrict__ bih0, const float* __restrict__ bhh0,
    const float* __restrict__ bih1, const float* __restrict__ bhh1,
    float* __restrict__ xh)
{
    __shared__ __attribute__((aligned(16))) unsigned short hA[2][2][2][16 * 136]; // 34.8 KB
    __shared__ __attribute__((aligned(16))) unsigned short xA[2][2][16 * 40];     // 5.1 KB

    const int tid = threadIdx.x;
    const int w2 = tid >> 6;
    const int lane = tid & 63;
    const int quad = lane >> 4;
    const int lm = lane & 15;
    const int n0 = blockIdx.x << 4;
    const int j = (w2 << 4) + lm;

    for (int i = tid; i < 2 * 2 * 2 * 16 * 136; i += 512) ((unsigned short*)hA)[i] = 0;
    for (int i = tid; i < 2 * 2 * 16 * 40; i += 512) ((unsigned short*)xA)[i] = 0;

    float br0 = bih0[j] + bhh0[j];
    float bz0 = bih0[128 + j] + bhh0[128 + j];
    float bni0 = bih0[256 + j];
    float bnh0 = bhh0[256 + j];
    float br1 = bih1[j] + bhh1[j];
    float bz1 = bih1[128 + j] + bhh1[128 + j];
    float bni1 = bih1[256 + j];
    float bnh1 = bhh1[256 + j];

    // register-resident weight fragments (t-invariant)
    short8 W0x[3], W0h[3][4], W1x[3][4], W1h[3][4];
    {
        const int lb = lane * 8;
        W0x[0] = *(const short8*)&wih0p[(size_t)(w2) * 512 + lb];
        W0x[1] = *(const short8*)&wih0p[(size_t)(8 + w2) * 512 + lb];
        W0x[2] = *(const short8*)&wih0p[(size_t)(16 + w2) * 512 + lb];
        #pragma unroll
        for (int c = 0; c < 4; c++) {
            W0h[0][c] = *(const short8*)&whh0p[(size_t)((w2) * 4 + c) * 512 + lb];
            W0h[1][c] = *(const short8*)&whh0p[(size_t)((8 + w2) * 4 + c) * 512 + lb];
            W0h[2][c] = *(const short8*)&whh0p[(size_t)((16 + w2) * 4 + c) * 512 + lb];
            W1x[0][c] = *(const short8*)&wih1p[(size_t)((w2) * 4 + c) * 512 + lb];
            W1x[1][c] = *(const short8*)&wih1p[(size_t)((8 + w2) * 4 + c) * 512 + lb];
            W1x[2][c] = *(const short8*)&wih1p[(size_t)((16 + w2) * 4 + c) * 512 + lb];
            W1h[0][c] = *(const short8*)&whh1p[(size_t)((w2) * 4 + c) * 512 + lb];
            W1h[1][c] = *(const short8*)&whh1p[(size_t)((8 + w2) * 4 + c) * 512 + lb];
            W1h[2][c] = *(const short8*)&whh1p[(size_t)((16 + w2) * 4 + c) * 512 + lb];
        }
    }

    const int aoff = lm * 136 + quad * 8;
    const int xoff = lm * 40 + quad * 8;

    {
        const float* src = seq + (size_t)n0 * DDIM;
        for (int i = tid; i < 16 * DDIM; i += 512) {
            int m = i / DDIM, d = i % DDIM;
            float v = src[i];
            unsigned short hi = f2bf(v);
            xA[0][0][m * 40 + d] = hi;
            xA[0][1][m * 40 + d] = f2bf(v - bf2f(hi));
        }
    }
    __syncthreads();

    for (int t = 0; t < TSTEPS; t++) {
        const int b = t & 1, rb = b ^ 1;
        f32x4 accr = (f32x4){0.f, 0.f, 0.f, 0.f};
        f32x4 accz = (f32x4){0.f, 0.f, 0.f, 0.f};
        f32x4 accni = (f32x4){0.f, 0.f, 0.f, 0.f};
        f32x4 accnh = (f32x4){0.f, 0.f, 0.f, 0.f};

        // ---- phase 1: L0 (reads hA[rb][0], xA[b]) ----
        {
            short8 axh = *(const short8*)&xA[b][0][xoff];
            short8 axl = *(const short8*)&xA[b][1][xoff];
            accr = MFMA16(axh, W0x[0], accr);
            accr = MFMA16(axl, W0x[0], accr);
            accz = MFMA16(axh, W0x[1], accz);
            accz = MFMA16(axl, W0x[1], accz);
            accni = MFMA16(axh, W0x[2], accni);
            accni = MFMA16(axl, W0x[2], accni);
        }
        #pragma unroll
        for (int c = 0; c < 4; c++) {
            short8 ahh = *(const short8*)&hA[rb][0][0][aoff + c * 32];
            short8 ahl = *(const short8*)&hA[rb][0][1][aoff + c * 32];
            accr = MFMA16(ahh, W0h[0][c], accr);
            accr = MFMA16(ahl, W0h[0][c], accr);
            accz = MFMA16(ahh, W0h[1][c], accz);
            accz = MFMA16(ahl, W0h[1][c], accz);
            accnh = MFMA16(ahh, W0h[2][c], accnh);
            accnh = MFMA16(ahl, W0h[2][c], accnh);
        }
        float hold[4];
        #pragma unroll
        for (int rg = 0; rg < 4; rg++) {
            int off = (quad * 4 + rg) * 136 + j;
            hold[rg] = bf2f(hA[rb][0][0][off]) + bf2f(hA[rb][0][1][off]);
        }

        // ---- phase 2: write h0-new -> hA[b][0]; stage x(t+1) -> xA[rb] ----
        #pragma unroll
        for (int rg = 0; rg < 4; rg++) {
            float r = sigm(accr[rg] + br0);
            float z = sigm(accz[rg] + bz0);
            float nc = tanh_f(accni[rg] + bni0 + r * (accnh[rg] + bnh0));
            float hnew = (1.f - z) * nc + z * hold[rg];
            int off = (quad * 4 + rg) * 136 + j;
            unsigned short hi = f2bf(hnew);
            hA[b][0][0][off] = hi;
            hA[b][0][1][off] = f2bf(hnew - bf2f(hi));
        }
        if (t + 1 < TSTEPS) {
            const float* src = seq + ((size_t)(t + 1) * NR + n0) * DDIM;
            for (int i = tid; i < 16 * DDIM; i += 512) {
                int m = i / DDIM, d = i % DDIM;
                float v = src[i];
                unsigned short hi = f2bf(v);
                xA[rb][0][m * 40 + d] = hi;
                xA[rb][1][m * 40 + d] = f2bf(v - bf2f(hi));
            }
        }
        __syncthreads();     // the ONE barrier: h0-new + x(t+1) visible

        // ---- phase 3: L1 (reads hA[b][0] new, hA[rb][1] old) ----
        accr = (f32x4){0.f, 0.f, 0.f, 0.f};
        accz = (f32x4){0.f, 0.f, 0.f, 0.f};
        accni = (f32x4){0.f, 0.f, 0.f, 0.f};
        accnh = (f32x4){0.f, 0.f, 0.f, 0.f};
        #pragma unroll
        for (int c = 0; c < 4; c++) {
            short8 a0h = *(const short8*)&hA[b][0][0][aoff + c * 32];
            short8 a0l = *(const short8*)&hA[b][0][1][aoff + c * 32];
            short8 a1h = *(const short8*)&hA[rb][1][0][aoff + c * 32];
            short8 a1l = *(const short8*)&hA[rb][1][1][aoff + c * 32];
            accr = MFMA16(a0h, W1x[0][c], accr);
            accr = MFMA16(a0l, W1x[0][c], accr);
            accr = MFMA16(a1h, W1h[0][c], accr);
            accr = MFMA16(a1l, W1h[0][c], accr);
            accz = MFMA16(a0h, W1x[1][c], accz);
            accz = MFMA16(a0l, W1x[1][c], accz);
            accz = MFMA16(a1h, W1h[1][c], accz);
            accz = MFMA16(a1l, W1h[1][c], accz);
            accni = MFMA16(a0h, W1x[2][c], accni);
            accni = MFMA16(a0l, W1x[2][c], accni);
            accnh = MFMA16(a1h, W1h[2][c], accnh);
            accnh = MFMA16(a1l, W1h[2][c], accnh);
        }
        #pragma unroll
        for (int rg = 0; rg < 4; rg++) {
            int off = (quad * 4 + rg) * 136 + j;
            hold[rg] = bf2f(hA[rb][1][0][off]) + bf2f(hA[rb][1][1][off]);
        }

        // ---- phase 4: write h1-new -> hA[b][1] (no barrier; next step's
        // barrier orders it before the next L1-read) ----
        #pragma unroll
        for (int rg = 0; rg < 4; rg++) {
            float r = sigm(accr[rg] + br1);
            float z = sigm(accz[rg] + bz1);
            float nc = tanh_f(accni[rg] + bni1 + r * (accnh[rg] + bnh1));
            float hnew = (1.f - z) * nc + z * hold[rg];
            int off = (quad * 4 + rg) * 136 + j;
            unsigned short hi = f2bf(hnew);
            hA[b][1][0][off] = hi;
            hA[b][1][1][off] = f2bf(hnew - bf2f(hi));
            if (t + 1 == TSTEPS)
                xh[(size_t)(n0 + quad * 4 + rg) * HDIM + j] = hnew;
        }
    }
}

// ---------------------------------------------------------------------------
// den / s2ct (unchanged)
// ---------------------------------------------------------------------------
__global__ __launch_bounds__(256) void den_atomic(const float* __restrict__ cm,
        const float* __restrict__ mv, float* __restrict__ den)
{
    int c = blockIdx.x * 64 + (threadIdx.x & 63);
    int rg = threadIdx.x >> 6;
    int nbase = blockIdx.y * 128;
    float acc = 0.f;
    for (int i = 0; i < 32; i++) {
        int n = nbase + rg + (i << 2);
        acc += cm[(size_t)n * CDIM + c] * mv[n];
    }
    __shared__ float red[4][64];
    red[rg][threadIdx.x & 63] = acc;
    __syncthreads();
    if (rg == 0)
        atomicAdd(&den[c], red[0][threadIdx.x] + red[1][threadIdx.x] +
                           red[2][threadIdx.x] + red[3][threadIdx.x]);
}

__global__ __launch_bounds__(256) void s2ct_trans(const float* __restrict__ cm,
        const float* __restrict__ mv, const float* __restrict__ den,
        float* __restrict__ s2cT)
{
    __shared__ float tile[64][65];
    __shared__ float mvs[64];
    const int tid = threadIdx.x;
    const int n0 = blockIdx.x << 6;
    const int c0 = blockIdx.y << 6;
    const int lc = tid & 63, lr = tid >> 6;
    if (tid < 64) mvs[tid] = mv[n0 + tid];
    #pragma unroll
    for (int i = 0; i < 16; i++) {
        int n = lr + (i << 2);
        tile[n][lc] = cm[(size_t)(n0 + n) * CDIM + c0 + lc];
    }
    __syncthreads();
    #pragma unroll
    for (int i = 0; i < 16; i++) {
        int c = lr + (i << 2);
        float m = tile[lc][c];
        float d = den[c0 + c];
        s2cT[(size_t)(c0 + c) * NR + n0 + lc] = (m * mvs[lc]) / (d * m + 1.f);
    }
}

// ---------------------------------------------------------------------------
// Small helpers
// ---------------------------------------------------------------------------
__global__ void row_norm(const float* __restrict__ a, float* __restrict__ out)
{
    int r = blockIdx.x;
    float acc = 0.f;
    for (int h = threadIdx.x; h < HDIM; h += 64) {
        float v = a[(size_t)r * HDIM + h];
        acc += v * v;
    }
    for (int o = 32; o > 0; o >>= 1) acc += __shfl_down(acc, o);
    if (threadIdx.x == 0) out[r] = sqrtf(acc);
}

__global__ void row_nonzero(const float* __restrict__ a, float* __restrict__ out)
{
    int r = blockIdx.x;
    float acc = 0.f;
    for (int h = threadIdx.x; h < HDIM; h += 64) acc += a[(size_t)r * HDIM + h];
    for (int o = 32; o > 0; o >>= 1) acc += __shfl_down(acc, o);
    if (threadIdx.x == 0) out[r] = (acc != 0.f) ? 1.f : 0.f;
}

__global__ void row_norm_nz(const float* __restrict__ a, float* __restrict__ nrm,
                            float* __restrict__ nz)
{
    int r = blockIdx.x;
    float acc = 0.f, s = 0.f;
    for (int h = threadIdx.x; h < HDIM; h += 64) {
        float v = a[(size_t)r * HDIM + h];
        acc += v * v;
        s += v;
    }
    for (int o = 32; o > 0; o >>= 1) { acc += __shfl_down(acc, o); s += __shfl_down(s, o); }
    if (threadIdx.x == 0) { nrm[r] = sqrtf(acc); nz[r] = (s != 0.f) ? 1.f : 0.f; }
}

__global__ __launch_bounds__(256) void cos_softmax_row(float* __restrict__ data, int N,
        const float* __restrict__ rn, const float* __restrict__ cn,
        const float* __restrict__ vmask)
{
    int row = blockIdx.x;
    float* d = data + (size_t)row * N;
    int tid = threadIdx.x;
    __shared__ float red[256];
    float rnv = rn ? rn[row] : 0.f;
    float mx = -INFINITY;
    for (int j = tid; j < N; j += 256) {
        float v = d[j];
        if (cn) v = v / fmaxf(rnv * cn[j], 1e-12f);
        if (vmask && vmask[j] == 0.f) v = -1e9f;
        d[j] = v;
        mx = fmaxf(mx, v);
    }
    red[tid] = mx; __syncthreads();
    for (int sdx = 128; sdx > 0; sdx >>= 1) {
        if (tid < sdx) red[tid] = fmaxf(red[tid], red[tid + sdx]);
        __syncthreads();
    }
    float M = red[0]; __syncthreads();
    float sum = 0.f;
    for (int j = tid; j < N; j += 256) {
        float e = expf(d[j] - M);
        d[j] = e;
        sum += e;
    }
    red[tid] = sum; __syncthreads();
    for (int sdx = 128; sdx > 0; sdx >>= 1) {
        if (tid < sdx) red[tid] += red[tid + sdx];
        __syncthreads();
    }
    float inv = 1.f / red[0];
    for (int j = tid; j < N; j += 256) {
        float v = d[j] * inv;
        if (vmask) v *= vmask[j];
        d[j] = v;
    }
}

__global__ void colsum_scatter(const float* __restrict__ vals, const int* __restrict__ idxs,
                               float* __restrict__ colsum)
{
    int idx = blockIdx.x * 256 + threadIdx.x;
    if (idx < NR * KTOP) atomicAdd(&colsum[idxs[idx]], vals[idx]);
}

__global__ void hh_scatter(const float* __restrict__ vals, const int* __restrict__ idxs,
                           const float* __restrict__ hsh, float* __restrict__ hh)
{
    int p = blockIdx.x;
    int j = idxs[p];
    float v = vals[p];
    int i = p / KTOP;
    atomicAdd(&hh[(size_t)j * HDIM + threadIdx.x], v * hsh[(size_t)i * HDIM + threadIdx.x]);
}

__global__ void hh_diag(const float* __restrict__ colsum, const float* __restrict__ diag,
                        const float* __restrict__ hsh, float* __restrict__ hh)
{
    int idx = blockIdx.x * 256 + threadIdx.x;
    int j = idx >> 7;
    if (colsum[j] != 0.f) hh[idx] += diag[j] * hsh[idx];
}

__global__ void head_kernel(const float* __restrict__ ps, const float* __restrict__ hs,
                            const float* __restrict__ indi, const float* __restrict__ w,
                            const float* __restrict__ b, float* __restrict__ out)
{
    int n = blockIdx.x;
    int t = threadIdx.x;
    float acc = 0.f;
    for (int h = t; h < HDIM; h += 64) {
        size_t k = (size_t)n * HDIM + h;
        acc += (ps[k] + hs[k] + indi[k]) * w[h];
    }
    for (int o = 32; o > 0; o >>= 1) acc += __shfl_down(acc, o);
    if (t == 0) out[n] = acc + b[0];
}

// ---------------------------------------------------------------------------
// host-side helpers
// ---------------------------------------------------------------------------
static inline void mg(hipStream_t s, const float* A, const unsigned short* Bh,
                      const unsigned short* Bl, const float* bias, float* C,
                      int M, int N, int K, int z, int flags,
                      const float* aux = nullptr, float* sub = nullptr)
{
    MG g{A, Bh, Bl, bias, C, aux, sub, N, K, K / z, flags | (z > 1 ? 4 : 0)};
    mfma_gemm<<<dim3(N / 64, M / 64, z), 256, 0, s>>>(g);
}
static inline void pbt(hipStream_t s, const float* src, unsigned short* hi,
                       unsigned short* lo, int N, int K)
{
    int total = (N / 16) * (K / 32) * 64;
    pack_bt<<<(total + 255) / 256, 256, 0, s>>>(src, hi, lo, K, total);
}
static inline void pboth(hipStream_t s, const float* src,
                         unsigned short* bth, unsigned short* btl,
                         unsigned short* knh, unsigned short* knl, int N)
{
    int totBT = (N / 16) * 4 * 64;
    int totKN = 8 * (N / 32) * 64;
    int tot = totBT > totKN ? totBT : totKN;
    pack_both<<<(tot + 255) / 256, 256, 0, s>>>(src, bth, btl, knh, knl, N, totKN);
}

extern "C" void kernel_launch(void* const* d_in, const int* in_sizes, int n_in,
                              void* d_out, int out_size, void* d_ws, size_t ws_size,
                              hipStream_t stream)
{
    (void)in_sizes; (void)n_in; (void)out_size; (void)ws_size;
    const float* x    = (const float*)d_in[0];
    const float* cm   = (const float*)d_in[1];
    const float* mv   = (const float*)d_in[2];
    const float* wih0 = (const float*)d_in[3];
    const float* whh0 = (const float*)d_in[4];
    const float* bih0 = (const float*)d_in[5];
    const float* bhh0 = (const float*)d_in[6];
    const float* wih1 = (const float*)d_in[7];
    const float* whh1 = (const float*)d_in[8];
    const float* bih1 = (const float*)d_in[9];
    const float* bhh1 = (const float*)d_in[10];
    const float* w_ps = (const float*)d_in[11];
    const float* b_ps = (const float*)d_in[12];
    const float* w_hs = (const float*)d_in[13];
    const float* b_hs = (const float*)d_in[14];
    const float* w_ps_fore = (const float*)d_in[15];
    const float* b_ps_fore = (const float*)d_in[16];
    const float* w_hs_fore = (const float*)d_in[17];
    const float* b_hs_fore = (const float*)d_in[18];
    const float* w_ps_back = (const float*)d_in[19];
    const float* b_ps_back = (const float*)d_in[20];
    const float* w_hs_back = (const float*)d_in[21];
    const float* b_hs_back = (const float*)d_in[22];
    const float* w_indi = (const float*)d_in[23];
    const float* b_indi = (const float*)d_in[24];
    const float* w_out  = (const float*)d_in[25];
    const float* b_out  = (const float*)d_in[26];
    float* out = (float*)d_out;

    // ---- workspace layout (floats) ----
    float* ws = (float*)d_ws;
    float* BIG = ws;                         // 16,777,216 (overlaid)
    float* h0 = ws + 16777216;               // 524288 (unused)
    float* h1 = h0 + 524288;                 // x_hidden
    float* den = h1 + 524288;                // 512
    float* v1 = den + 512;                   // 512
    float* hidden = v1 + 512;                // 65536
    float* hidden2 = hidden + 65536;         // 65536
    float* xnorm = hidden2 + 65536;          // 4096
    float* h2n = xnorm + 4096;               // 512
    float* p0 = h2n + 512;                   // 524288
    float* p_shared = p0 + 524288;
    float* p_back = p_shared + 524288;
    float* out_ps = p_back + 524288;
    float* h_shared = out_ps + 524288;
    float* hn = h_shared + 524288;           // 4096
    float* diagv = hn + 4096;                // 4096
    float* colsum = diagv + 4096;            // 4096
    float* tvals = colsum + 4096;            // 40960
    int*   tidx = (int*)(tvals + 40960);     // 40960 ints
    float* hidden_h = (float*)(tidx + 40960);
    float* v2 = hidden_h + 524288;           // 4096
    float* hhn = v2 + 4096;                  // 4096
    float* hsi0 = hhn + 4096;                // 524288
    float* h_si = hsi0 + 524288;
    float* h_back = h_si + 524288;
    float* out_hs = h_back + 524288;
    float* indi = out_hs + 524288;
    float* out_indi = indi + 524288;
    float* extra = out_indi + 524288;

    // GRU-phase overlays inside BIG:
    float* seqt = BIG;
    unsigned short* wih0p = (unsigned short*)(BIG + 5242880);
    unsigned short* whh0p = wih0p + 12288;
    unsigned short* wih1p = whh0p + 49152;
    unsigned short* whh1p = wih1p + 49152;
    // concept-phase overlays inside BIG:
    float* s2cT = BIG;
    float* L    = BIG + 2097152;
    float* c2s  = BIG + 4194304;
    unsigned short* PB = (unsigned short*)(BIG + 6291456);
    unsigned short* pbt_xh_hi = PB;
    unsigned short* pbt_xh_lo = pbt_xh_hi + 524288;
    unsigned short* pkn_xh_hi = pbt_xh_lo + 524288;
    unsigned short* pkn_xh_lo = pkn_xh_hi + 524288;
    unsigned short* pbt_h2_hi = pkn_xh_lo + 524288;
    unsigned short* pbt_h2_lo = pbt_h2_hi + 65536;
    unsigned short* pkn_h2_hi = pbt_h2_lo + 65536;
    unsigned short* pkn_h2_lo = pkn_h2_hi + 65536;
    unsigned short* wps_hi  = pkn_h2_lo + 65536;
    unsigned short* wps_lo  = wps_hi + 16384;
    unsigned short* wpsb_hi = wps_lo + 16384;
    unsigned short* wpsb_lo = wpsb_hi + 16384;
    unsigned short* wpsf_hi = wpsb_lo + 16384;
    unsigned short* wpsf_lo = wpsf_hi + 16384;
    unsigned short* pbt_hsh_hi = (unsigned short*)p0;
    unsigned short* pbt_hsh_lo = pbt_hsh_hi + 524288;
    unsigned short* pbt_hh_hi = (unsigned short*)indi;
    unsigned short* pbt_hh_lo = pbt_hh_hi + 524288;
    unsigned short* pkn_hh_hi = (unsigned short*)out_indi;
    unsigned short* pkn_hh_lo = pkn_hh_hi + 524288;
    unsigned short* EX = (unsigned short*)extra;
    unsigned short* whs_hi  = EX;            unsigned short* whs_lo  = EX + 16384;
    unsigned short* whsb_hi = EX + 32768;    unsigned short* whsb_lo = EX + 49152;
    unsigned short* whsf_hi = EX + 65536;    unsigned short* whsf_lo = EX + 81920;
    unsigned short* wind_hi = EX + 98304;    unsigned short* wind_lo = EX + 114688;

    // ================= Phase A: MFMA 2-layer GRU =================
    seq_transpose<<<(TSTEPS * NR * DDIM) / 256, 256, 0, stream>>>(x, seqt);
    pack_wb<<<6, 256, 0, stream>>>(wih0, wih0p, DDIM, 1);
    pack_wb<<<24, 256, 0, stream>>>(whh0, whh0p, HDIM, 4);
    pack_wb<<<24, 256, 0, stream>>>(wih1, wih1p, HDIM, 4);
    pack_wb<<<24, 256, 0, stream>>>(whh1, whh1p, HDIM, 4);
    {
        W7 w7;
        w7.src[0] = w_ps;      w7.hi[0] = wps_hi;  w7.lo[0] = wps_lo;
        w7.src[1] = w_ps_back; w7.hi[1] = wpsb_hi; w7.lo[1] = wpsb_lo;
        w7.src[2] = w_ps_fore; w7.hi[2] = wpsf_hi; w7.lo[2] = wpsf_lo;
        w7.src[3] = w_hs;      w7.hi[3] = whs_hi;  w7.lo[3] = whs_lo;
        w7.src[4] = w_hs_back; w7.hi[4] = whsb_hi; w7.lo[4] = whsb_lo;
        w7.src[5] = w_hs_fore; w7.hi[5] = whsf_hi; w7.lo[5] = whsf_lo;
        w7.src[6] = w_indi;    w7.hi[6] = wind_hi; w7.lo[6] = wind_lo;
        pack_w7<<<56, 256, 0, stream>>>(w7);
    }
    gru_mfma<<<NR / 16, 512, 0, stream>>>(seqt, wih0p, whh0p, wih1p, whh1p,
                                          bih0, bhh0, bih1, bhh1, h1);
    float* x_hidden = h1;

    // ================= Phase B: predefined-concept branch =================
    hipMemsetAsync(den, 0, CDIM * sizeof(float), stream);
    den_atomic<<<dim3(CDIM / 64, 32), 256, 0, stream>>>(cm, mv, den);
    s2ct_trans<<<dim3(NR / 64, CDIM / 64), 256, 0, stream>>>(cm, mv, den, s2cT);
    pboth(stream, x_hidden, pbt_xh_hi, pbt_xh_lo, pkn_xh_hi, pkn_xh_lo, NR);
    hipMemsetAsync(hidden, 0, 65536 * sizeof(float), stream);
    mg(stream, s2cT, pkn_xh_hi, pkn_xh_lo, nullptr, hidden, CDIM, HDIM, NR, 8, 0);
    row_nonzero<<<CDIM, 64, 0, stream>>>(hidden, v1);
    mg(stream, hidden, pbt_xh_hi, pbt_xh_lo, nullptr, L, CDIM, NR, HDIM, 1, 0);
    cos_softmax_row<<<CDIM, 256, 0, stream>>>(L, NR, nullptr, nullptr, nullptr);
    hipMemsetAsync(hidden2, 0, 65536 * sizeof(float), stream);
    mg(stream, L, pkn_xh_hi, pkn_xh_lo, nullptr, hidden2, CDIM, HDIM, NR, 8, 0);
    row_norm<<<NR, 64, 0, stream>>>(x_hidden, xnorm);
    row_norm<<<CDIM, 64, 0, stream>>>(hidden2, h2n);
    pboth(stream, hidden2, pbt_h2_hi, pbt_h2_lo, pkn_h2_hi, pkn_h2_lo, CDIM);
    mg(stream, x_hidden, pbt_h2_hi, pbt_h2_lo, nullptr, c2s, NR, CDIM, HDIM, 1, 0);
    cos_softmax_row<<<NR, 256, 0, stream>>>(c2s, CDIM, xnorm, h2n, v1);
    hipMemsetAsync(p0, 0, 524288 * sizeof(float), stream);
    mg(stream, c2s, pkn_h2_hi, pkn_h2_lo, nullptr, p0, NR, HDIM, CDIM, 2, 0);
    mg(stream, p0, wps_hi, wps_lo, b_ps, p_shared, NR, HDIM, HDIM, 1, 1);
    // p_back fused with h_shared = x_hidden - p_back
    mg(stream, p_shared, wpsb_hi, wpsb_lo, b_ps_back, p_back, NR, HDIM, HDIM, 1, 1 | 8,
       x_hidden, h_shared);
    mg(stream, p_shared, wpsf_hi, wpsf_lo, b_ps_fore, out_ps, NR, HDIM, HDIM, 1, 1 | 2);

    // ================= Phase C: hidden-concept branch =================
    row_norm<<<NR, 64, 0, stream>>>(h_shared, hn);
    pbt(stream, h_shared, pbt_hsh_hi, pbt_hsh_lo, NR, HDIM);
    mg(stream, h_shared, pbt_hsh_hi, pbt_hsh_lo, nullptr, BIG, NR, NR, HDIM, 1, 0);
    scan_topk<<<NR, 256, 0, stream>>>(BIG, hn, diagv, tvals, tidx);
    hipMemsetAsync(colsum, 0, NR * sizeof(float), stream);
    hipMemsetAsync(hidden_h, 0, 524288 * sizeof(float), stream);
    colsum_scatter<<<(NR * KTOP + 255) / 256, 256, 0, stream>>>(tvals, tidx, colsum);
    hh_scatter<<<NR * KTOP, HDIM, 0, stream>>>(tvals, tidx, h_shared, hidden_h);
    hh_diag<<<2048, 256, 0, stream>>>(colsum, diagv, h_shared, hidden_h);
    row_norm_nz<<<NR, 64, 0, stream>>>(hidden_h, hhn, v2);
    pboth(stream, hidden_h, pbt_hh_hi, pbt_hh_lo, pkn_hh_hi, pkn_hh_lo, NR);
    hc2s_flash<<<NR / 16, 256, 0, stream>>>(h_shared, hn, hhn, v2,
                                            pbt_hh_hi, pbt_hh_lo,
                                            pkn_hh_hi, pkn_hh_lo, hsi0);
    mg(stream, hsi0, whs_hi, whs_lo, b_hs, h_si, NR, HDIM, HDIM, 1, 1);
    // h_back fused with indi = h_shared - h_back = x_hidden - p_back - h_back
    mg(stream, h_si, whsb_hi, whsb_lo, b_hs_back, h_back, NR, HDIM, HDIM, 1, 1 | 8,
       h_shared, indi);
    mg(stream, h_si, whsf_hi, whsf_lo, b_hs_fore, out_hs, NR, HDIM, HDIM, 1, 1 | 2);

    // ================= Phase D: individual branch + head =================
    mg(stream, indi, wind_hi, wind_lo, b_indi, out_indi, NR, HDIM, HDIM, 1, 1 | 2);
    head_kernel<<<NR, 64, 0, stream>>>(out_ps, out_hs, out_indi, w_out, b_out, out);
}